// Round 5
// baseline (289.010 us; speedup 1.0000x reference)
//
#include <hip/hip_runtime.h>
#include <math.h>

// Shapes (fixed): B=4, C=256, H=W=64, N=4096, 4C=1024, c8=32, r=16.

typedef float f32x4 __attribute__((ext_vector_type(4)));
typedef short s16x8 __attribute__((ext_vector_type(8)));
union FRAG { uint4 u; s16x8 s; };

__device__ __forceinline__ unsigned short f2bf(float f) {
    union { float f; unsigned int u; } v; v.f = f;
    unsigned int r = v.u + 0x7FFFu + ((v.u >> 16) & 1u);
    return (unsigned short)(r >> 16);
}

// ---------------------------------------------------------------------------
// K1/K5: per-(b,c) plane -> block-mean pyramid (+ feats in mode 0, x2 in mode 1)
// ---------------------------------------------------------------------------
__global__ __launch_bounds__(256) void k_pyramid(
    const float* __restrict__ xin, const float* __restrict__ gch,
    const float* __restrict__ spg, float* __restrict__ x2out,
    float* __restrict__ bm2, float* __restrict__ bm4, float* __restrict__ bm8,
    float* __restrict__ featA, float* __restrict__ fm1, float* __restrict__ fm2,
    float* __restrict__ fm4, float* __restrict__ fm8, int mode)
{
    __shared__ float sx[4096];
    __shared__ float s2[1024];
    __shared__ float s4[256];
    __shared__ float wred[4][8];
    const int bc = blockIdx.x;
    const int b = bc >> 8;
    const int t = threadIdx.x;
    const float* xp = xin + (size_t)bc * 4096;
    float gc = 1.f;
    if (mode == 1) gc = gch[bc];
    float sum = 0.f, mx = -1e30f;
    for (int r = 0; r < 4; r++) {
        int i4 = t + 256 * r;
        float4 v = ((const float4*)xp)[i4];
        if (mode == 1) {
            float4 sg = ((const float4*)(spg + (size_t)b * 4096))[i4];
            v.x *= gc * sg.x; v.y *= gc * sg.y; v.z *= gc * sg.z; v.w *= gc * sg.w;
            ((float4*)(x2out + (size_t)bc * 4096))[i4] = v;
        } else {
            sum += v.x + v.y + v.z + v.w;
            mx = fmaxf(mx, fmaxf(fmaxf(v.x, v.y), fmaxf(v.z, v.w)));
        }
        ((float4*)sx)[i4] = v;
    }
    __syncthreads();
    float mx2 = -1e30f;
    for (int r = 0; r < 4; r++) {
        int i = t + 256 * r;
        int r2 = i >> 5, c2 = i & 31;
        int p0 = 128 * r2 + 2 * c2;
        float v = 0.25f * (sx[p0] + sx[p0 + 1] + sx[p0 + 64] + sx[p0 + 65]);
        s2[i] = v;
        bm2[(size_t)bc * 1024 + i] = v;
        mx2 = fmaxf(mx2, v);
    }
    __syncthreads();
    float mx4;
    {
        int r4 = t >> 4, c4 = t & 15;
        int p0 = 64 * r4 + 2 * c4;
        float v = 0.25f * (s2[p0] + s2[p0 + 1] + s2[p0 + 32] + s2[p0 + 33]);
        s4[t] = v;
        bm4[(size_t)bc * 256 + t] = v;
        mx4 = v;
    }
    __syncthreads();
    float mx8 = -1e30f;
    if (t < 64) {
        int r8 = t >> 3, c8 = t & 7;
        int p0 = 32 * r8 + 2 * c8;
        float v = 0.25f * (s4[p0] + s4[p0 + 1] + s4[p0 + 16] + s4[p0 + 17]);
        bm8[(size_t)bc * 64 + t] = v;
        mx8 = v;
    }
    if (mode == 0) {
        float vs = sum, v1 = mx, v2 = mx2, v4 = mx4, v8 = mx8;
        #pragma unroll
        for (int o = 1; o < 64; o <<= 1) {
            vs += __shfl_xor(vs, o);
            v1 = fmaxf(v1, __shfl_xor(v1, o));
            v2 = fmaxf(v2, __shfl_xor(v2, o));
            v4 = fmaxf(v4, __shfl_xor(v4, o));
            v8 = fmaxf(v8, __shfl_xor(v8, o));
        }
        if ((t & 63) == 0) {
            int wd = t >> 6;
            wred[wd][0] = vs; wred[wd][1] = v1; wred[wd][2] = v2;
            wred[wd][3] = v4; wred[wd][4] = v8;
        }
        __syncthreads();
        if (t == 0) featA[bc] = (wred[0][0] + wred[1][0] + wred[2][0] + wred[3][0]) * (1.f / 4096.f);
        else if (t == 1) fm1[bc] = fmaxf(fmaxf(wred[0][1], wred[1][1]), fmaxf(wred[2][1], wred[3][1]));
        else if (t == 2) fm2[bc] = fmaxf(fmaxf(wred[0][2], wred[1][2]), fmaxf(wred[2][2], wred[3][2]));
        else if (t == 3) fm4[bc] = fmaxf(fmaxf(wred[0][3], wred[1][3]), fmaxf(wred[2][3], wred[3][3]));
        else if (t == 4) fm8[bc] = fmaxf(fmaxf(wred[0][4], wred[1][4]), fmaxf(wred[2][4], wred[3][4]));
    }
}

// ---------------------------------------------------------------------------
// K2: channel-gate MLP
// ---------------------------------------------------------------------------
__global__ __launch_bounds__(256) void k2_gate(
    const float* __restrict__ featA, const float* __restrict__ fm1,
    const float* __restrict__ fm2, const float* __restrict__ fm4, const float* __restrict__ fm8,
    const float* __restrict__ W1, const float* __restrict__ b1,
    const float* __restrict__ W2, const float* __restrict__ b2,
    float* __restrict__ g)
{
    __shared__ float sf[5][256];
    __shared__ float sh[5][16];
    __shared__ float hs[16];
    const int b = blockIdx.x, t = threadIdx.x;
    sf[0][t] = featA[b * 256 + t];
    sf[1][t] = fm1[b * 256 + t];
    sf[2][t] = fm2[b * 256 + t];
    sf[3][t] = fm4[b * 256 + t];
    sf[4][t] = fm8[b * 256 + t];
    __syncthreads();
    if (t < 80) {
        int f = t / 16, j = t % 16;
        float a = b1[j];
        for (int c = 0; c < 256; c++) a += sf[f][c] * W1[c * 16 + j];
        sh[f][j] = fmaxf(a, 0.f);
    }
    __syncthreads();
    if (t < 16) hs[t] = 4.f * sh[0][t] + sh[1][t] + sh[2][t] + sh[3][t] + sh[4][t];
    __syncthreads();
    float a = 8.f * b2[t];
    for (int j = 0; j < 16; j++) a += hs[j] * W2[j * 256 + t];
    g[b * 256 + t] = 1.f / (1.f + __expf(-a));
}

// ---------------------------------------------------------------------------
// K3: spatial-gate input. Grid 256: block = (b, 64-pixel chunk); 4 waves
// split the 256 channels; LDS cross-wave reduce.
// ---------------------------------------------------------------------------
__global__ __launch_bounds__(256) void k3_comp(
    const float* __restrict__ x, const float* __restrict__ bm2,
    const float* __restrict__ bm4, const float* __restrict__ bm8,
    const float* __restrict__ g, float* __restrict__ comp)
{
    __shared__ float sg[256];
    __shared__ float rmx[4][64];
    __shared__ float rsm[4][64];
    const int b = blockIdx.x >> 6;
    const int pix = ((blockIdx.x & 63) << 6) + (threadIdx.x & 63);
    const int wid = threadIdx.x >> 6;
    const int c0 = wid << 6;
    sg[threadIdx.x] = g[(b << 8) + threadIdx.x];
    __syncthreads();
    const int h = pix >> 6, w = pix & 63;
    const int i2 = ((h >> 1) << 5) + (w >> 1);
    const int i4 = ((h >> 2) << 4) + (w >> 2);
    const int i8 = ((h >> 3) << 3) + (w >> 3);
    const float* xb = x + ((size_t)b << 8) * 4096;
    const float* p2 = bm2 + ((size_t)b << 8) * 1024;
    const float* p4 = bm4 + ((size_t)b << 8) * 256;
    const float* p8 = bm8 + ((size_t)b << 8) * 64;
    float mx = -1e30f, sm = 0.f;
    for (int c = c0; c < c0 + 64; c++) {
        float gc = sg[c];
        float xv = xb[(size_t)c * 4096 + pix] * gc;
        float v2 = p2[c * 1024 + i2] * gc;
        float v4 = p4[c * 256 + i4] * gc;
        float v8 = p8[c * 64 + i8] * gc;
        mx = fmaxf(fmaxf(mx, xv), fmaxf(fmaxf(v2, v4), v8));
        sm += xv + v2 + v4 + v8;
    }
    rmx[wid][threadIdx.x & 63] = mx;
    rsm[wid][threadIdx.x & 63] = sm;
    __syncthreads();
    if (wid == 0) {
        int l = threadIdx.x;
        float m = fmaxf(fmaxf(rmx[0][l], rmx[1][l]), fmaxf(rmx[2][l], rmx[3][l]));
        float s = rsm[0][l] + rsm[1][l] + rsm[2][l] + rsm[3][l];
        comp[((size_t)b * 2) * 4096 + pix] = m;
        comp[((size_t)b * 2 + 1) * 4096 + pix] = s * (1.f / 1024.f);
    }
}

// ---------------------------------------------------------------------------
// K4: 7x7 conv (2->1, pad 3, no bias) + BN(eval) + sigmoid. Grid 256 x 64thr.
// ---------------------------------------------------------------------------
__global__ __launch_bounds__(64) void k4_spgate(
    const float* __restrict__ comp, const float* __restrict__ Wsp,
    const float* __restrict__ bn_g, const float* __restrict__ bn_b,
    const float* __restrict__ bn_m, const float* __restrict__ bn_v,
    float* __restrict__ spg)
{
    __shared__ float w[98];
    const int t = threadIdx.x;
    for (int i = t; i < 98; i += 64) w[i] = Wsp[i];
    __syncthreads();
    const int b = blockIdx.x >> 6;
    const int pix = ((blockIdx.x & 63) << 6) + t;
    const int h = pix >> 6, wx = pix & 63;
    const float* c0 = comp + (size_t)b * 2 * 4096;
    float acc = 0.f;
    for (int ci = 0; ci < 2; ci++)
        for (int kh = 0; kh < 7; kh++) {
            int hh = h + kh - 3;
            if (hh < 0 || hh >= 64) continue;
            for (int kw = 0; kw < 7; kw++) {
                int wwp = wx + kw - 3;
                if (wwp < 0 || wwp >= 64) continue;
                acc += c0[ci * 4096 + hh * 64 + wwp] * w[ci * 49 + kh * 7 + kw];
            }
        }
    float sc = rsqrtf(bn_v[0] + 1e-5f) * bn_g[0];
    float sp = (acc - bn_m[0]) * sc + bn_b[0];
    spg[b * 4096 + pix] = 1.f / (1.f + __expf(-sp));
}

// ---------------------------------------------------------------------------
// K_WCAST: bf16 copy of W[:,768:1024] rows (q|k|v order) -> WB[320][256]
// ---------------------------------------------------------------------------
__global__ __launch_bounds__(256) void k_wcast(
    const float* __restrict__ Wq, const float* __restrict__ Wk, const float* __restrict__ Wv,
    unsigned short* __restrict__ WB)
{
    const int o = blockIdx.x;
    const int t = threadIdx.x;
    const float* row = (o < 32) ? (Wq + (size_t)o * 1024)
                      : (o < 64) ? (Wk + (size_t)(o - 32) * 1024)
                                 : (Wv + (size_t)(o - 64) * 1024);
    WB[o * 256 + t] = f2bf(row[768 + t]);
}

// ---------------------------------------------------------------------------
// K_X2T: x2 fp32 [b][256 c][4096 n] -> x2T bf16 [b][4096 n][256 c]
// ---------------------------------------------------------------------------
__global__ __launch_bounds__(256) void k_x2t(
    const float* __restrict__ x2, unsigned short* __restrict__ x2T)
{
    __shared__ unsigned short T[64][72];
    const int b = blockIdx.z;
    const int cb = blockIdx.y * 64;
    const int nb = blockIdx.x * 64;
    const int t = threadIdx.x;
    #pragma unroll
    for (int r = 0; r < 16; r++) {
        int cl = (t >> 6) + 4 * r;
        int nl = t & 63;
        float v = x2[((size_t)(b * 256 + cb + cl)) * 4096 + nb + nl];
        T[nl][cl] = f2bf(v);
    }
    __syncthreads();
    #pragma unroll
    for (int pass = 0; pass < 4; pass++) {
        int nl = (t >> 4) + 16 * pass;
        int c4 = (t & 15) * 4;
        uint2 pk;
        pk.x = (unsigned)T[nl][c4] | ((unsigned)T[nl][c4 + 1] << 16);
        pk.y = (unsigned)T[nl][c4 + 2] | ((unsigned)T[nl][c4 + 3] << 16);
        *(uint2*)(x2T + ((size_t)(b * 4096 + nb + nl)) * 256 + cb + c4) = pk;
    }
}

// ---------------------------------------------------------------------------
// K6: fp32 projection GEMM for low-res P2/P4/P8, all three scales in ONE
// launch: blockIdx.x 0..15 -> P2, 16..19 -> P4, 20 -> P8.
// ---------------------------------------------------------------------------
__global__ __launch_bounds__(256) void k6_gemm(
    const float* __restrict__ Wq, const float* __restrict__ Wk, const float* __restrict__ Wv,
    const float* __restrict__ bm2b, const float* __restrict__ bm4b, const float* __restrict__ bm8b,
    float* __restrict__ P2, float* __restrict__ P4, float* __restrict__ P8)
{
    __shared__ float At[32][68];
    __shared__ float Bt[32][64];
    const int bx = blockIdx.x;
    int col_off, ns, nb;
    const float* src;
    float* outp;
    if (bx < 16)      { col_off = 0;   src = bm2b; ns = 1024; outp = P2; nb = bx; }
    else if (bx < 20) { col_off = 256; src = bm4b; ns = 256;  outp = P4; nb = bx - 16; }
    else              { col_off = 512; src = bm8b; ns = 64;   outp = P8; nb = 0; }
    const int b = blockIdx.z;
    const int o_base = blockIdx.y * 64;
    const int n_base = nb * 64;
    const int t = threadIdx.x;
    const int tn = t >> 4, tm = t & 15;
    const int lk = t & 31, lo8 = t >> 5;
    const int ln = t & 63, lk4 = t >> 6;
    float acc[4][4];
    #pragma unroll
    for (int i = 0; i < 4; i++)
        #pragma unroll
        for (int j = 0; j < 4; j++) acc[i][j] = 0.f;
    for (int k0 = 0; k0 < 256; k0 += 32) {
        __syncthreads();
        #pragma unroll
        for (int r = 0; r < 8; r++) {
            int o = o_base + lo8 + 8 * r;
            const float* wrow = (o < 32) ? (Wq + (size_t)o * 1024)
                              : (o < 64) ? (Wk + (size_t)(o - 32) * 1024)
                                         : (Wv + (size_t)(o - 64) * 1024);
            At[lk][lo8 + 8 * r] = wrow[col_off + k0 + lk];
        }
        #pragma unroll
        for (int r = 0; r < 8; r++)
            Bt[lk4 + 4 * r][ln] = src[((size_t)b * 256 + k0 + lk4 + 4 * r) * ns + n_base + ln];
        __syncthreads();
        #pragma unroll
        for (int kk = 0; kk < 32; kk++) {
            float4 a = *(const float4*)&At[kk][4 * tn];
            float4 bb = *(const float4*)&Bt[kk][4 * tm];
            acc[0][0] += a.x * bb.x; acc[0][1] += a.x * bb.y; acc[0][2] += a.x * bb.z; acc[0][3] += a.x * bb.w;
            acc[1][0] += a.y * bb.x; acc[1][1] += a.y * bb.y; acc[1][2] += a.y * bb.z; acc[1][3] += a.y * bb.w;
            acc[2][0] += a.z * bb.x; acc[2][1] += a.z * bb.y; acc[2][2] += a.z * bb.z; acc[2][3] += a.z * bb.w;
            acc[3][0] += a.w * bb.x; acc[3][1] += a.w * bb.y; acc[3][2] += a.w * bb.z; acc[3][3] += a.w * bb.w;
        }
    }
    #pragma unroll
    for (int i = 0; i < 4; i++)
        #pragma unroll
        for (int j = 0; j < 4; j++)
            outp[((size_t)b * 320 + o_base + 4 * tn + i) * ns + n_base + 4 * tm + j] = acc[i][j];
}

// ---------------------------------------------------------------------------
// K6M: full-res projection via bf16 MFMA. v writes go to FRAG-CONTIGUOUS
// layout: per chunk (n>>6), per frag (c16 = c>>4, khw = (k>>5)&1), the
// 64-lane MFMA A-fragment is stored contiguously in lane order:
//   addr = chunkbase + ((c16*2 + khw)*512) + (quad*16 + (c&15))*8 + (k&7)
// where quad=(k>>3)&3.  k7b then loads each A-frag with ONE perfectly
// coalesced global_load_dwordx4 (1 KB per frag) — no LDS staging for V.
// ---------------------------------------------------------------------------
__global__ __launch_bounds__(256) void k6m(
    const unsigned short* __restrict__ WB, const unsigned short* __restrict__ x2T,
    const float* __restrict__ bq, const float* __restrict__ bk, const float* __restrict__ bv,
    const float* __restrict__ P2, const float* __restrict__ P4, const float* __restrict__ P8,
    unsigned short* __restrict__ qT, unsigned short* __restrict__ kT,
    unsigned short* __restrict__ vC)
{
    const int b = blockIdx.z;
    const int obase = blockIdx.y * 64;
    const int nb = blockIdx.x * 128;
    const int t = threadIdx.x;
    const int w_ = t >> 6, lane = t & 63;
    const int quad = lane >> 4, l16 = lane & 15;
    const int nbase = nb + 32 * w_;
    f32x4 acc[4][2];
    #pragma unroll
    for (int ot = 0; ot < 4; ot++)
        #pragma unroll
        for (int nt = 0; nt < 2; nt++) { acc[ot][nt][0] = 0.f; acc[ot][nt][1] = 0.f; acc[ot][nt][2] = 0.f; acc[ot][nt][3] = 0.f; }
    const unsigned short* xb = x2T + ((size_t)b * 4096 + nbase) * 256;
    for (int k0 = 0; k0 < 256; k0 += 32) {
        FRAG af[4], bf[2];
        #pragma unroll
        for (int ot = 0; ot < 4; ot++)
            af[ot].u = *(const uint4*)(WB + (size_t)(obase + 16 * ot + l16) * 256 + k0 + quad * 8);
        #pragma unroll
        for (int nt = 0; nt < 2; nt++)
            bf[nt].u = *(const uint4*)(xb + (size_t)(16 * nt + l16) * 256 + k0 + quad * 8);
        #pragma unroll
        for (int ot = 0; ot < 4; ot++)
            #pragma unroll
            for (int nt = 0; nt < 2; nt++)
                acc[ot][nt] = __builtin_amdgcn_mfma_f32_16x16x32_bf16(af[ot].s, bf[nt].s, acc[ot][nt], 0, 0, 0);
    }
    #pragma unroll
    for (int ot = 0; ot < 4; ot++) {
        #pragma unroll
        for (int nt = 0; nt < 2; nt++) {
            int n = nbase + 16 * nt + l16;
            int h = n >> 6, wx = n & 63;
            int i2 = ((h >> 1) << 5) + (wx >> 1);
            int i4 = ((h >> 2) << 4) + (wx >> 2);
            int i8 = ((h >> 3) << 3) + (wx >> 3);
            float vals[4];
            #pragma unroll
            for (int r = 0; r < 4; r++) {
                int o = obase + 16 * ot + 4 * quad + r;
                float bias = (o < 32) ? bq[o] : (o < 64) ? bk[o - 32] : bv[o - 64];
                size_t ro = (size_t)b * 320 + o;
                vals[r] = acc[ot][nt][r] + bias
                        + P2[ro * 1024 + i2] + P4[ro * 256 + i4] + P8[ro * 64 + i8];
            }
            int o0 = obase + 16 * ot + 4 * quad;
            if (o0 < 64) {
                uint2 pk;
                pk.x = (unsigned)f2bf(vals[0]) | ((unsigned)f2bf(vals[1]) << 16);
                pk.y = (unsigned)f2bf(vals[2]) | ((unsigned)f2bf(vals[3]) << 16);
                if (o0 < 32)
                    *(uint2*)(qT + ((size_t)(b * 4096 + n)) * 32 + o0) = pk;
                else
                    *(uint2*)(kT + ((size_t)(b * 4096 + n)) * 32 + (o0 - 32)) = pk;
            } else {
                int chunk = n >> 6;
                int kk = n & 63;
                int khw_ = (kk >> 5) & 1, qd = (kk >> 3) & 3, ko = kk & 7;
                unsigned short* dst = vC + (((size_t)b * 64 + chunk) << 14);
                #pragma unroll
                for (int r = 0; r < 4; r++) {
                    int c = o0 - 64 + r;
                    dst[((((c >> 4) << 1) + khw_) << 9) + ((qd * 16 + (c & 15)) << 3) + ko] = f2bf(vals[r]);
                }
            }
        }
    }
}

// ---------------------------------------------------------------------------
// K7A: softmax stats pass (dense kT reads). XCD-aware bid decode: blocks of
// the same b land on one XCD-pair so kT_b/qT_b stay L2-resident.
// ---------------------------------------------------------------------------
__global__ __launch_bounds__(1024, 4) void k7a_stats(
    const unsigned short* __restrict__ qT, const unsigned short* __restrict__ kT,
    float* __restrict__ mout, float* __restrict__ ilout)
{
    __shared__ float sm[4][4][16], sl[4][4][16];   // [g][s][l16]
    const int bid = blockIdx.x;
    const int b = (bid >> 1) & 3;
    const int qbase = (((bid >> 3) << 1) | (bid & 1)) << 6;
    const int t = threadIdx.x;
    const int wid = t >> 6, lane = t & 63;
    const int g_ = wid >> 2, s_ = wid & 3;
    const int quad = lane >> 4, l16 = lane & 15;

    FRAG qf;
    qf.u = *(const uint4*)(qT + ((size_t)(b * 4096 + qbase + 16 * g_ + l16)) * 32 + quad * 8);
    const unsigned short* kTb = kT + (size_t)b * 4096 * 32;

    float m_run = -1e30f, l_run = 0.f;
    for (int j = 0; j < 16; j++) {
        const int mo = (s_ << 10) + (j << 6);
        f32x4 e[4];
        #pragma unroll
        for (int mt = 0; mt < 4; mt++) {
            FRAG kf;
            kf.u = *(const uint4*)(kTb + (size_t)(mo + 16 * mt + l16) * 32 + quad * 8);
            f32x4 z; z[0] = 0.f; z[1] = 0.f; z[2] = 0.f; z[3] = 0.f;
            e[mt] = __builtin_amdgcn_mfma_f32_16x16x32_bf16(kf.s, qf.s, z, 0, 0, 0);
        }
        float pm = e[0][0];
        #pragma unroll
        for (int mt = 0; mt < 4; mt++)
            #pragma unroll
            for (int r = 0; r < 4; r++) pm = fmaxf(pm, e[mt][r]);
        float mnew = fmaxf(m_run, pm);
        float al = __expf(m_run - mnew);
        float ps = 0.f;
        #pragma unroll
        for (int mt = 0; mt < 4; mt++)
            #pragma unroll
            for (int r = 0; r < 4; r++) ps += __expf(e[mt][r] - mnew);
        l_run = l_run * al + ps;
        m_run = mnew;
    }
    #pragma unroll
    for (int o = 16; o < 64; o <<= 1) {
        float mo_ = __shfl_xor(m_run, o);
        float lo_ = __shfl_xor(l_run, o);
        float m2 = fmaxf(m_run, mo_);
        l_run = l_run * __expf(m_run - m2) + lo_ * __expf(mo_ - m2);
        m_run = m2;
    }
    if (quad == 0) { sm[g_][s_][l16] = m_run; sl[g_][s_][l16] = l_run; }
    __syncthreads();
    if (t < 64) {
        int g = t >> 4, l = t & 15;
        float m0 = sm[g][0][l], m1 = sm[g][1][l], m2 = sm[g][2][l], m3 = sm[g][3][l];
        float mx = fmaxf(fmaxf(m0, m1), fmaxf(m2, m3));
        float l_ = sl[g][0][l] * __expf(m0 - mx) + sl[g][1][l] * __expf(m1 - mx)
                 + sl[g][2][l] * __expf(m2 - mx) + sl[g][3][l] * __expf(m3 - mx);
        int n = qbase + 16 * g + l;
        mout[b * 4096 + n] = mx;
        ilout[b * 4096 + n] = 1.f / l_;
    }
}

// ---------------------------------------------------------------------------
// K7B v12: OCCUPANCY fix — 4 small blocks per CU instead of 1 big one.
//  - v11 post-mortem: barrier-free slab duplication regressed (bank
//    conflicts 14.7M from the 64B-row slab + 4x exp VALU 51%). v10's real
//    limiter was 1 block/CU: at every barrier / L2-latency point nothing
//    fills the SIMD (Occupancy 20%).
//  - v12: block = 256 thr (4 waves), covers (b, 32 q-cols, 128 channels).
//    Grid 1024 = 4 blocks/CU = 16 waves/CU (4/SIMD). Independent blocks'
//    stalls anti-correlate. Per-CU PV MFMA unchanged; QK duplicated only
//    2x (c-split); q-split duplicates nothing.
//  - Keeps v10's PROVEN PL swizzle (128B rows, granule ^ (l16&7), 1.1M
//    conflicts) and v11's PROVEN XCD pinning (FETCH 45.7 -> 18 MB):
//    b = (bid>>1)&3, csplit = bid&1 -> each XCD serves one (b, c-half)
//    = 1MB vC-half + 1MB kT, L2-resident.
//  - V direct global->VGPR frag loads (dbuf, 1 chunk ahead); K frags 2
//    ahead; per-chunk barriered P handoff exactly as v10.
// Waves: wid = (cw = wid&1 [64c stripe], khw = wid>>1 [32-key half]).
// Wave QK: ntq = cw (its 16q x its khw's 32 keys -> 2 MFMA + 8 exp).
// Wave PV: acc[4][2] = 64c x 32q over its key half.
// LDS: PL[2][32][64] 8KB + SB[64][36] 9.2KB = 17.2KB -> 4 blocks = 69KB/CU.
// ---------------------------------------------------------------------------
__global__ __launch_bounds__(256, 4) void k7b_attn(
    const unsigned short* __restrict__ qT, const unsigned short* __restrict__ kT,
    const unsigned short* __restrict__ vC, const float* __restrict__ mstat,
    const float* __restrict__ ilstat, const float* __restrict__ x2,
    const float* __restrict__ gamma, float* __restrict__ outp)
{
    __shared__ __align__(16) unsigned short PL[2][32][64];  // 8 KB P tiles
    __shared__ __align__(16) float SB[64][36];              // 9.2 KB combine buffer
    const int bid = blockIdx.x;
    const int b = (bid >> 1) & 3;
    const int csplit = bid & 1;
    const int qbase = (bid >> 3) << 5;      // 32 q-cols per block
    const int t = threadIdx.x;
    const int wid = t >> 6, lane = t & 63;
    const int cw = wid & 1, khw = wid >> 1;
    const int quad = lane >> 4, l16 = lane & 15;
    const int mt0 = 2 * khw, mt1 = 2 * khw + 1;
    const int nq = qbase + 16 * cw + l16;   // q-column of this wave's P rows

    FRAG qf;
    qf.u = *(const uint4*)(qT + ((size_t)(b * 4096 + nq)) * 32 + quad * 8);
    const float mN = mstat[b * 4096 + nq];

    f32x4 acc[4][2];
    #pragma unroll
    for (int ct = 0; ct < 4; ct++)
        #pragma unroll
        for (int nt = 0; nt < 2; nt++) { acc[ct][nt][0] = 0.f; acc[ct][nt][1] = 0.f; acc[ct][nt][2] = 0.f; acc[ct][nt][3] = 0.f; }
    const unsigned short* kTb = kT + (size_t)b * 4096 * 32;
    // per-wave V-frag base: frag (c16 = 8*csplit + 4*cw + ct, khw), lane-contig.
    const unsigned short* vfb = vC + ((size_t)b * 64 << 14)
                              + ((((8 * csplit + 4 * cw) << 1) + khw) << 9) + lane * 8;

    // PL swizzle (v10-proven): row = 64 shorts = 128 B = 8 granules of 16 B;
    // phys_granule = logical ^ (l16 & 7).
    const int po  = 4 * (quad & 1);
    const int pg0 = ((4 * khw + (quad >> 1)) ^ (l16 & 7));        // pkA granule
    const int pg1 = pg0 ^ 2;                                       // pkB granule
    const int pgr = ((4 * khw + quad) ^ (l16 & 7)) << 3;          // bp read offset

    FRAG avA[4], avB[4], kcA0, kcA1, kcB0, kcB1;

#define AV_LOAD(AV, CH) do { \
    const unsigned short* vfj = vfb + ((size_t)(CH) << 14); \
    AV[0].u = *(const uint4*)(vfj); \
    AV[1].u = *(const uint4*)(vfj + 1024); \
    AV[2].u = *(const uint4*)(vfj + 2048); \
    AV[3].u = *(const uint4*)(vfj + 3072); \
} while (0)

#define KC_LOAD(K0, K1, CH) do { \
    const int mo_ = (CH) << 6; \
    K0.u = *(const uint4*)(kTb + (size_t)(mo_ + 16 * mt0 + l16) * 32 + quad * 8); \
    K1.u = *(const uint4*)(kTb + (size_t)(mo_ + 16 * mt1 + l16) * 32 + quad * 8); \
} while (0)

// QK for this wave's (ntq = cw, khw) -> P tile rows 16*cw + l16.
#define QK_STORE(DST, K0, K1) do { \
    f32x4 z; z[0] = 0.f; z[1] = 0.f; z[2] = 0.f; z[3] = 0.f; \
    f32x4 e0 = __builtin_amdgcn_mfma_f32_16x16x32_bf16(K0.s, qf.s, z, 0, 0, 0); \
    f32x4 e1 = __builtin_amdgcn_mfma_f32_16x16x32_bf16(K1.s, qf.s, z, 0, 0, 0); \
    union { float f; unsigned int u; } p0, p1, p2, p3; \
    uint2 pkA, pkB; \
    p0.f = __expf(e0[0] - mN); p1.f = __expf(e0[1] - mN); \
    p2.f = __expf(e0[2] - mN); p3.f = __expf(e0[3] - mN); \
    pkA.x = __builtin_amdgcn_perm(p1.u, p0.u, 0x07060302u); \
    pkA.y = __builtin_amdgcn_perm(p3.u, p2.u, 0x07060302u); \
    p0.f = __expf(e1[0] - mN); p1.f = __expf(e1[1] - mN); \
    p2.f = __expf(e1[2] - mN); p3.f = __expf(e1[3] - mN); \
    pkB.x = __builtin_amdgcn_perm(p1.u, p0.u, 0x07060302u); \
    pkB.y = __builtin_amdgcn_perm(p3.u, p2.u, 0x07060302u); \
    unsigned short* rw = &PL[DST][16 * cw + l16][po]; \
    *(uint2*)(rw + pg0 * 8) = pkA; \
    *(uint2*)(rw + pg1 * 8) = pkB; \
} while (0)

#define PV_STEP(AV, CUR) do { \
    FRAG bp[2]; \
    bp[0].u = *(const uint4*)&PL[CUR][l16][pgr]; \
    bp[1].u = *(const uint4*)&PL[CUR][16 + l16][pgr]; \
    __builtin_amdgcn_s_setprio(1); \
    _Pragma("unroll") \
    for (int ct_ = 0; ct_ < 4; ct_++) { \
        acc[ct_][0] = __builtin_amdgcn_mfma_f32_16x16x32_bf16(AV[ct_].s, bp[0].s, acc[ct_][0], 0, 0, 0); \
        acc[ct_][1] = __builtin_amdgcn_mfma_f32_16x16x32_bf16(AV[ct_].s, bp[1].s, acc[ct_][1], 0, 0, 0); \
    } \
    __builtin_amdgcn_s_setprio(0); \
} while (0)

    // --- prologue: av(0); kc(0); QK(0)->PL[0]; kc(1) ---
    AV_LOAD(avA, 0);
    KC_LOAD(kcA0, kcA1, 0);
    QK_STORE(0, kcA0, kcA1);
    KC_LOAD(kcB0, kcB1, 1);

    for (int jj = 0; jj < 32; jj++) {
        const int j = 2 * jj;
        // ---- phase A: compute PV(j) [even chunk], prefetch j+1 ----
        __syncthreads();
        {
            if (j < 63) AV_LOAD(avB, j + 1);
            QK_STORE(1, kcB0, kcB1);                 // chunk j+1 (j <= 62 always)
            if (j < 62) KC_LOAD(kcA0, kcA1, j + 2);
        }
        PV_STEP(avA, 0);
        // ---- phase B: compute PV(j+1) [odd chunk], prefetch j+2 ----
        __syncthreads();
        if (j < 62) {
            AV_LOAD(avA, j + 2);
            QK_STORE(0, kcA0, kcA1);                 // chunk j+2
            if (j < 61) KC_LOAD(kcB0, kcB1, j + 3);
        }
        PV_STEP(avB, 1);
    }
#undef AV_LOAD
#undef KC_LOAD
#undef QK_STORE
#undef PV_STEP

    // --- epilogue: combine khw halves via SB, 2 cw-stripe rounds ---
    const float gm = gamma[0];
    for (int s = 0; s < 2; s++) {
        __syncthreads();
        if (khw == 0 && cw == s) {
            #pragma unroll
            for (int ct = 0; ct < 4; ct++)
                #pragma unroll
                for (int nt = 0; nt < 2; nt++)
                    #pragma unroll
                    for (int r = 0; r < 4; r++)
                        SB[16 * ct + 4 * quad + r][16 * nt + l16] = acc[ct][nt][r];
        }
        __syncthreads();
        if (khw == 1 && cw == s) {
            #pragma unroll
            for (int ct = 0; ct < 4; ct++)
                #pragma unroll
                for (int nt = 0; nt < 2; nt++)
                    #pragma unroll
                    for (int r = 0; r < 4; r++)
                        SB[16 * ct + 4 * quad + r][16 * nt + l16] += acc[ct][nt][r];
        }
        __syncthreads();
        // cooperative store: 64c x 32n with 256 threads
        #pragma unroll
        for (int pass = 0; pass < 2; pass++) {
            int cl = (t >> 3) + 32 * pass;
            int n4 = (t & 7) * 4;
            float4 vv = *(float4*)&SB[cl][n4];
            float4 il4 = *(const float4*)(ilstat + (size_t)b * 4096 + qbase + n4);
            size_t idx = ((size_t)(b * 256 + 128 * csplit + 64 * s + cl)) * 4096 + qbase + n4;
            float4 xv = *(const float4*)(x2 + idx);
            float4 ov;
            ov.x = gm * vv.x * il4.x + xv.x;
            ov.y = gm * vv.y * il4.y + xv.y;
            ov.z = gm * vv.z * il4.z + xv.z;
            ov.w = gm * vv.w * il4.w + xv.w;
            *(float4*)(outp + idx) = ov;
        }
    }
}

// ---------------------------------------------------------------------------
extern "C" void kernel_launch(void* const* d_in, const int* in_sizes, int n_in,
                              void* d_out, int out_size, void* d_ws, size_t ws_size,
                              hipStream_t stream) {
    (void)in_sizes; (void)n_in; (void)out_size; (void)ws_size;
    const float* x    = (const float*)d_in[0];
    const float* W1   = (const float*)d_in[1];
    const float* b1   = (const float*)d_in[2];
    const float* W2   = (const float*)d_in[3];
    const float* b2   = (const float*)d_in[4];
    const float* Wq   = (const float*)d_in[5];
    const float* bq   = (const float*)d_in[6];
    const float* Wk   = (const float*)d_in[7];
    const float* bk   = (const float*)d_in[8];
    const float* Wv   = (const float*)d_in[9];
    const float* bv   = (const float*)d_in[10];
    const float* gam  = (const float*)d_in[11];
    const float* Wsp  = (const float*)d_in[12];
    const float* bn_g = (const float*)d_in[13];
    const float* bn_b = (const float*)d_in[14];
    const float* bn_m = (const float*)d_in[15];
    const float* bn_v = (const float*)d_in[16];

    float* ws = (float*)d_ws;
    float* bm2   = ws; ws += (size_t)4 * 256 * 1024;
    float* bm4   = ws; ws += (size_t)4 * 256 * 256;
    float* bm8   = ws; ws += (size_t)4 * 256 * 64;
    float* featA = ws; ws += 1024;
    float* fm1   = ws; ws += 1024;
    float* fm2   = ws; ws += 1024;
    float* fm4   = ws; ws += 1024;
    float* fm8   = ws; ws += 1024;
    float* g     = ws; ws += 1024;
    float* comp  = ws; ws += (size_t)4 * 2 * 4096;
    float* spg   = ws; ws += (size_t)4 * 4096;
    float* x2    = ws; ws += (size_t)4 * 256 * 4096;
    float* bm2b  = ws; ws += (size_t)4 * 256 * 1024;
    float* bm4b  = ws; ws += (size_t)4 * 256 * 256;
    float* bm8b  = ws; ws += (size_t)4 * 256 * 64;
    float* P2    = ws; ws += (size_t)4 * 320 * 1024;
    float* P4    = ws; ws += (size_t)4 * 320 * 256;
    float* P8    = ws; ws += (size_t)4 * 320 * 64;
    float* mstat = ws; ws += (size_t)4 * 4096;
    float* ilstat= ws; ws += (size_t)4 * 4096;
    unsigned short* qT  = (unsigned short*)ws; ws += (size_t)4 * 4096 * 32 / 2;
    unsigned short* kT  = (unsigned short*)ws; ws += (size_t)4 * 4096 * 32 / 2;
    unsigned short* vCp = (unsigned short*)ws; ws += (size_t)4 * 64 * 16384 / 2;
    unsigned short* x2T = (unsigned short*)ws; ws += (size_t)4 * 4096 * 256 / 2;
    unsigned short* WB  = (unsigned short*)ws; ws += (size_t)320 * 256 / 2;

    // Weight cast (no deps)
    k_wcast<<<320, 256, 0, stream>>>(Wq, Wk, Wv, WB);
    // Stage 1: channel gate
    k_pyramid<<<1024, 256, 0, stream>>>(x, nullptr, nullptr, nullptr,
                                        bm2, bm4, bm8, featA, fm1, fm2, fm4, fm8, 0);
    k2_gate<<<4, 256, 0, stream>>>(featA, fm1, fm2, fm4, fm8, W1, b1, W2, b2, g);
    // Stage 2: spatial gate
    k3_comp<<<256, 256, 0, stream>>>(x, bm2, bm4, bm8, g, comp);
    k4_spgate<<<256, 64, 0, stream>>>(comp, Wsp, bn_g, bn_b, bn_m, bn_v, spg);
    k_pyramid<<<1024, 256, 0, stream>>>(x, g, spg, x2,
                                        bm2b, bm4b, bm8b,
                                        nullptr, nullptr, nullptr, nullptr, nullptr, 1);
    // x2 -> bf16 transposed [n][c]
    k_x2t<<<dim3(64, 4, 4), 256, 0, stream>>>(x2, x2T);
    // Stage 3: q/k/v projections, multiscale-decomposed (single low-res launch)
    k6_gemm<<<dim3(21, 5, 4), 256, 0, stream>>>(Wq, Wk, Wv, bm2b, bm4b, bm8b, P2, P4, P8);
    k6m<<<dim3(32, 5, 4), 256, 0, stream>>>(WB, x2T, bq, bk, bv, P2, P4, P8, qT, kT, vCp);
    // Two-pass attention: stats, then 4-blocks/CU pipelined PV
    k7a_stats<<<256, 1024, 0, stream>>>(qT, kT, mstat, ilstat);
    k7b_attn<<<1024, 256, 0, stream>>>(qT, kT, vCp, mstat, ilstat, x2, gam, (float*)d_out);
}

// Round 6
// 278.492 us; speedup vs baseline: 1.0378x; 1.0378x over previous
//
#include <hip/hip_runtime.h>
#include <math.h>

// Shapes (fixed): B=4, C=256, H=W=64, N=4096, 4C=1024, c8=32, r=16.

typedef float f32x4 __attribute__((ext_vector_type(4)));
typedef short s16x8 __attribute__((ext_vector_type(8)));
union FRAG { uint4 u; s16x8 s; };

__device__ __forceinline__ unsigned short f2bf(float f) {
    union { float f; unsigned int u; } v; v.f = f;
    unsigned int r = v.u + 0x7FFFu + ((v.u >> 16) & 1u);
    return (unsigned short)(r >> 16);
}

// ---------------------------------------------------------------------------
// K1/K5: per-(b,c) plane -> block-mean pyramid (+ feats in mode 0, x2 in mode 1)
// ---------------------------------------------------------------------------
__global__ __launch_bounds__(256) void k_pyramid(
    const float* __restrict__ xin, const float* __restrict__ gch,
    const float* __restrict__ spg, float* __restrict__ x2out,
    float* __restrict__ bm2, float* __restrict__ bm4, float* __restrict__ bm8,
    float* __restrict__ featA, float* __restrict__ fm1, float* __restrict__ fm2,
    float* __restrict__ fm4, float* __restrict__ fm8, int mode)
{
    __shared__ float sx[4096];
    __shared__ float s2[1024];
    __shared__ float s4[256];
    __shared__ float wred[4][8];
    const int bc = blockIdx.x;
    const int b = bc >> 8;
    const int t = threadIdx.x;
    const float* xp = xin + (size_t)bc * 4096;
    float gc = 1.f;
    if (mode == 1) gc = gch[bc];
    float sum = 0.f, mx = -1e30f;
    for (int r = 0; r < 4; r++) {
        int i4 = t + 256 * r;
        float4 v = ((const float4*)xp)[i4];
        if (mode == 1) {
            float4 sg = ((const float4*)(spg + (size_t)b * 4096))[i4];
            v.x *= gc * sg.x; v.y *= gc * sg.y; v.z *= gc * sg.z; v.w *= gc * sg.w;
            ((float4*)(x2out + (size_t)bc * 4096))[i4] = v;
        } else {
            sum += v.x + v.y + v.z + v.w;
            mx = fmaxf(mx, fmaxf(fmaxf(v.x, v.y), fmaxf(v.z, v.w)));
        }
        ((float4*)sx)[i4] = v;
    }
    __syncthreads();
    float mx2 = -1e30f;
    for (int r = 0; r < 4; r++) {
        int i = t + 256 * r;
        int r2 = i >> 5, c2 = i & 31;
        int p0 = 128 * r2 + 2 * c2;
        float v = 0.25f * (sx[p0] + sx[p0 + 1] + sx[p0 + 64] + sx[p0 + 65]);
        s2[i] = v;
        bm2[(size_t)bc * 1024 + i] = v;
        mx2 = fmaxf(mx2, v);
    }
    __syncthreads();
    float mx4;
    {
        int r4 = t >> 4, c4 = t & 15;
        int p0 = 64 * r4 + 2 * c4;
        float v = 0.25f * (s2[p0] + s2[p0 + 1] + s2[p0 + 32] + s2[p0 + 33]);
        s4[t] = v;
        bm4[(size_t)bc * 256 + t] = v;
        mx4 = v;
    }
    __syncthreads();
    float mx8 = -1e30f;
    if (t < 64) {
        int r8 = t >> 3, c8 = t & 7;
        int p0 = 32 * r8 + 2 * c8;
        float v = 0.25f * (s4[p0] + s4[p0 + 1] + s4[p0 + 16] + s4[p0 + 17]);
        bm8[(size_t)bc * 64 + t] = v;
        mx8 = v;
    }
    if (mode == 0) {
        float vs = sum, v1 = mx, v2 = mx2, v4 = mx4, v8 = mx8;
        #pragma unroll
        for (int o = 1; o < 64; o <<= 1) {
            vs += __shfl_xor(vs, o);
            v1 = fmaxf(v1, __shfl_xor(v1, o));
            v2 = fmaxf(v2, __shfl_xor(v2, o));
            v4 = fmaxf(v4, __shfl_xor(v4, o));
            v8 = fmaxf(v8, __shfl_xor(v8, o));
        }
        if ((t & 63) == 0) {
            int wd = t >> 6;
            wred[wd][0] = vs; wred[wd][1] = v1; wred[wd][2] = v2;
            wred[wd][3] = v4; wred[wd][4] = v8;
        }
        __syncthreads();
        if (t == 0) featA[bc] = (wred[0][0] + wred[1][0] + wred[2][0] + wred[3][0]) * (1.f / 4096.f);
        else if (t == 1) fm1[bc] = fmaxf(fmaxf(wred[0][1], wred[1][1]), fmaxf(wred[2][1], wred[3][1]));
        else if (t == 2) fm2[bc] = fmaxf(fmaxf(wred[0][2], wred[1][2]), fmaxf(wred[2][2], wred[3][2]));
        else if (t == 3) fm4[bc] = fmaxf(fmaxf(wred[0][3], wred[1][3]), fmaxf(wred[2][3], wred[3][3]));
        else if (t == 4) fm8[bc] = fmaxf(fmaxf(wred[0][4], wred[1][4]), fmaxf(wred[2][4], wred[3][4]));
    }
}

// ---------------------------------------------------------------------------
// K2: channel-gate MLP
// ---------------------------------------------------------------------------
__global__ __launch_bounds__(256) void k2_gate(
    const float* __restrict__ featA, const float* __restrict__ fm1,
    const float* __restrict__ fm2, const float* __restrict__ fm4, const float* __restrict__ fm8,
    const float* __restrict__ W1, const float* __restrict__ b1,
    const float* __restrict__ W2, const float* __restrict__ b2,
    float* __restrict__ g)
{
    __shared__ float sf[5][256];
    __shared__ float sh[5][16];
    __shared__ float hs[16];
    const int b = blockIdx.x, t = threadIdx.x;
    sf[0][t] = featA[b * 256 + t];
    sf[1][t] = fm1[b * 256 + t];
    sf[2][t] = fm2[b * 256 + t];
    sf[3][t] = fm4[b * 256 + t];
    sf[4][t] = fm8[b * 256 + t];
    __syncthreads();
    if (t < 80) {
        int f = t / 16, j = t % 16;
        float a = b1[j];
        for (int c = 0; c < 256; c++) a += sf[f][c] * W1[c * 16 + j];
        sh[f][j] = fmaxf(a, 0.f);
    }
    __syncthreads();
    if (t < 16) hs[t] = 4.f * sh[0][t] + sh[1][t] + sh[2][t] + sh[3][t] + sh[4][t];
    __syncthreads();
    float a = 8.f * b2[t];
    for (int j = 0; j < 16; j++) a += hs[j] * W2[j * 256 + t];
    g[b * 256 + t] = 1.f / (1.f + __expf(-a));
}

// ---------------------------------------------------------------------------
// K3: spatial-gate input. Grid 256: block = (b, 64-pixel chunk); 4 waves
// split the 256 channels; LDS cross-wave reduce.
// ---------------------------------------------------------------------------
__global__ __launch_bounds__(256) void k3_comp(
    const float* __restrict__ x, const float* __restrict__ bm2,
    const float* __restrict__ bm4, const float* __restrict__ bm8,
    const float* __restrict__ g, float* __restrict__ comp)
{
    __shared__ float sg[256];
    __shared__ float rmx[4][64];
    __shared__ float rsm[4][64];
    const int b = blockIdx.x >> 6;
    const int pix = ((blockIdx.x & 63) << 6) + (threadIdx.x & 63);
    const int wid = threadIdx.x >> 6;
    const int c0 = wid << 6;
    sg[threadIdx.x] = g[(b << 8) + threadIdx.x];
    __syncthreads();
    const int h = pix >> 6, w = pix & 63;
    const int i2 = ((h >> 1) << 5) + (w >> 1);
    const int i4 = ((h >> 2) << 4) + (w >> 2);
    const int i8 = ((h >> 3) << 3) + (w >> 3);
    const float* xb = x + ((size_t)b << 8) * 4096;
    const float* p2 = bm2 + ((size_t)b << 8) * 1024;
    const float* p4 = bm4 + ((size_t)b << 8) * 256;
    const float* p8 = bm8 + ((size_t)b << 8) * 64;
    float mx = -1e30f, sm = 0.f;
    for (int c = c0; c < c0 + 64; c++) {
        float gc = sg[c];
        float xv = xb[(size_t)c * 4096 + pix] * gc;
        float v2 = p2[c * 1024 + i2] * gc;
        float v4 = p4[c * 256 + i4] * gc;
        float v8 = p8[c * 64 + i8] * gc;
        mx = fmaxf(fmaxf(mx, xv), fmaxf(fmaxf(v2, v4), v8));
        sm += xv + v2 + v4 + v8;
    }
    rmx[wid][threadIdx.x & 63] = mx;
    rsm[wid][threadIdx.x & 63] = sm;
    __syncthreads();
    if (wid == 0) {
        int l = threadIdx.x;
        float m = fmaxf(fmaxf(rmx[0][l], rmx[1][l]), fmaxf(rmx[2][l], rmx[3][l]));
        float s = rsm[0][l] + rsm[1][l] + rsm[2][l] + rsm[3][l];
        comp[((size_t)b * 2) * 4096 + pix] = m;
        comp[((size_t)b * 2 + 1) * 4096 + pix] = s * (1.f / 1024.f);
    }
}

// ---------------------------------------------------------------------------
// K4: 7x7 conv (2->1, pad 3, no bias) + BN(eval) + sigmoid. Grid 256 x 64thr.
// ---------------------------------------------------------------------------
__global__ __launch_bounds__(64) void k4_spgate(
    const float* __restrict__ comp, const float* __restrict__ Wsp,
    const float* __restrict__ bn_g, const float* __restrict__ bn_b,
    const float* __restrict__ bn_m, const float* __restrict__ bn_v,
    float* __restrict__ spg)
{
    __shared__ float w[98];
    const int t = threadIdx.x;
    for (int i = t; i < 98; i += 64) w[i] = Wsp[i];
    __syncthreads();
    const int b = blockIdx.x >> 6;
    const int pix = ((blockIdx.x & 63) << 6) + t;
    const int h = pix >> 6, wx = pix & 63;
    const float* c0 = comp + (size_t)b * 2 * 4096;
    float acc = 0.f;
    for (int ci = 0; ci < 2; ci++)
        for (int kh = 0; kh < 7; kh++) {
            int hh = h + kh - 3;
            if (hh < 0 || hh >= 64) continue;
            for (int kw = 0; kw < 7; kw++) {
                int wwp = wx + kw - 3;
                if (wwp < 0 || wwp >= 64) continue;
                acc += c0[ci * 4096 + hh * 64 + wwp] * w[ci * 49 + kh * 7 + kw];
            }
        }
    float sc = rsqrtf(bn_v[0] + 1e-5f) * bn_g[0];
    float sp = (acc - bn_m[0]) * sc + bn_b[0];
    spg[b * 4096 + pix] = 1.f / (1.f + __expf(-sp));
}

// ---------------------------------------------------------------------------
// K_WCAST: bf16 copy of W[:,768:1024] rows (q|k|v order) -> WB[320][256]
// ---------------------------------------------------------------------------
__global__ __launch_bounds__(256) void k_wcast(
    const float* __restrict__ Wq, const float* __restrict__ Wk, const float* __restrict__ Wv,
    unsigned short* __restrict__ WB)
{
    const int o = blockIdx.x;
    const int t = threadIdx.x;
    const float* row = (o < 32) ? (Wq + (size_t)o * 1024)
                      : (o < 64) ? (Wk + (size_t)(o - 32) * 1024)
                                 : (Wv + (size_t)(o - 64) * 1024);
    WB[o * 256 + t] = f2bf(row[768 + t]);
}

// ---------------------------------------------------------------------------
// K_X2T: x2 fp32 [b][256 c][4096 n] -> x2T bf16 [b][4096 n][256 c]
// ---------------------------------------------------------------------------
__global__ __launch_bounds__(256) void k_x2t(
    const float* __restrict__ x2, unsigned short* __restrict__ x2T)
{
    __shared__ unsigned short T[64][72];
    const int b = blockIdx.z;
    const int cb = blockIdx.y * 64;
    const int nb = blockIdx.x * 64;
    const int t = threadIdx.x;
    #pragma unroll
    for (int r = 0; r < 16; r++) {
        int cl = (t >> 6) + 4 * r;
        int nl = t & 63;
        float v = x2[((size_t)(b * 256 + cb + cl)) * 4096 + nb + nl];
        T[nl][cl] = f2bf(v);
    }
    __syncthreads();
    #pragma unroll
    for (int pass = 0; pass < 4; pass++) {
        int nl = (t >> 4) + 16 * pass;
        int c4 = (t & 15) * 4;
        uint2 pk;
        pk.x = (unsigned)T[nl][c4] | ((unsigned)T[nl][c4 + 1] << 16);
        pk.y = (unsigned)T[nl][c4 + 2] | ((unsigned)T[nl][c4 + 3] << 16);
        *(uint2*)(x2T + ((size_t)(b * 4096 + nb + nl)) * 256 + cb + c4) = pk;
    }
}

// ---------------------------------------------------------------------------
// K6: fp32 projection GEMM for low-res P2/P4/P8, all three scales in ONE
// launch: blockIdx.x 0..15 -> P2, 16..19 -> P4, 20 -> P8.
// ---------------------------------------------------------------------------
__global__ __launch_bounds__(256) void k6_gemm(
    const float* __restrict__ Wq, const float* __restrict__ Wk, const float* __restrict__ Wv,
    const float* __restrict__ bm2b, const float* __restrict__ bm4b, const float* __restrict__ bm8b,
    float* __restrict__ P2, float* __restrict__ P4, float* __restrict__ P8)
{
    __shared__ float At[32][68];
    __shared__ float Bt[32][64];
    const int bx = blockIdx.x;
    int col_off, ns, nb;
    const float* src;
    float* outp;
    if (bx < 16)      { col_off = 0;   src = bm2b; ns = 1024; outp = P2; nb = bx; }
    else if (bx < 20) { col_off = 256; src = bm4b; ns = 256;  outp = P4; nb = bx - 16; }
    else              { col_off = 512; src = bm8b; ns = 64;   outp = P8; nb = 0; }
    const int b = blockIdx.z;
    const int o_base = blockIdx.y * 64;
    const int n_base = nb * 64;
    const int t = threadIdx.x;
    const int tn = t >> 4, tm = t & 15;
    const int lk = t & 31, lo8 = t >> 5;
    const int ln = t & 63, lk4 = t >> 6;
    float acc[4][4];
    #pragma unroll
    for (int i = 0; i < 4; i++)
        #pragma unroll
        for (int j = 0; j < 4; j++) acc[i][j] = 0.f;
    for (int k0 = 0; k0 < 256; k0 += 32) {
        __syncthreads();
        #pragma unroll
        for (int r = 0; r < 8; r++) {
            int o = o_base + lo8 + 8 * r;
            const float* wrow = (o < 32) ? (Wq + (size_t)o * 1024)
                              : (o < 64) ? (Wk + (size_t)(o - 32) * 1024)
                                         : (Wv + (size_t)(o - 64) * 1024);
            At[lk][lo8 + 8 * r] = wrow[col_off + k0 + lk];
        }
        #pragma unroll
        for (int r = 0; r < 8; r++)
            Bt[lk4 + 4 * r][ln] = src[((size_t)b * 256 + k0 + lk4 + 4 * r) * ns + n_base + ln];
        __syncthreads();
        #pragma unroll
        for (int kk = 0; kk < 32; kk++) {
            float4 a = *(const float4*)&At[kk][4 * tn];
            float4 bb = *(const float4*)&Bt[kk][4 * tm];
            acc[0][0] += a.x * bb.x; acc[0][1] += a.x * bb.y; acc[0][2] += a.x * bb.z; acc[0][3] += a.x * bb.w;
            acc[1][0] += a.y * bb.x; acc[1][1] += a.y * bb.y; acc[1][2] += a.y * bb.z; acc[1][3] += a.y * bb.w;
            acc[2][0] += a.z * bb.x; acc[2][1] += a.z * bb.y; acc[2][2] += a.z * bb.z; acc[2][3] += a.z * bb.w;
            acc[3][0] += a.w * bb.x; acc[3][1] += a.w * bb.y; acc[3][2] += a.w * bb.z; acc[3][3] += a.w * bb.w;
        }
    }
    #pragma unroll
    for (int i = 0; i < 4; i++)
        #pragma unroll
        for (int j = 0; j < 4; j++)
            outp[((size_t)b * 320 + o_base + 4 * tn + i) * ns + n_base + 4 * tm + j] = acc[i][j];
}

// ---------------------------------------------------------------------------
// K6M: full-res projection via bf16 MFMA. v writes go to FRAG-CONTIGUOUS
// layout: per chunk (n>>6), per frag (c16 = c>>4, khw = (k>>5)&1), the
// 64-lane MFMA A-fragment is stored contiguously in lane order:
//   addr = chunkbase + ((c16*2 + khw)*512) + (quad*16 + (c&15))*8 + (k&7)
// where quad=(k>>3)&3.  k7b then loads each A-frag with ONE perfectly
// coalesced global_load_dwordx4 (1 KB per frag) — no LDS staging for V.
// ---------------------------------------------------------------------------
__global__ __launch_bounds__(256) void k6m(
    const unsigned short* __restrict__ WB, const unsigned short* __restrict__ x2T,
    const float* __restrict__ bq, const float* __restrict__ bk, const float* __restrict__ bv,
    const float* __restrict__ P2, const float* __restrict__ P4, const float* __restrict__ P8,
    unsigned short* __restrict__ qT, unsigned short* __restrict__ kT,
    unsigned short* __restrict__ vC)
{
    const int b = blockIdx.z;
    const int obase = blockIdx.y * 64;
    const int nb = blockIdx.x * 128;
    const int t = threadIdx.x;
    const int w_ = t >> 6, lane = t & 63;
    const int quad = lane >> 4, l16 = lane & 15;
    const int nbase = nb + 32 * w_;
    f32x4 acc[4][2];
    #pragma unroll
    for (int ot = 0; ot < 4; ot++)
        #pragma unroll
        for (int nt = 0; nt < 2; nt++) { acc[ot][nt][0] = 0.f; acc[ot][nt][1] = 0.f; acc[ot][nt][2] = 0.f; acc[ot][nt][3] = 0.f; }
    const unsigned short* xb = x2T + ((size_t)b * 4096 + nbase) * 256;
    for (int k0 = 0; k0 < 256; k0 += 32) {
        FRAG af[4], bf[2];
        #pragma unroll
        for (int ot = 0; ot < 4; ot++)
            af[ot].u = *(const uint4*)(WB + (size_t)(obase + 16 * ot + l16) * 256 + k0 + quad * 8);
        #pragma unroll
        for (int nt = 0; nt < 2; nt++)
            bf[nt].u = *(const uint4*)(xb + (size_t)(16 * nt + l16) * 256 + k0 + quad * 8);
        #pragma unroll
        for (int ot = 0; ot < 4; ot++)
            #pragma unroll
            for (int nt = 0; nt < 2; nt++)
                acc[ot][nt] = __builtin_amdgcn_mfma_f32_16x16x32_bf16(af[ot].s, bf[nt].s, acc[ot][nt], 0, 0, 0);
    }
    #pragma unroll
    for (int ot = 0; ot < 4; ot++) {
        #pragma unroll
        for (int nt = 0; nt < 2; nt++) {
            int n = nbase + 16 * nt + l16;
            int h = n >> 6, wx = n & 63;
            int i2 = ((h >> 1) << 5) + (wx >> 1);
            int i4 = ((h >> 2) << 4) + (wx >> 2);
            int i8 = ((h >> 3) << 3) + (wx >> 3);
            float vals[4];
            #pragma unroll
            for (int r = 0; r < 4; r++) {
                int o = obase + 16 * ot + 4 * quad + r;
                float bias = (o < 32) ? bq[o] : (o < 64) ? bk[o - 32] : bv[o - 64];
                size_t ro = (size_t)b * 320 + o;
                vals[r] = acc[ot][nt][r] + bias
                        + P2[ro * 1024 + i2] + P4[ro * 256 + i4] + P8[ro * 64 + i8];
            }
            int o0 = obase + 16 * ot + 4 * quad;
            if (o0 < 64) {
                uint2 pk;
                pk.x = (unsigned)f2bf(vals[0]) | ((unsigned)f2bf(vals[1]) << 16);
                pk.y = (unsigned)f2bf(vals[2]) | ((unsigned)f2bf(vals[3]) << 16);
                if (o0 < 32)
                    *(uint2*)(qT + ((size_t)(b * 4096 + n)) * 32 + o0) = pk;
                else
                    *(uint2*)(kT + ((size_t)(b * 4096 + n)) * 32 + (o0 - 32)) = pk;
            } else {
                int chunk = n >> 6;
                int kk = n & 63;
                int khw_ = (kk >> 5) & 1, qd = (kk >> 3) & 3, ko = kk & 7;
                unsigned short* dst = vC + (((size_t)b * 64 + chunk) << 14);
                #pragma unroll
                for (int r = 0; r < 4; r++) {
                    int c = o0 - 64 + r;
                    dst[((((c >> 4) << 1) + khw_) << 9) + ((qd * 16 + (c & 15)) << 3) + ko] = f2bf(vals[r]);
                }
            }
        }
    }
}

// ---------------------------------------------------------------------------
// K7A: softmax stats pass (dense kT reads). XCD-aware bid decode: blocks of
// the same b land on one XCD-pair so kT_b/qT_b stay L2-resident.
// ---------------------------------------------------------------------------
__global__ __launch_bounds__(1024, 4) void k7a_stats(
    const unsigned short* __restrict__ qT, const unsigned short* __restrict__ kT,
    float* __restrict__ mout, float* __restrict__ ilout)
{
    __shared__ float sm[4][4][16], sl[4][4][16];   // [g][s][l16]
    const int bid = blockIdx.x;
    const int b = (bid >> 1) & 3;
    const int qbase = (((bid >> 3) << 1) | (bid & 1)) << 6;
    const int t = threadIdx.x;
    const int wid = t >> 6, lane = t & 63;
    const int g_ = wid >> 2, s_ = wid & 3;
    const int quad = lane >> 4, l16 = lane & 15;

    FRAG qf;
    qf.u = *(const uint4*)(qT + ((size_t)(b * 4096 + qbase + 16 * g_ + l16)) * 32 + quad * 8);
    const unsigned short* kTb = kT + (size_t)b * 4096 * 32;

    float m_run = -1e30f, l_run = 0.f;
    for (int j = 0; j < 16; j++) {
        const int mo = (s_ << 10) + (j << 6);
        f32x4 e[4];
        #pragma unroll
        for (int mt = 0; mt < 4; mt++) {
            FRAG kf;
            kf.u = *(const uint4*)(kTb + (size_t)(mo + 16 * mt + l16) * 32 + quad * 8);
            f32x4 z; z[0] = 0.f; z[1] = 0.f; z[2] = 0.f; z[3] = 0.f;
            e[mt] = __builtin_amdgcn_mfma_f32_16x16x32_bf16(kf.s, qf.s, z, 0, 0, 0);
        }
        float pm = e[0][0];
        #pragma unroll
        for (int mt = 0; mt < 4; mt++)
            #pragma unroll
            for (int r = 0; r < 4; r++) pm = fmaxf(pm, e[mt][r]);
        float mnew = fmaxf(m_run, pm);
        float al = __expf(m_run - mnew);
        float ps = 0.f;
        #pragma unroll
        for (int mt = 0; mt < 4; mt++)
            #pragma unroll
            for (int r = 0; r < 4; r++) ps += __expf(e[mt][r] - mnew);
        l_run = l_run * al + ps;
        m_run = mnew;
    }
    #pragma unroll
    for (int o = 16; o < 64; o <<= 1) {
        float mo_ = __shfl_xor(m_run, o);
        float lo_ = __shfl_xor(l_run, o);
        float m2 = fmaxf(m_run, mo_);
        l_run = l_run * __expf(m_run - m2) + lo_ * __expf(mo_ - m2);
        m_run = m2;
    }
    if (quad == 0) { sm[g_][s_][l16] = m_run; sl[g_][s_][l16] = l_run; }
    __syncthreads();
    if (t < 64) {
        int g = t >> 4, l = t & 15;
        float m0 = sm[g][0][l], m1 = sm[g][1][l], m2 = sm[g][2][l], m3 = sm[g][3][l];
        float mx = fmaxf(fmaxf(m0, m1), fmaxf(m2, m3));
        float l_ = sl[g][0][l] * __expf(m0 - mx) + sl[g][1][l] * __expf(m1 - mx)
                 + sl[g][2][l] * __expf(m2 - mx) + sl[g][3][l] * __expf(m3 - mx);
        int n = qbase + 16 * g + l;
        mout[b * 4096 + n] = mx;
        ilout[b * 4096 + n] = 1.f / l_;
    }
}

// ---------------------------------------------------------------------------
// K7B v13: v10 structure (64q block, 2-barrier pipeline, proven PL swizzle)
// at HALF the channels per block -> 2 CO-RESIDENT blocks per CU.
//  - v10's 20% occupancy was GRID-limited (256 blocks = 256 CUs), not
//    resource-limited. v12's 32q fragmentation doubled per-CU vmem; this
//    keeps 64q (V reuse intact) and splits c instead.
//  - Block = 8 waves, 64q x 128c: cw in 0..3 (32c stripes), khw in 0..1.
//    Per-wave PV acc[2][4] (32c x 64q over its 32-key half), QK identical
//    to v10 (ntq = cw). Grid 512 -> 2 blocks/CU = 4 waves/SIMD; when one
//    block drains vmcnt at a barrier, the other block computes.
//  - Co-resident blocks (bid stride 8, same XCD) share (b, csplit) ->
//    identical V-frag + kT reads each chunk: L1/L2 hits, per-CU distinct
//    traffic ~= v10. QK/exp duplicated only 2x (csplit).
//  - XCD pinning kept: b=(bid>>1)&3, csplit=bid&1 -> each XCD owns one
//    (b, c-half): 1MB vC-half + 1MB kT, L2-resident (FETCH 45.7->14.5MB
//    proven in v11/v12).
// LDS: PL[2][64][64] 16KB + SB[128][68] 34.8KB = 50.8KB x2 blocks = 101.6KB.
// ---------------------------------------------------------------------------
__global__ __launch_bounds__(512, 4) void k7b_attn(
    const unsigned short* __restrict__ qT, const unsigned short* __restrict__ kT,
    const unsigned short* __restrict__ vC, const float* __restrict__ mstat,
    const float* __restrict__ ilstat, const float* __restrict__ x2,
    const float* __restrict__ gamma, float* __restrict__ outp)
{
    __shared__ __align__(16) unsigned short PL[2][64][64];  // 16 KB swizzled P
    __shared__ __align__(16) float SB[128][68];             // 34.8 KB combine buffer
    const int bid = blockIdx.x;
    const int b = (bid >> 1) & 3;
    const int csplit = bid & 1;
    const int qbase = (bid >> 3) << 6;      // 64 q-cols per block
    const int t = threadIdx.x;
    const int wid = t >> 6, lane = t & 63;
    const int cw = wid & 3, khw = wid >> 2;
    const int quad = lane >> 4, l16 = lane & 15;
    const int ntq = cw;                     // QK n-tile of this wave
    const int mt0 = 2 * khw, mt1 = 2 * khw + 1;
    const int nq = qbase + 16 * ntq + l16;  // q-column of this wave's P rows

    FRAG qf;
    qf.u = *(const uint4*)(qT + ((size_t)(b * 4096 + nq)) * 32 + quad * 8);
    const float mN = mstat[b * 4096 + nq];

    f32x4 acc[2][4];
    #pragma unroll
    for (int ct = 0; ct < 2; ct++)
        #pragma unroll
        for (int nt = 0; nt < 4; nt++) { acc[ct][nt][0] = 0.f; acc[ct][nt][1] = 0.f; acc[ct][nt][2] = 0.f; acc[ct][nt][3] = 0.f; }
    const unsigned short* kTb = kT + (size_t)b * 4096 * 32;
    // per-wave V-frag base: frag (c16 = 8*csplit + 2*cw + ct, khw), lane-contig.
    const unsigned short* vfb = vC + ((size_t)b * 64 << 14)
                              + ((((8 * csplit + 2 * cw) << 1) + khw) << 9) + lane * 8;

    // PL swizzle (v10-proven): row = 64 shorts = 128 B = 8 granules of 16 B;
    // phys_granule = logical ^ (l16 & 7).
    const int po  = 4 * (quad & 1);
    const int pg0 = ((4 * khw + (quad >> 1)) ^ (l16 & 7));        // pkA granule
    const int pg1 = pg0 ^ 2;                                       // pkB granule
    const int pgr = ((4 * khw + quad) ^ (l16 & 7)) << 3;          // bp read offset

    FRAG avA[2], avB[2], kcA0, kcA1, kcB0, kcB1;

#define AV_LOAD(AV, CH) do { \
    const unsigned short* vfj = vfb + ((size_t)(CH) << 14); \
    AV[0].u = *(const uint4*)(vfj); \
    AV[1].u = *(const uint4*)(vfj + 1024); \
} while (0)

#define KC_LOAD(K0, K1, CH) do { \
    const int mo_ = (CH) << 6; \
    K0.u = *(const uint4*)(kTb + (size_t)(mo_ + 16 * mt0 + l16) * 32 + quad * 8); \
    K1.u = *(const uint4*)(kTb + (size_t)(mo_ + 16 * mt1 + l16) * 32 + quad * 8); \
} while (0)

// QK for this wave's (ntq, khw) -> PL rows 16*ntq + l16, its khw columns.
#define QK_STORE(DST, K0, K1) do { \
    f32x4 z; z[0] = 0.f; z[1] = 0.f; z[2] = 0.f; z[3] = 0.f; \
    f32x4 e0 = __builtin_amdgcn_mfma_f32_16x16x32_bf16(K0.s, qf.s, z, 0, 0, 0); \
    f32x4 e1 = __builtin_amdgcn_mfma_f32_16x16x32_bf16(K1.s, qf.s, z, 0, 0, 0); \
    union { float f; unsigned int u; } p0, p1, p2, p3; \
    uint2 pkA, pkB; \
    p0.f = __expf(e0[0] - mN); p1.f = __expf(e0[1] - mN); \
    p2.f = __expf(e0[2] - mN); p3.f = __expf(e0[3] - mN); \
    pkA.x = __builtin_amdgcn_perm(p1.u, p0.u, 0x07060302u); \
    pkA.y = __builtin_amdgcn_perm(p3.u, p2.u, 0x07060302u); \
    p0.f = __expf(e1[0] - mN); p1.f = __expf(e1[1] - mN); \
    p2.f = __expf(e1[2] - mN); p3.f = __expf(e1[3] - mN); \
    pkB.x = __builtin_amdgcn_perm(p1.u, p0.u, 0x07060302u); \
    pkB.y = __builtin_amdgcn_perm(p3.u, p2.u, 0x07060302u); \
    unsigned short* rw = &PL[DST][16 * ntq + l16][po]; \
    *(uint2*)(rw + pg0 * 8) = pkA; \
    *(uint2*)(rw + pg1 * 8) = pkB; \
} while (0)

#define PV_STEP(AV, CUR) do { \
    FRAG bp[4]; \
    _Pragma("unroll") \
    for (int nt_ = 0; nt_ < 4; nt_++) \
        bp[nt_].u = *(const uint4*)&PL[CUR][16 * nt_ + l16][pgr]; \
    __builtin_amdgcn_s_setprio(1); \
    _Pragma("unroll") \
    for (int ct_ = 0; ct_ < 2; ct_++) { \
        _Pragma("unroll") \
        for (int nt_ = 0; nt_ < 4; nt_++) \
            acc[ct_][nt_] = __builtin_amdgcn_mfma_f32_16x16x32_bf16(AV[ct_].s, bp[nt_].s, acc[ct_][nt_], 0, 0, 0); \
    } \
    __builtin_amdgcn_s_setprio(0); \
} while (0)

    // --- prologue: av(0); kc(0); QK(0)->PL[0]; kc(1) ---
    AV_LOAD(avA, 0);
    KC_LOAD(kcA0, kcA1, 0);
    QK_STORE(0, kcA0, kcA1);
    KC_LOAD(kcB0, kcB1, 1);

    for (int jj = 0; jj < 32; jj++) {
        const int j = 2 * jj;
        // ---- phase A: compute PV(j) [even chunk], prefetch j+1 ----
        __syncthreads();
        {
            if (j < 63) AV_LOAD(avB, j + 1);
            QK_STORE(1, kcB0, kcB1);                 // chunk j+1 (j <= 62 always)
            if (j < 62) KC_LOAD(kcA0, kcA1, j + 2);
        }
        PV_STEP(avA, 0);
        // ---- phase B: compute PV(j+1) [odd chunk], prefetch j+2 ----
        __syncthreads();
        if (j < 62) {
            AV_LOAD(avA, j + 2);
            QK_STORE(0, kcA0, kcA1);                 // chunk j+2
            if (j < 61) KC_LOAD(kcB0, kcB1, j + 3);
        }
        PV_STEP(avB, 1);
    }
#undef AV_LOAD
#undef KC_LOAD
#undef QK_STORE
#undef PV_STEP

    // --- epilogue: combine khw halves via SB (single round: 128 rows) ---
    const float gm = gamma[0];
    __syncthreads();
    if (khw == 0) {
        #pragma unroll
        for (int ct = 0; ct < 2; ct++)
            #pragma unroll
            for (int nt = 0; nt < 4; nt++)
                #pragma unroll
                for (int r = 0; r < 4; r++)
                    SB[32 * cw + 16 * ct + 4 * quad + r][16 * nt + l16] = acc[ct][nt][r];
    }
    __syncthreads();
    if (khw == 1) {
        #pragma unroll
        for (int ct = 0; ct < 2; ct++)
            #pragma unroll
            for (int nt = 0; nt < 4; nt++)
                #pragma unroll
                for (int r = 0; r < 4; r++)
                    SB[32 * cw + 16 * ct + 4 * quad + r][16 * nt + l16] += acc[ct][nt][r];
    }
    __syncthreads();
    // cooperative store: 128c x 64n with 512 threads, 4 passes of float4
    #pragma unroll
    for (int pass = 0; pass < 4; pass++) {
        int cl = (t >> 4) + 32 * pass;
        int n4 = (t & 15) * 4;
        float4 vv = *(float4*)&SB[cl][n4];
        float4 il4 = *(const float4*)(ilstat + (size_t)b * 4096 + qbase + n4);
        size_t idx = ((size_t)(b * 256 + 128 * csplit + cl)) * 4096 + qbase + n4;
        float4 xv = *(const float4*)(x2 + idx);
        float4 ov;
        ov.x = gm * vv.x * il4.x + xv.x;
        ov.y = gm * vv.y * il4.y + xv.y;
        ov.z = gm * vv.z * il4.z + xv.z;
        ov.w = gm * vv.w * il4.w + xv.w;
        *(float4*)(outp + idx) = ov;
    }
}

// ---------------------------------------------------------------------------
extern "C" void kernel_launch(void* const* d_in, const int* in_sizes, int n_in,
                              void* d_out, int out_size, void* d_ws, size_t ws_size,
                              hipStream_t stream) {
    (void)in_sizes; (void)n_in; (void)out_size; (void)ws_size;
    const float* x    = (const float*)d_in[0];
    const float* W1   = (const float*)d_in[1];
    const float* b1   = (const float*)d_in[2];
    const float* W2   = (const float*)d_in[3];
    const float* b2   = (const float*)d_in[4];
    const float* Wq   = (const float*)d_in[5];
    const float* bq   = (const float*)d_in[6];
    const float* Wk   = (const float*)d_in[7];
    const float* bk   = (const float*)d_in[8];
    const float* Wv   = (const float*)d_in[9];
    const float* bv   = (const float*)d_in[10];
    const float* gam  = (const float*)d_in[11];
    const float* Wsp  = (const float*)d_in[12];
    const float* bn_g = (const float*)d_in[13];
    const float* bn_b = (const float*)d_in[14];
    const float* bn_m = (const float*)d_in[15];
    const float* bn_v = (const float*)d_in[16];

    float* ws = (float*)d_ws;
    float* bm2   = ws; ws += (size_t)4 * 256 * 1024;
    float* bm4   = ws; ws += (size_t)4 * 256 * 256;
    float* bm8   = ws; ws += (size_t)4 * 256 * 64;
    float* featA = ws; ws += 1024;
    float* fm1   = ws; ws += 1024;
    float* fm2   = ws; ws += 1024;
    float* fm4   = ws; ws += 1024;
    float* fm8   = ws; ws += 1024;
    float* g     = ws; ws += 1024;
    float* comp  = ws; ws += (size_t)4 * 2 * 4096;
    float* spg   = ws; ws += (size_t)4 * 4096;
    float* x2    = ws; ws += (size_t)4 * 256 * 4096;
    float* bm2b  = ws; ws += (size_t)4 * 256 * 1024;
    float* bm4b  = ws; ws += (size_t)4 * 256 * 256;
    float* bm8b  = ws; ws += (size_t)4 * 256 * 64;
    float* P2    = ws; ws += (size_t)4 * 320 * 1024;
    float* P4    = ws; ws += (size_t)4 * 320 * 256;
    float* P8    = ws; ws += (size_t)4 * 320 * 64;
    float* mstat = ws; ws += (size_t)4 * 4096;
    float* ilstat= ws; ws += (size_t)4 * 4096;
    unsigned short* qT  = (unsigned short*)ws; ws += (size_t)4 * 4096 * 32 / 2;
    unsigned short* kT  = (unsigned short*)ws; ws += (size_t)4 * 4096 * 32 / 2;
    unsigned short* vCp = (unsigned short*)ws; ws += (size_t)4 * 64 * 16384 / 2;
    unsigned short* x2T = (unsigned short*)ws; ws += (size_t)4 * 4096 * 256 / 2;
    unsigned short* WB  = (unsigned short*)ws; ws += (size_t)320 * 256 / 2;

    // Weight cast (no deps)
    k_wcast<<<320, 256, 0, stream>>>(Wq, Wk, Wv, WB);
    // Stage 1: channel gate
    k_pyramid<<<1024, 256, 0, stream>>>(x, nullptr, nullptr, nullptr,
                                        bm2, bm4, bm8, featA, fm1, fm2, fm4, fm8, 0);
    k2_gate<<<4, 256, 0, stream>>>(featA, fm1, fm2, fm4, fm8, W1, b1, W2, b2, g);
    // Stage 2: spatial gate
    k3_comp<<<256, 256, 0, stream>>>(x, bm2, bm4, bm8, g, comp);
    k4_spgate<<<256, 64, 0, stream>>>(comp, Wsp, bn_g, bn_b, bn_m, bn_v, spg);
    k_pyramid<<<1024, 256, 0, stream>>>(x, g, spg, x2,
                                        bm2b, bm4b, bm8b,
                                        nullptr, nullptr, nullptr, nullptr, nullptr, 1);
    // x2 -> bf16 transposed [n][c]
    k_x2t<<<dim3(64, 4, 4), 256, 0, stream>>>(x2, x2T);
    // Stage 3: q/k/v projections, multiscale-decomposed (single low-res launch)
    k6_gemm<<<dim3(21, 5, 4), 256, 0, stream>>>(Wq, Wk, Wv, bm2b, bm4b, bm8b, P2, P4, P8);
    k6m<<<dim3(32, 5, 4), 256, 0, stream>>>(WB, x2T, bq, bk, bv, P2, P4, P8, qT, kT, vCp);
    // Two-pass attention: stats, then 2-blocks/CU pipelined PV
    k7a_stats<<<256, 1024, 0, stream>>>(qT, kT, mstat, ilstat);
    k7b_attn<<<512, 512, 0, stream>>>(qT, kT, vCp, mstat, ilstat, x2, gam, (float*)d_out);
}

// Round 7
// 276.528 us; speedup vs baseline: 1.0451x; 1.0071x over previous
//
#include <hip/hip_runtime.h>
#include <math.h>

// Shapes (fixed): B=4, C=256, H=W=64, N=4096, 4C=1024, c8=32, r=16.

typedef float f32x4 __attribute__((ext_vector_type(4)));
typedef short s16x8 __attribute__((ext_vector_type(8)));
union FRAG { uint4 u; s16x8 s; };

__device__ __forceinline__ unsigned short f2bf(float f) {
    union { float f; unsigned int u; } v; v.f = f;
    unsigned int r = v.u + 0x7FFFu + ((v.u >> 16) & 1u);
    return (unsigned short)(r >> 16);
}

// ---------------------------------------------------------------------------
// K1/K5: per-(b,c) plane -> block-mean pyramid (+ feats in mode 0, x2 in mode 1)
// ---------------------------------------------------------------------------
__global__ __launch_bounds__(256) void k_pyramid(
    const float* __restrict__ xin, const float* __restrict__ gch,
    const float* __restrict__ spg, float* __restrict__ x2out,
    float* __restrict__ bm2, float* __restrict__ bm4, float* __restrict__ bm8,
    float* __restrict__ featA, float* __restrict__ fm1, float* __restrict__ fm2,
    float* __restrict__ fm4, float* __restrict__ fm8, int mode)
{
    __shared__ float sx[4096];
    __shared__ float s2[1024];
    __shared__ float s4[256];
    __shared__ float wred[4][8];
    const int bc = blockIdx.x;
    const int b = bc >> 8;
    const int t = threadIdx.x;
    const float* xp = xin + (size_t)bc * 4096;
    float gc = 1.f;
    if (mode == 1) gc = gch[bc];
    float sum = 0.f, mx = -1e30f;
    for (int r = 0; r < 4; r++) {
        int i4 = t + 256 * r;
        float4 v = ((const float4*)xp)[i4];
        if (mode == 1) {
            float4 sg = ((const float4*)(spg + (size_t)b * 4096))[i4];
            v.x *= gc * sg.x; v.y *= gc * sg.y; v.z *= gc * sg.z; v.w *= gc * sg.w;
            ((float4*)(x2out + (size_t)bc * 4096))[i4] = v;
        } else {
            sum += v.x + v.y + v.z + v.w;
            mx = fmaxf(mx, fmaxf(fmaxf(v.x, v.y), fmaxf(v.z, v.w)));
        }
        ((float4*)sx)[i4] = v;
    }
    __syncthreads();
    float mx2 = -1e30f;
    for (int r = 0; r < 4; r++) {
        int i = t + 256 * r;
        int r2 = i >> 5, c2 = i & 31;
        int p0 = 128 * r2 + 2 * c2;
        float v = 0.25f * (sx[p0] + sx[p0 + 1] + sx[p0 + 64] + sx[p0 + 65]);
        s2[i] = v;
        bm2[(size_t)bc * 1024 + i] = v;
        mx2 = fmaxf(mx2, v);
    }
    __syncthreads();
    float mx4;
    {
        int r4 = t >> 4, c4 = t & 15;
        int p0 = 64 * r4 + 2 * c4;
        float v = 0.25f * (s2[p0] + s2[p0 + 1] + s2[p0 + 32] + s2[p0 + 33]);
        s4[t] = v;
        bm4[(size_t)bc * 256 + t] = v;
        mx4 = v;
    }
    __syncthreads();
    float mx8 = -1e30f;
    if (t < 64) {
        int r8 = t >> 3, c8 = t & 7;
        int p0 = 32 * r8 + 2 * c8;
        float v = 0.25f * (s4[p0] + s4[p0 + 1] + s4[p0 + 16] + s4[p0 + 17]);
        bm8[(size_t)bc * 64 + t] = v;
        mx8 = v;
    }
    if (mode == 0) {
        float vs = sum, v1 = mx, v2 = mx2, v4 = mx4, v8 = mx8;
        #pragma unroll
        for (int o = 1; o < 64; o <<= 1) {
            vs += __shfl_xor(vs, o);
            v1 = fmaxf(v1, __shfl_xor(v1, o));
            v2 = fmaxf(v2, __shfl_xor(v2, o));
            v4 = fmaxf(v4, __shfl_xor(v4, o));
            v8 = fmaxf(v8, __shfl_xor(v8, o));
        }
        if ((t & 63) == 0) {
            int wd = t >> 6;
            wred[wd][0] = vs; wred[wd][1] = v1; wred[wd][2] = v2;
            wred[wd][3] = v4; wred[wd][4] = v8;
        }
        __syncthreads();
        if (t == 0) featA[bc] = (wred[0][0] + wred[1][0] + wred[2][0] + wred[3][0]) * (1.f / 4096.f);
        else if (t == 1) fm1[bc] = fmaxf(fmaxf(wred[0][1], wred[1][1]), fmaxf(wred[2][1], wred[3][1]));
        else if (t == 2) fm2[bc] = fmaxf(fmaxf(wred[0][2], wred[1][2]), fmaxf(wred[2][2], wred[3][2]));
        else if (t == 3) fm4[bc] = fmaxf(fmaxf(wred[0][3], wred[1][3]), fmaxf(wred[2][3], wred[3][3]));
        else if (t == 4) fm8[bc] = fmaxf(fmaxf(wred[0][4], wred[1][4]), fmaxf(wred[2][4], wred[3][4]));
    }
}

// ---------------------------------------------------------------------------
// K2: channel-gate MLP
// ---------------------------------------------------------------------------
__global__ __launch_bounds__(256) void k2_gate(
    const float* __restrict__ featA, const float* __restrict__ fm1,
    const float* __restrict__ fm2, const float* __restrict__ fm4, const float* __restrict__ fm8,
    const float* __restrict__ W1, const float* __restrict__ b1,
    const float* __restrict__ W2, const float* __restrict__ b2,
    float* __restrict__ g)
{
    __shared__ float sf[5][256];
    __shared__ float sh[5][16];
    __shared__ float hs[16];
    const int b = blockIdx.x, t = threadIdx.x;
    sf[0][t] = featA[b * 256 + t];
    sf[1][t] = fm1[b * 256 + t];
    sf[2][t] = fm2[b * 256 + t];
    sf[3][t] = fm4[b * 256 + t];
    sf[4][t] = fm8[b * 256 + t];
    __syncthreads();
    if (t < 80) {
        int f = t / 16, j = t % 16;
        float a = b1[j];
        for (int c = 0; c < 256; c++) a += sf[f][c] * W1[c * 16 + j];
        sh[f][j] = fmaxf(a, 0.f);
    }
    __syncthreads();
    if (t < 16) hs[t] = 4.f * sh[0][t] + sh[1][t] + sh[2][t] + sh[3][t] + sh[4][t];
    __syncthreads();
    float a = 8.f * b2[t];
    for (int j = 0; j < 16; j++) a += hs[j] * W2[j * 256 + t];
    g[b * 256 + t] = 1.f / (1.f + __expf(-a));
}

// ---------------------------------------------------------------------------
// K3: spatial-gate input. Grid 256: block = (b, 64-pixel chunk); 4 waves
// split the 256 channels; LDS cross-wave reduce.
// ---------------------------------------------------------------------------
__global__ __launch_bounds__(256) void k3_comp(
    const float* __restrict__ x, const float* __restrict__ bm2,
    const float* __restrict__ bm4, const float* __restrict__ bm8,
    const float* __restrict__ g, float* __restrict__ comp)
{
    __shared__ float sg[256];
    __shared__ float rmx[4][64];
    __shared__ float rsm[4][64];
    const int b = blockIdx.x >> 6;
    const int pix = ((blockIdx.x & 63) << 6) + (threadIdx.x & 63);
    const int wid = threadIdx.x >> 6;
    const int c0 = wid << 6;
    sg[threadIdx.x] = g[(b << 8) + threadIdx.x];
    __syncthreads();
    const int h = pix >> 6, w = pix & 63;
    const int i2 = ((h >> 1) << 5) + (w >> 1);
    const int i4 = ((h >> 2) << 4) + (w >> 2);
    const int i8 = ((h >> 3) << 3) + (w >> 3);
    const float* xb = x + ((size_t)b << 8) * 4096;
    const float* p2 = bm2 + ((size_t)b << 8) * 1024;
    const float* p4 = bm4 + ((size_t)b << 8) * 256;
    const float* p8 = bm8 + ((size_t)b << 8) * 64;
    float mx = -1e30f, sm = 0.f;
    for (int c = c0; c < c0 + 64; c++) {
        float gc = sg[c];
        float xv = xb[(size_t)c * 4096 + pix] * gc;
        float v2 = p2[c * 1024 + i2] * gc;
        float v4 = p4[c * 256 + i4] * gc;
        float v8 = p8[c * 64 + i8] * gc;
        mx = fmaxf(fmaxf(mx, xv), fmaxf(fmaxf(v2, v4), v8));
        sm += xv + v2 + v4 + v8;
    }
    rmx[wid][threadIdx.x & 63] = mx;
    rsm[wid][threadIdx.x & 63] = sm;
    __syncthreads();
    if (wid == 0) {
        int l = threadIdx.x;
        float m = fmaxf(fmaxf(rmx[0][l], rmx[1][l]), fmaxf(rmx[2][l], rmx[3][l]));
        float s = rsm[0][l] + rsm[1][l] + rsm[2][l] + rsm[3][l];
        comp[((size_t)b * 2) * 4096 + pix] = m;
        comp[((size_t)b * 2 + 1) * 4096 + pix] = s * (1.f / 1024.f);
    }
}

// ---------------------------------------------------------------------------
// K4: 7x7 conv (2->1, pad 3, no bias) + BN(eval) + sigmoid. Grid 256 x 64thr.
// ---------------------------------------------------------------------------
__global__ __launch_bounds__(64) void k4_spgate(
    const float* __restrict__ comp, const float* __restrict__ Wsp,
    const float* __restrict__ bn_g, const float* __restrict__ bn_b,
    const float* __restrict__ bn_m, const float* __restrict__ bn_v,
    float* __restrict__ spg)
{
    __shared__ float w[98];
    const int t = threadIdx.x;
    for (int i = t; i < 98; i += 64) w[i] = Wsp[i];
    __syncthreads();
    const int b = blockIdx.x >> 6;
    const int pix = ((blockIdx.x & 63) << 6) + t;
    const int h = pix >> 6, wx = pix & 63;
    const float* c0 = comp + (size_t)b * 2 * 4096;
    float acc = 0.f;
    for (int ci = 0; ci < 2; ci++)
        for (int kh = 0; kh < 7; kh++) {
            int hh = h + kh - 3;
            if (hh < 0 || hh >= 64) continue;
            for (int kw = 0; kw < 7; kw++) {
                int wwp = wx + kw - 3;
                if (wwp < 0 || wwp >= 64) continue;
                acc += c0[ci * 4096 + hh * 64 + wwp] * w[ci * 49 + kh * 7 + kw];
            }
        }
    float sc = rsqrtf(bn_v[0] + 1e-5f) * bn_g[0];
    float sp = (acc - bn_m[0]) * sc + bn_b[0];
    spg[b * 4096 + pix] = 1.f / (1.f + __expf(-sp));
}

// ---------------------------------------------------------------------------
// K_WCAST: bf16 copy of W[:,768:1024] rows (q|k|v order) -> WB[320][256]
// ---------------------------------------------------------------------------
__global__ __launch_bounds__(256) void k_wcast(
    const float* __restrict__ Wq, const float* __restrict__ Wk, const float* __restrict__ Wv,
    unsigned short* __restrict__ WB)
{
    const int o = blockIdx.x;
    const int t = threadIdx.x;
    const float* row = (o < 32) ? (Wq + (size_t)o * 1024)
                      : (o < 64) ? (Wk + (size_t)(o - 32) * 1024)
                                 : (Wv + (size_t)(o - 64) * 1024);
    WB[o * 256 + t] = f2bf(row[768 + t]);
}

// ---------------------------------------------------------------------------
// K_X2T: x2 fp32 [b][256 c][4096 n] -> x2T bf16 [b][4096 n][256 c]
// ---------------------------------------------------------------------------
__global__ __launch_bounds__(256) void k_x2t(
    const float* __restrict__ x2, unsigned short* __restrict__ x2T)
{
    __shared__ unsigned short T[64][72];
    const int b = blockIdx.z;
    const int cb = blockIdx.y * 64;
    const int nb = blockIdx.x * 64;
    const int t = threadIdx.x;
    #pragma unroll
    for (int r = 0; r < 16; r++) {
        int cl = (t >> 6) + 4 * r;
        int nl = t & 63;
        float v = x2[((size_t)(b * 256 + cb + cl)) * 4096 + nb + nl];
        T[nl][cl] = f2bf(v);
    }
    __syncthreads();
    #pragma unroll
    for (int pass = 0; pass < 4; pass++) {
        int nl = (t >> 4) + 16 * pass;
        int c4 = (t & 15) * 4;
        uint2 pk;
        pk.x = (unsigned)T[nl][c4] | ((unsigned)T[nl][c4 + 1] << 16);
        pk.y = (unsigned)T[nl][c4 + 2] | ((unsigned)T[nl][c4 + 3] << 16);
        *(uint2*)(x2T + ((size_t)(b * 4096 + nb + nl)) * 256 + cb + c4) = pk;
    }
}

// ---------------------------------------------------------------------------
// K6: fp32 projection GEMM for low-res P2/P4/P8, all three scales in ONE
// launch: blockIdx.x 0..15 -> P2, 16..19 -> P4, 20 -> P8.
// ---------------------------------------------------------------------------
__global__ __launch_bounds__(256) void k6_gemm(
    const float* __restrict__ Wq, const float* __restrict__ Wk, const float* __restrict__ Wv,
    const float* __restrict__ bm2b, const float* __restrict__ bm4b, const float* __restrict__ bm8b,
    float* __restrict__ P2, float* __restrict__ P4, float* __restrict__ P8)
{
    __shared__ float At[32][68];
    __shared__ float Bt[32][64];
    const int bx = blockIdx.x;
    int col_off, ns, nb;
    const float* src;
    float* outp;
    if (bx < 16)      { col_off = 0;   src = bm2b; ns = 1024; outp = P2; nb = bx; }
    else if (bx < 20) { col_off = 256; src = bm4b; ns = 256;  outp = P4; nb = bx - 16; }
    else              { col_off = 512; src = bm8b; ns = 64;   outp = P8; nb = 0; }
    const int b = blockIdx.z;
    const int o_base = blockIdx.y * 64;
    const int n_base = nb * 64;
    const int t = threadIdx.x;
    const int tn = t >> 4, tm = t & 15;
    const int lk = t & 31, lo8 = t >> 5;
    const int ln = t & 63, lk4 = t >> 6;
    float acc[4][4];
    #pragma unroll
    for (int i = 0; i < 4; i++)
        #pragma unroll
        for (int j = 0; j < 4; j++) acc[i][j] = 0.f;
    for (int k0 = 0; k0 < 256; k0 += 32) {
        __syncthreads();
        #pragma unroll
        for (int r = 0; r < 8; r++) {
            int o = o_base + lo8 + 8 * r;
            const float* wrow = (o < 32) ? (Wq + (size_t)o * 1024)
                              : (o < 64) ? (Wk + (size_t)(o - 32) * 1024)
                                         : (Wv + (size_t)(o - 64) * 1024);
            At[lk][lo8 + 8 * r] = wrow[col_off + k0 + lk];
        }
        #pragma unroll
        for (int r = 0; r < 8; r++)
            Bt[lk4 + 4 * r][ln] = src[((size_t)b * 256 + k0 + lk4 + 4 * r) * ns + n_base + ln];
        __syncthreads();
        #pragma unroll
        for (int kk = 0; kk < 32; kk++) {
            float4 a = *(const float4*)&At[kk][4 * tn];
            float4 bb = *(const float4*)&Bt[kk][4 * tm];
            acc[0][0] += a.x * bb.x; acc[0][1] += a.x * bb.y; acc[0][2] += a.x * bb.z; acc[0][3] += a.x * bb.w;
            acc[1][0] += a.y * bb.x; acc[1][1] += a.y * bb.y; acc[1][2] += a.y * bb.z; acc[1][3] += a.y * bb.w;
            acc[2][0] += a.z * bb.x; acc[2][1] += a.z * bb.y; acc[2][2] += a.z * bb.z; acc[2][3] += a.z * bb.w;
            acc[3][0] += a.w * bb.x; acc[3][1] += a.w * bb.y; acc[3][2] += a.w * bb.z; acc[3][3] += a.w * bb.w;
        }
    }
    #pragma unroll
    for (int i = 0; i < 4; i++)
        #pragma unroll
        for (int j = 0; j < 4; j++)
            outp[((size_t)b * 320 + o_base + 4 * tn + i) * ns + n_base + 4 * tm + j] = acc[i][j];
}

// ---------------------------------------------------------------------------
// K6M: full-res projection via bf16 MFMA. v writes go to FRAG-CONTIGUOUS
// layout: per chunk (n>>6), per frag (c16 = c>>4, khw = (k>>5)&1), the
// 64-lane MFMA A-fragment is stored contiguously in lane order:
//   addr = chunkbase + ((c16*2 + khw)*512) + (quad*16 + (c&15))*8 + (k&7)
// where quad=(k>>3)&3.  k7b then loads each A-frag with ONE perfectly
// coalesced global_load_dwordx4 (1 KB per frag) — no LDS staging for V.
// ---------------------------------------------------------------------------
__global__ __launch_bounds__(256) void k6m(
    const unsigned short* __restrict__ WB, const unsigned short* __restrict__ x2T,
    const float* __restrict__ bq, const float* __restrict__ bk, const float* __restrict__ bv,
    const float* __restrict__ P2, const float* __restrict__ P4, const float* __restrict__ P8,
    unsigned short* __restrict__ qT, unsigned short* __restrict__ kT,
    unsigned short* __restrict__ vC)
{
    const int b = blockIdx.z;
    const int obase = blockIdx.y * 64;
    const int nb = blockIdx.x * 128;
    const int t = threadIdx.x;
    const int w_ = t >> 6, lane = t & 63;
    const int quad = lane >> 4, l16 = lane & 15;
    const int nbase = nb + 32 * w_;
    f32x4 acc[4][2];
    #pragma unroll
    for (int ot = 0; ot < 4; ot++)
        #pragma unroll
        for (int nt = 0; nt < 2; nt++) { acc[ot][nt][0] = 0.f; acc[ot][nt][1] = 0.f; acc[ot][nt][2] = 0.f; acc[ot][nt][3] = 0.f; }
    const unsigned short* xb = x2T + ((size_t)b * 4096 + nbase) * 256;
    for (int k0 = 0; k0 < 256; k0 += 32) {
        FRAG af[4], bf[2];
        #pragma unroll
        for (int ot = 0; ot < 4; ot++)
            af[ot].u = *(const uint4*)(WB + (size_t)(obase + 16 * ot + l16) * 256 + k0 + quad * 8);
        #pragma unroll
        for (int nt = 0; nt < 2; nt++)
            bf[nt].u = *(const uint4*)(xb + (size_t)(16 * nt + l16) * 256 + k0 + quad * 8);
        #pragma unroll
        for (int ot = 0; ot < 4; ot++)
            #pragma unroll
            for (int nt = 0; nt < 2; nt++)
                acc[ot][nt] = __builtin_amdgcn_mfma_f32_16x16x32_bf16(af[ot].s, bf[nt].s, acc[ot][nt], 0, 0, 0);
    }
    #pragma unroll
    for (int ot = 0; ot < 4; ot++) {
        #pragma unroll
        for (int nt = 0; nt < 2; nt++) {
            int n = nbase + 16 * nt + l16;
            int h = n >> 6, wx = n & 63;
            int i2 = ((h >> 1) << 5) + (wx >> 1);
            int i4 = ((h >> 2) << 4) + (wx >> 2);
            int i8 = ((h >> 3) << 3) + (wx >> 3);
            float vals[4];
            #pragma unroll
            for (int r = 0; r < 4; r++) {
                int o = obase + 16 * ot + 4 * quad + r;
                float bias = (o < 32) ? bq[o] : (o < 64) ? bk[o - 32] : bv[o - 64];
                size_t ro = (size_t)b * 320 + o;
                vals[r] = acc[ot][nt][r] + bias
                        + P2[ro * 1024 + i2] + P4[ro * 256 + i4] + P8[ro * 64 + i8];
            }
            int o0 = obase + 16 * ot + 4 * quad;
            if (o0 < 64) {
                uint2 pk;
                pk.x = (unsigned)f2bf(vals[0]) | ((unsigned)f2bf(vals[1]) << 16);
                pk.y = (unsigned)f2bf(vals[2]) | ((unsigned)f2bf(vals[3]) << 16);
                if (o0 < 32)
                    *(uint2*)(qT + ((size_t)(b * 4096 + n)) * 32 + o0) = pk;
                else
                    *(uint2*)(kT + ((size_t)(b * 4096 + n)) * 32 + (o0 - 32)) = pk;
            } else {
                int chunk = n >> 6;
                int kk = n & 63;
                int khw_ = (kk >> 5) & 1, qd = (kk >> 3) & 3, ko = kk & 7;
                unsigned short* dst = vC + (((size_t)b * 64 + chunk) << 14);
                #pragma unroll
                for (int r = 0; r < 4; r++) {
                    int c = o0 - 64 + r;
                    dst[((((c >> 4) << 1) + khw_) << 9) + ((qd * 16 + (c & 15)) << 3) + ko] = f2bf(vals[r]);
                }
            }
        }
    }
}

// ---------------------------------------------------------------------------
// K7A: softmax stats pass (dense kT reads). XCD-aware bid decode: blocks of
// the same b land on one XCD-pair so kT_b/qT_b stay L2-resident.
// ---------------------------------------------------------------------------
__global__ __launch_bounds__(1024, 4) void k7a_stats(
    const unsigned short* __restrict__ qT, const unsigned short* __restrict__ kT,
    float* __restrict__ mout, float* __restrict__ ilout)
{
    __shared__ float sm[4][4][16], sl[4][4][16];   // [g][s][l16]
    const int bid = blockIdx.x;
    const int b = (bid >> 1) & 3;
    const int qbase = (((bid >> 3) << 1) | (bid & 1)) << 6;
    const int t = threadIdx.x;
    const int wid = t >> 6, lane = t & 63;
    const int g_ = wid >> 2, s_ = wid & 3;
    const int quad = lane >> 4, l16 = lane & 15;

    FRAG qf;
    qf.u = *(const uint4*)(qT + ((size_t)(b * 4096 + qbase + 16 * g_ + l16)) * 32 + quad * 8);
    const unsigned short* kTb = kT + (size_t)b * 4096 * 32;

    float m_run = -1e30f, l_run = 0.f;
    for (int j = 0; j < 16; j++) {
        const int mo = (s_ << 10) + (j << 6);
        f32x4 e[4];
        #pragma unroll
        for (int mt = 0; mt < 4; mt++) {
            FRAG kf;
            kf.u = *(const uint4*)(kTb + (size_t)(mo + 16 * mt + l16) * 32 + quad * 8);
            f32x4 z; z[0] = 0.f; z[1] = 0.f; z[2] = 0.f; z[3] = 0.f;
            e[mt] = __builtin_amdgcn_mfma_f32_16x16x32_bf16(kf.s, qf.s, z, 0, 0, 0);
        }
        float pm = e[0][0];
        #pragma unroll
        for (int mt = 0; mt < 4; mt++)
            #pragma unroll
            for (int r = 0; r < 4; r++) pm = fmaxf(pm, e[mt][r]);
        float mnew = fmaxf(m_run, pm);
        float al = __expf(m_run - mnew);
        float ps = 0.f;
        #pragma unroll
        for (int mt = 0; mt < 4; mt++)
            #pragma unroll
            for (int r = 0; r < 4; r++) ps += __expf(e[mt][r] - mnew);
        l_run = l_run * al + ps;
        m_run = mnew;
    }
    #pragma unroll
    for (int o = 16; o < 64; o <<= 1) {
        float mo_ = __shfl_xor(m_run, o);
        float lo_ = __shfl_xor(l_run, o);
        float m2 = fmaxf(m_run, mo_);
        l_run = l_run * __expf(m_run - m2) + lo_ * __expf(mo_ - m2);
        m_run = m2;
    }
    if (quad == 0) { sm[g_][s_][l16] = m_run; sl[g_][s_][l16] = l_run; }
    __syncthreads();
    if (t < 64) {
        int g = t >> 4, l = t & 15;
        float m0 = sm[g][0][l], m1 = sm[g][1][l], m2 = sm[g][2][l], m3 = sm[g][3][l];
        float mx = fmaxf(fmaxf(m0, m1), fmaxf(m2, m3));
        float l_ = sl[g][0][l] * __expf(m0 - mx) + sl[g][1][l] * __expf(m1 - mx)
                 + sl[g][2][l] * __expf(m2 - mx) + sl[g][3][l] * __expf(m3 - mx);
        int n = qbase + 16 * g + l;
        mout[b * 4096 + n] = mx;
        ilout[b * 4096 + n] = 1.f / l_;
    }
}

// ---------------------------------------------------------------------------
// K7B v14: v13 + COUNTED-WAIT BARRIERS (T4) — the isolated fix this round.
//  - v13 post-mortem: occupancy 35%, FETCH 14.5MB, conflicts 6% — all the
//    invoked mechanisms worked, yet dur rose 8% vs v10. Diagnosis: every
//    __syncthreads() compiles to s_waitcnt vmcnt(0) lgkmcnt(0) + s_barrier,
//    draining ALL outstanding global loads (the AV/KC prefetches) at EVERY
//    barrier, 2x per chunk. Prefetch never spans the barrier; every
//    co-resident wave hits the same L2-latency wall, so occupancy cannot
//    fill it. This is the guide's m97 barrier-drain ceiling verbatim.
//  - Fix: in-loop barriers become {s_waitcnt lgkmcnt(0); s_barrier} via
//    inline asm + builtin. LDS correctness preserved (producer ds_writes
//    drained pre-barrier; consumer ds_reads tracked by compiler lgkmcnt).
//    AV/KC global loads stay in flight across the barrier; the compiler's
//    waitcnt pass inserts COUNTED vmcnt before their first MFMA use.
//  - Everything else identical to v13 (64q x 128c blocks, 2 blocks/CU,
//    proven PL swizzle, XCD pinning).
// ---------------------------------------------------------------------------
__global__ __launch_bounds__(512, 4) void k7b_attn(
    const unsigned short* __restrict__ qT, const unsigned short* __restrict__ kT,
    const unsigned short* __restrict__ vC, const float* __restrict__ mstat,
    const float* __restrict__ ilstat, const float* __restrict__ x2,
    const float* __restrict__ gamma, float* __restrict__ outp)
{
    __shared__ __align__(16) unsigned short PL[2][64][64];  // 16 KB swizzled P
    __shared__ __align__(16) float SB[128][68];             // 34.8 KB combine buffer
    const int bid = blockIdx.x;
    const int b = (bid >> 1) & 3;
    const int csplit = bid & 1;
    const int qbase = (bid >> 3) << 6;      // 64 q-cols per block
    const int t = threadIdx.x;
    const int wid = t >> 6, lane = t & 63;
    const int cw = wid & 3, khw = wid >> 2;
    const int quad = lane >> 4, l16 = lane & 15;
    const int ntq = cw;                     // QK n-tile of this wave
    const int mt0 = 2 * khw, mt1 = 2 * khw + 1;
    const int nq = qbase + 16 * ntq + l16;  // q-column of this wave's P rows

    FRAG qf;
    qf.u = *(const uint4*)(qT + ((size_t)(b * 4096 + nq)) * 32 + quad * 8);
    const float mN = mstat[b * 4096 + nq];

    f32x4 acc[2][4];
    #pragma unroll
    for (int ct = 0; ct < 2; ct++)
        #pragma unroll
        for (int nt = 0; nt < 4; nt++) { acc[ct][nt][0] = 0.f; acc[ct][nt][1] = 0.f; acc[ct][nt][2] = 0.f; acc[ct][nt][3] = 0.f; }
    const unsigned short* kTb = kT + (size_t)b * 4096 * 32;
    // per-wave V-frag base: frag (c16 = 8*csplit + 2*cw + ct, khw), lane-contig.
    const unsigned short* vfb = vC + ((size_t)b * 64 << 14)
                              + ((((8 * csplit + 2 * cw) << 1) + khw) << 9) + lane * 8;

    // PL swizzle (v10-proven): row = 64 shorts = 128 B = 8 granules of 16 B;
    // phys_granule = logical ^ (l16 & 7).
    const int po  = 4 * (quad & 1);
    const int pg0 = ((4 * khw + (quad >> 1)) ^ (l16 & 7));        // pkA granule
    const int pg1 = pg0 ^ 2;                                       // pkB granule
    const int pgr = ((4 * khw + quad) ^ (l16 & 7)) << 3;          // bp read offset

    FRAG avA[2], avB[2], kcA0, kcA1, kcB0, kcB1;

// Counted-wait barrier: drain only LDS ops (my ds_writes visible, my ds_reads
// complete), then plain s_barrier. Global prefetches stay in flight.
#define LBAR() do { \
    asm volatile("s_waitcnt lgkmcnt(0)" ::: "memory"); \
    __builtin_amdgcn_s_barrier(); \
} while (0)

#define AV_LOAD(AV, CH) do { \
    const unsigned short* vfj = vfb + ((size_t)(CH) << 14); \
    AV[0].u = *(const uint4*)(vfj); \
    AV[1].u = *(const uint4*)(vfj + 1024); \
} while (0)

#define KC_LOAD(K0, K1, CH) do { \
    const int mo_ = (CH) << 6; \
    K0.u = *(const uint4*)(kTb + (size_t)(mo_ + 16 * mt0 + l16) * 32 + quad * 8); \
    K1.u = *(const uint4*)(kTb + (size_t)(mo_ + 16 * mt1 + l16) * 32 + quad * 8); \
} while (0)

// QK for this wave's (ntq, khw) -> PL rows 16*ntq + l16, its khw columns.
#define QK_STORE(DST, K0, K1) do { \
    f32x4 z; z[0] = 0.f; z[1] = 0.f; z[2] = 0.f; z[3] = 0.f; \
    f32x4 e0 = __builtin_amdgcn_mfma_f32_16x16x32_bf16(K0.s, qf.s, z, 0, 0, 0); \
    f32x4 e1 = __builtin_amdgcn_mfma_f32_16x16x32_bf16(K1.s, qf.s, z, 0, 0, 0); \
    union { float f; unsigned int u; } p0, p1, p2, p3; \
    uint2 pkA, pkB; \
    p0.f = __expf(e0[0] - mN); p1.f = __expf(e0[1] - mN); \
    p2.f = __expf(e0[2] - mN); p3.f = __expf(e0[3] - mN); \
    pkA.x = __builtin_amdgcn_perm(p1.u, p0.u, 0x07060302u); \
    pkA.y = __builtin_amdgcn_perm(p3.u, p2.u, 0x07060302u); \
    p0.f = __expf(e1[0] - mN); p1.f = __expf(e1[1] - mN); \
    p2.f = __expf(e1[2] - mN); p3.f = __expf(e1[3] - mN); \
    pkB.x = __builtin_amdgcn_perm(p1.u, p0.u, 0x07060302u); \
    pkB.y = __builtin_amdgcn_perm(p3.u, p2.u, 0x07060302u); \
    unsigned short* rw = &PL[DST][16 * ntq + l16][po]; \
    *(uint2*)(rw + pg0 * 8) = pkA; \
    *(uint2*)(rw + pg1 * 8) = pkB; \
} while (0)

#define PV_STEP(AV, CUR) do { \
    FRAG bp[4]; \
    _Pragma("unroll") \
    for (int nt_ = 0; nt_ < 4; nt_++) \
        bp[nt_].u = *(const uint4*)&PL[CUR][16 * nt_ + l16][pgr]; \
    __builtin_amdgcn_s_setprio(1); \
    _Pragma("unroll") \
    for (int ct_ = 0; ct_ < 2; ct_++) { \
        _Pragma("unroll") \
        for (int nt_ = 0; nt_ < 4; nt_++) \
            acc[ct_][nt_] = __builtin_amdgcn_mfma_f32_16x16x32_bf16(AV[ct_].s, bp[nt_].s, acc[ct_][nt_], 0, 0, 0); \
    } \
    __builtin_amdgcn_s_setprio(0); \
} while (0)

    // --- prologue: av(0); kc(0); QK(0)->PL[0]; kc(1) ---
    AV_LOAD(avA, 0);
    KC_LOAD(kcA0, kcA1, 0);
    QK_STORE(0, kcA0, kcA1);
    KC_LOAD(kcB0, kcB1, 1);

    for (int jj = 0; jj < 32; jj++) {
        const int j = 2 * jj;
        // ---- phase A: compute PV(j) [even chunk], prefetch j+1 ----
        LBAR();
        {
            if (j < 63) AV_LOAD(avB, j + 1);
            QK_STORE(1, kcB0, kcB1);                 // chunk j+1 (j <= 62 always)
            if (j < 62) KC_LOAD(kcA0, kcA1, j + 2);
        }
        PV_STEP(avA, 0);
        // ---- phase B: compute PV(j+1) [odd chunk], prefetch j+2 ----
        LBAR();
        if (j < 62) {
            AV_LOAD(avA, j + 2);
            QK_STORE(0, kcA0, kcA1);                 // chunk j+2
            if (j < 61) KC_LOAD(kcB0, kcB1, j + 3);
        }
        PV_STEP(avB, 1);
    }
#undef AV_LOAD
#undef KC_LOAD
#undef QK_STORE
#undef PV_STEP
#undef LBAR

    // --- epilogue: combine khw halves via SB (single round: 128 rows) ---
    const float gm = gamma[0];
    __syncthreads();
    if (khw == 0) {
        #pragma unroll
        for (int ct = 0; ct < 2; ct++)
            #pragma unroll
            for (int nt = 0; nt < 4; nt++)
                #pragma unroll
                for (int r = 0; r < 4; r++)
                    SB[32 * cw + 16 * ct + 4 * quad + r][16 * nt + l16] = acc[ct][nt][r];
    }
    __syncthreads();
    if (khw == 1) {
        #pragma unroll
        for (int ct = 0; ct < 2; ct++)
            #pragma unroll
            for (int nt = 0; nt < 4; nt++)
                #pragma unroll
                for (int r = 0; r < 4; r++)
                    SB[32 * cw + 16 * ct + 4 * quad + r][16 * nt + l16] += acc[ct][nt][r];
    }
    __syncthreads();
    // cooperative store: 128c x 64n with 512 threads, 4 passes of float4
    #pragma unroll
    for (int pass = 0; pass < 4; pass++) {
        int cl = (t >> 4) + 32 * pass;
        int n4 = (t & 15) * 4;
        float4 vv = *(float4*)&SB[cl][n4];
        float4 il4 = *(const float4*)(ilstat + (size_t)b * 4096 + qbase + n4);
        size_t idx = ((size_t)(b * 256 + 128 * csplit + cl)) * 4096 + qbase + n4;
        float4 xv = *(const float4*)(x2 + idx);
        float4 ov;
        ov.x = gm * vv.x * il4.x + xv.x;
        ov.y = gm * vv.y * il4.y + xv.y;
        ov.z = gm * vv.z * il4.z + xv.z;
        ov.w = gm * vv.w * il4.w + xv.w;
        *(float4*)(outp + idx) = ov;
    }
}

// ---------------------------------------------------------------------------
extern "C" void kernel_launch(void* const* d_in, const int* in_sizes, int n_in,
                              void* d_out, int out_size, void* d_ws, size_t ws_size,
                              hipStream_t stream) {
    (void)in_sizes; (void)n_in; (void)out_size; (void)ws_size;
    const float* x    = (const float*)d_in[0];
    const float* W1   = (const float*)d_in[1];
    const float* b1   = (const float*)d_in[2];
    const float* W2   = (const float*)d_in[3];
    const float* b2   = (const float*)d_in[4];
    const float* Wq   = (const float*)d_in[5];
    const float* bq   = (const float*)d_in[6];
    const float* Wk   = (const float*)d_in[7];
    const float* bk   = (const float*)d_in[8];
    const float* Wv   = (const float*)d_in[9];
    const float* bv   = (const float*)d_in[10];
    const float* gam  = (const float*)d_in[11];
    const float* Wsp  = (const float*)d_in[12];
    const float* bn_g = (const float*)d_in[13];
    const float* bn_b = (const float*)d_in[14];
    const float* bn_m = (const float*)d_in[15];
    const float* bn_v = (const float*)d_in[16];

    float* ws = (float*)d_ws;
    float* bm2   = ws; ws += (size_t)4 * 256 * 1024;
    float* bm4   = ws; ws += (size_t)4 * 256 * 256;
    float* bm8   = ws; ws += (size_t)4 * 256 * 64;
    float* featA = ws; ws += 1024;
    float* fm1   = ws; ws += 1024;
    float* fm2   = ws; ws += 1024;
    float* fm4   = ws; ws += 1024;
    float* fm8   = ws; ws += 1024;
    float* g     = ws; ws += 1024;
    float* comp  = ws; ws += (size_t)4 * 2 * 4096;
    float* spg   = ws; ws += (size_t)4 * 4096;
    float* x2    = ws; ws += (size_t)4 * 256 * 4096;
    float* bm2b  = ws; ws += (size_t)4 * 256 * 1024;
    float* bm4b  = ws; ws += (size_t)4 * 256 * 256;
    float* bm8b  = ws; ws += (size_t)4 * 256 * 64;
    float* P2    = ws; ws += (size_t)4 * 320 * 1024;
    float* P4    = ws; ws += (size_t)4 * 320 * 256;
    float* P8    = ws; ws += (size_t)4 * 320 * 64;
    float* mstat = ws; ws += (size_t)4 * 4096;
    float* ilstat= ws; ws += (size_t)4 * 4096;
    unsigned short* qT  = (unsigned short*)ws; ws += (size_t)4 * 4096 * 32 / 2;
    unsigned short* kT  = (unsigned short*)ws; ws += (size_t)4 * 4096 * 32 / 2;
    unsigned short* vCp = (unsigned short*)ws; ws += (size_t)4 * 64 * 16384 / 2;
    unsigned short* x2T = (unsigned short*)ws; ws += (size_t)4 * 4096 * 256 / 2;
    unsigned short* WB  = (unsigned short*)ws; ws += (size_t)320 * 256 / 2;

    // Weight cast (no deps)
    k_wcast<<<320, 256, 0, stream>>>(Wq, Wk, Wv, WB);
    // Stage 1: channel gate
    k_pyramid<<<1024, 256, 0, stream>>>(x, nullptr, nullptr, nullptr,
                                        bm2, bm4, bm8, featA, fm1, fm2, fm4, fm8, 0);
    k2_gate<<<4, 256, 0, stream>>>(featA, fm1, fm2, fm4, fm8, W1, b1, W2, b2, g);
    // Stage 2: spatial gate
    k3_comp<<<256, 256, 0, stream>>>(x, bm2, bm4, bm8, g, comp);
    k4_spgate<<<256, 64, 0, stream>>>(comp, Wsp, bn_g, bn_b, bn_m, bn_v, spg);
    k_pyramid<<<1024, 256, 0, stream>>>(x, g, spg, x2,
                                        bm2b, bm4b, bm8b,
                                        nullptr, nullptr, nullptr, nullptr, nullptr, 1);
    // x2 -> bf16 transposed [n][c]
    k_x2t<<<dim3(64, 4, 4), 256, 0, stream>>>(x2, x2T);
    // Stage 3: q/k/v projections, multiscale-decomposed (single low-res launch)
    k6_gemm<<<dim3(21, 5, 4), 256, 0, stream>>>(Wq, Wk, Wv, bm2b, bm4b, bm8b, P2, P4, P8);
    k6m<<<dim3(32, 5, 4), 256, 0, stream>>>(WB, x2T, bq, bk, bv, P2, P4, P8, qT, kT, vCp);
    // Two-pass attention: stats, then counted-wait-barrier pipelined PV
    k7a_stats<<<256, 1024, 0, stream>>>(qT, kT, mstat, ilstat);
    k7b_attn<<<512, 512, 0, stream>>>(qT, kT, vCp, mstat, ilstat, x2, gam, (float*)d_out);
}

// Round 8
// 274.467 us; speedup vs baseline: 1.0530x; 1.0075x over previous
//
#include <hip/hip_runtime.h>
#include <math.h>

// Shapes (fixed): B=4, C=256, H=W=64, N=4096, 4C=1024, c8=32, r=16.

typedef float f32x4 __attribute__((ext_vector_type(4)));
typedef short s16x8 __attribute__((ext_vector_type(8)));
union FRAG { uint4 u; s16x8 s; };

__device__ __forceinline__ unsigned short f2bf(float f) {
    union { float f; unsigned int u; } v; v.f = f;
    unsigned int r = v.u + 0x7FFFu + ((v.u >> 16) & 1u);
    return (unsigned short)(r >> 16);
}

// ---------------------------------------------------------------------------
// K1/K5: per-(b,c) plane -> block-mean pyramid (+ feats in mode 0, x2 in mode 1)
// Mode-0 launch carries 80 extra blocks (bc >= 1024) that do the WB bf16
// weight-cast (fused former k_wcast — saves a launch).
// ---------------------------------------------------------------------------
__global__ __launch_bounds__(256) void k_pyramid(
    const float* __restrict__ xin, const float* __restrict__ gch,
    const float* __restrict__ spg, float* __restrict__ x2out,
    float* __restrict__ bm2, float* __restrict__ bm4, float* __restrict__ bm8,
    float* __restrict__ featA, float* __restrict__ fm1, float* __restrict__ fm2,
    float* __restrict__ fm4, float* __restrict__ fm8, int mode,
    const float* __restrict__ Wq, const float* __restrict__ Wk,
    const float* __restrict__ Wv, unsigned short* __restrict__ WB)
{
    __shared__ float sx[4096];
    __shared__ float s2[1024];
    __shared__ float s4[256];
    __shared__ float wred[4][8];
    const int bc = blockIdx.x;
    const int t = threadIdx.x;
    if (mode == 0 && bc >= 1024) {
        // fused weight cast: WB[320][256], 80 blocks x 1024 entries
        const int e0 = (bc - 1024) * 1024 + t * 4;
        const int o = e0 >> 8, col = e0 & 255;
        const float* row = (o < 32) ? (Wq + (size_t)o * 1024)
                          : (o < 64) ? (Wk + (size_t)(o - 32) * 1024)
                                     : (Wv + (size_t)(o - 64) * 1024);
        float4 v = *(const float4*)(row + 768 + col);
        uint2 pk;
        pk.x = (unsigned)f2bf(v.x) | ((unsigned)f2bf(v.y) << 16);
        pk.y = (unsigned)f2bf(v.z) | ((unsigned)f2bf(v.w) << 16);
        *(uint2*)(WB + e0) = pk;
        return;
    }
    const int b = bc >> 8;
    const float* xp = xin + (size_t)bc * 4096;
    float gc = 1.f;
    if (mode == 1) gc = gch[bc];
    float sum = 0.f, mx = -1e30f;
    for (int r = 0; r < 4; r++) {
        int i4 = t + 256 * r;
        float4 v = ((const float4*)xp)[i4];
        if (mode == 1) {
            float4 sg = ((const float4*)(spg + (size_t)b * 4096))[i4];
            v.x *= gc * sg.x; v.y *= gc * sg.y; v.z *= gc * sg.z; v.w *= gc * sg.w;
            ((float4*)(x2out + (size_t)bc * 4096))[i4] = v;
        } else {
            sum += v.x + v.y + v.z + v.w;
            mx = fmaxf(mx, fmaxf(fmaxf(v.x, v.y), fmaxf(v.z, v.w)));
        }
        ((float4*)sx)[i4] = v;
    }
    __syncthreads();
    float mx2 = -1e30f;
    for (int r = 0; r < 4; r++) {
        int i = t + 256 * r;
        int r2 = i >> 5, c2 = i & 31;
        int p0 = 128 * r2 + 2 * c2;
        float v = 0.25f * (sx[p0] + sx[p0 + 1] + sx[p0 + 64] + sx[p0 + 65]);
        s2[i] = v;
        bm2[(size_t)bc * 1024 + i] = v;
        mx2 = fmaxf(mx2, v);
    }
    __syncthreads();
    float mx4;
    {
        int r4 = t >> 4, c4 = t & 15;
        int p0 = 64 * r4 + 2 * c4;
        float v = 0.25f * (s2[p0] + s2[p0 + 1] + s2[p0 + 32] + s2[p0 + 33]);
        s4[t] = v;
        bm4[(size_t)bc * 256 + t] = v;
        mx4 = v;
    }
    __syncthreads();
    float mx8 = -1e30f;
    if (t < 64) {
        int r8 = t >> 3, c8 = t & 7;
        int p0 = 32 * r8 + 2 * c8;
        float v = 0.25f * (s4[p0] + s4[p0 + 1] + s4[p0 + 16] + s4[p0 + 17]);
        bm8[(size_t)bc * 64 + t] = v;
        mx8 = v;
    }
    if (mode == 0) {
        float vs = sum, v1 = mx, v2 = mx2, v4 = mx4, v8 = mx8;
        #pragma unroll
        for (int o = 1; o < 64; o <<= 1) {
            vs += __shfl_xor(vs, o);
            v1 = fmaxf(v1, __shfl_xor(v1, o));
            v2 = fmaxf(v2, __shfl_xor(v2, o));
            v4 = fmaxf(v4, __shfl_xor(v4, o));
            v8 = fmaxf(v8, __shfl_xor(v8, o));
        }
        if ((t & 63) == 0) {
            int wd = t >> 6;
            wred[wd][0] = vs; wred[wd][1] = v1; wred[wd][2] = v2;
            wred[wd][3] = v4; wred[wd][4] = v8;
        }
        __syncthreads();
        if (t == 0) featA[bc] = (wred[0][0] + wred[1][0] + wred[2][0] + wred[3][0]) * (1.f / 4096.f);
        else if (t == 1) fm1[bc] = fmaxf(fmaxf(wred[0][1], wred[1][1]), fmaxf(wred[2][1], wred[3][1]));
        else if (t == 2) fm2[bc] = fmaxf(fmaxf(wred[0][2], wred[1][2]), fmaxf(wred[2][2], wred[3][2]));
        else if (t == 3) fm4[bc] = fmaxf(fmaxf(wred[0][3], wred[1][3]), fmaxf(wred[2][3], wred[3][3]));
        else if (t == 4) fm8[bc] = fmaxf(fmaxf(wred[0][4], wred[1][4]), fmaxf(wred[2][4], wred[3][4]));
    }
}

// ---------------------------------------------------------------------------
// K3: spatial-gate input, with the channel-gate MLP FUSED (former k2 — each
// block recomputes g[b] from featA..fm8; block (bid&63)==0 also writes g for
// k_pyramid mode-1). Grid 256: block = (b, 64-pixel chunk); 4 waves split
// the 256 channels; LDS cross-wave reduce.
// ---------------------------------------------------------------------------
__global__ __launch_bounds__(256) void k3_comp(
    const float* __restrict__ x, const float* __restrict__ bm2,
    const float* __restrict__ bm4, const float* __restrict__ bm8,
    const float* __restrict__ featA, const float* __restrict__ fm1,
    const float* __restrict__ fm2, const float* __restrict__ fm4,
    const float* __restrict__ fm8,
    const float* __restrict__ W1, const float* __restrict__ b1,
    const float* __restrict__ W2, const float* __restrict__ b2,
    float* __restrict__ g, float* __restrict__ comp)
{
    __shared__ float sf[5][256];
    __shared__ float sh[5][16];
    __shared__ float hs[16];
    __shared__ float sg[256];
    __shared__ float rmx[4][64];
    __shared__ float rsm[4][64];
    const int b = blockIdx.x >> 6;
    const int t = threadIdx.x;
    // --- inline channel-gate MLP (identical math to former k2_gate) ---
    sf[0][t] = featA[(b << 8) + t];
    sf[1][t] = fm1[(b << 8) + t];
    sf[2][t] = fm2[(b << 8) + t];
    sf[3][t] = fm4[(b << 8) + t];
    sf[4][t] = fm8[(b << 8) + t];
    __syncthreads();
    if (t < 80) {
        int f = t / 16, j = t % 16;
        float a = b1[j];
        for (int c = 0; c < 256; c++) a += sf[f][c] * W1[c * 16 + j];
        sh[f][j] = fmaxf(a, 0.f);
    }
    __syncthreads();
    if (t < 16) hs[t] = 4.f * sh[0][t] + sh[1][t] + sh[2][t] + sh[3][t] + sh[4][t];
    __syncthreads();
    {
        float a = 8.f * b2[t];
        for (int j = 0; j < 16; j++) a += hs[j] * W2[j * 256 + t];
        sg[t] = 1.f / (1.f + __expf(-a));
    }
    __syncthreads();
    if ((blockIdx.x & 63) == 0) g[(b << 8) + t] = sg[t];   // for k_pyramid mode 1
    // --- original k3 body ---
    const int pix = ((blockIdx.x & 63) << 6) + (t & 63);
    const int wid = t >> 6;
    const int c0 = wid << 6;
    const int h = pix >> 6, w = pix & 63;
    const int i2 = ((h >> 1) << 5) + (w >> 1);
    const int i4 = ((h >> 2) << 4) + (w >> 2);
    const int i8 = ((h >> 3) << 3) + (w >> 3);
    const float* xb = x + ((size_t)b << 8) * 4096;
    const float* p2 = bm2 + ((size_t)b << 8) * 1024;
    const float* p4 = bm4 + ((size_t)b << 8) * 256;
    const float* p8 = bm8 + ((size_t)b << 8) * 64;
    float mx = -1e30f, sm = 0.f;
    for (int c = c0; c < c0 + 64; c++) {
        float gc = sg[c];
        float xv = xb[(size_t)c * 4096 + pix] * gc;
        float v2 = p2[c * 1024 + i2] * gc;
        float v4 = p4[c * 256 + i4] * gc;
        float v8 = p8[c * 64 + i8] * gc;
        mx = fmaxf(fmaxf(mx, xv), fmaxf(fmaxf(v2, v4), v8));
        sm += xv + v2 + v4 + v8;
    }
    rmx[wid][t & 63] = mx;
    rsm[wid][t & 63] = sm;
    __syncthreads();
    if (wid == 0) {
        int l = t;
        float m = fmaxf(fmaxf(rmx[0][l], rmx[1][l]), fmaxf(rmx[2][l], rmx[3][l]));
        float s = rsm[0][l] + rsm[1][l] + rsm[2][l] + rsm[3][l];
        comp[((size_t)b * 2) * 4096 + pix] = m;
        comp[((size_t)b * 2 + 1) * 4096 + pix] = s * (1.f / 1024.f);
    }
}

// ---------------------------------------------------------------------------
// K4: 7x7 conv (2->1, pad 3, no bias) + BN(eval) + sigmoid. Grid 256 x 64thr.
// ---------------------------------------------------------------------------
__global__ __launch_bounds__(64) void k4_spgate(
    const float* __restrict__ comp, const float* __restrict__ Wsp,
    const float* __restrict__ bn_g, const float* __restrict__ bn_b,
    const float* __restrict__ bn_m, const float* __restrict__ bn_v,
    float* __restrict__ spg)
{
    __shared__ float w[98];
    const int t = threadIdx.x;
    for (int i = t; i < 98; i += 64) w[i] = Wsp[i];
    __syncthreads();
    const int b = blockIdx.x >> 6;
    const int pix = ((blockIdx.x & 63) << 6) + t;
    const int h = pix >> 6, wx = pix & 63;
    const float* c0 = comp + (size_t)b * 2 * 4096;
    float acc = 0.f;
    for (int ci = 0; ci < 2; ci++)
        for (int kh = 0; kh < 7; kh++) {
            int hh = h + kh - 3;
            if (hh < 0 || hh >= 64) continue;
            for (int kw = 0; kw < 7; kw++) {
                int wwp = wx + kw - 3;
                if (wwp < 0 || wwp >= 64) continue;
                acc += c0[ci * 4096 + hh * 64 + wwp] * w[ci * 49 + kh * 7 + kw];
            }
        }
    float sc = rsqrtf(bn_v[0] + 1e-5f) * bn_g[0];
    float sp = (acc - bn_m[0]) * sc + bn_b[0];
    spg[b * 4096 + pix] = 1.f / (1.f + __expf(-sp));
}

// ---------------------------------------------------------------------------
// K_X2T: x2 fp32 [b][256 c][4096 n] -> x2T bf16 [b][4096 n][256 c]
// ---------------------------------------------------------------------------
__global__ __launch_bounds__(256) void k_x2t(
    const float* __restrict__ x2, unsigned short* __restrict__ x2T)
{
    __shared__ unsigned short T[64][72];
    const int b = blockIdx.z;
    const int cb = blockIdx.y * 64;
    const int nb = blockIdx.x * 64;
    const int t = threadIdx.x;
    #pragma unroll
    for (int r = 0; r < 16; r++) {
        int cl = (t >> 6) + 4 * r;
        int nl = t & 63;
        float v = x2[((size_t)(b * 256 + cb + cl)) * 4096 + nb + nl];
        T[nl][cl] = f2bf(v);
    }
    __syncthreads();
    #pragma unroll
    for (int pass = 0; pass < 4; pass++) {
        int nl = (t >> 4) + 16 * pass;
        int c4 = (t & 15) * 4;
        uint2 pk;
        pk.x = (unsigned)T[nl][c4] | ((unsigned)T[nl][c4 + 1] << 16);
        pk.y = (unsigned)T[nl][c4 + 2] | ((unsigned)T[nl][c4 + 3] << 16);
        *(uint2*)(x2T + ((size_t)(b * 4096 + nb + nl)) * 256 + cb + c4) = pk;
    }
}

// ---------------------------------------------------------------------------
// K6: fp32 projection GEMM for low-res P2/P4/P8, all three scales in ONE
// launch: blockIdx.x 0..15 -> P2, 16..19 -> P4, 20 -> P8.
// ---------------------------------------------------------------------------
__global__ __launch_bounds__(256) void k6_gemm(
    const float* __restrict__ Wq, const float* __restrict__ Wk, const float* __restrict__ Wv,
    const float* __restrict__ bm2b, const float* __restrict__ bm4b, const float* __restrict__ bm8b,
    float* __restrict__ P2, float* __restrict__ P4, float* __restrict__ P8)
{
    __shared__ float At[32][68];
    __shared__ float Bt[32][64];
    const int bx = blockIdx.x;
    int col_off, ns, nb;
    const float* src;
    float* outp;
    if (bx < 16)      { col_off = 0;   src = bm2b; ns = 1024; outp = P2; nb = bx; }
    else if (bx < 20) { col_off = 256; src = bm4b; ns = 256;  outp = P4; nb = bx - 16; }
    else              { col_off = 512; src = bm8b; ns = 64;   outp = P8; nb = 0; }
    const int b = blockIdx.z;
    const int o_base = blockIdx.y * 64;
    const int n_base = nb * 64;
    const int t = threadIdx.x;
    const int tn = t >> 4, tm = t & 15;
    const int lk = t & 31, lo8 = t >> 5;
    const int ln = t & 63, lk4 = t >> 6;
    float acc[4][4];
    #pragma unroll
    for (int i = 0; i < 4; i++)
        #pragma unroll
        for (int j = 0; j < 4; j++) acc[i][j] = 0.f;
    for (int k0 = 0; k0 < 256; k0 += 32) {
        __syncthreads();
        #pragma unroll
        for (int r = 0; r < 8; r++) {
            int o = o_base + lo8 + 8 * r;
            const float* wrow = (o < 32) ? (Wq + (size_t)o * 1024)
                              : (o < 64) ? (Wk + (size_t)(o - 32) * 1024)
                                         : (Wv + (size_t)(o - 64) * 1024);
            At[lk][lo8 + 8 * r] = wrow[col_off + k0 + lk];
        }
        #pragma unroll
        for (int r = 0; r < 8; r++)
            Bt[lk4 + 4 * r][ln] = src[((size_t)b * 256 + k0 + lk4 + 4 * r) * ns + n_base + ln];
        __syncthreads();
        #pragma unroll
        for (int kk = 0; kk < 32; kk++) {
            float4 a = *(const float4*)&At[kk][4 * tn];
            float4 bb = *(const float4*)&Bt[kk][4 * tm];
            acc[0][0] += a.x * bb.x; acc[0][1] += a.x * bb.y; acc[0][2] += a.x * bb.z; acc[0][3] += a.x * bb.w;
            acc[1][0] += a.y * bb.x; acc[1][1] += a.y * bb.y; acc[1][2] += a.y * bb.z; acc[1][3] += a.y * bb.w;
            acc[2][0] += a.z * bb.x; acc[2][1] += a.z * bb.y; acc[2][2] += a.z * bb.z; acc[2][3] += a.z * bb.w;
            acc[3][0] += a.w * bb.x; acc[3][1] += a.w * bb.y; acc[3][2] += a.w * bb.z; acc[3][3] += a.w * bb.w;
        }
    }
    #pragma unroll
    for (int i = 0; i < 4; i++)
        #pragma unroll
        for (int j = 0; j < 4; j++)
            outp[((size_t)b * 320 + o_base + 4 * tn + i) * ns + n_base + 4 * tm + j] = acc[i][j];
}

// ---------------------------------------------------------------------------
// K6M: full-res projection via bf16 MFMA. v writes go to FRAG-CONTIGUOUS
// layout (see k7b AV_LOAD).
// ---------------------------------------------------------------------------
__global__ __launch_bounds__(256) void k6m(
    const unsigned short* __restrict__ WB, const unsigned short* __restrict__ x2T,
    const float* __restrict__ bq, const float* __restrict__ bk, const float* __restrict__ bv,
    const float* __restrict__ P2, const float* __restrict__ P4, const float* __restrict__ P8,
    unsigned short* __restrict__ qT, unsigned short* __restrict__ kT,
    unsigned short* __restrict__ vC)
{
    const int b = blockIdx.z;
    const int obase = blockIdx.y * 64;
    const int nb = blockIdx.x * 128;
    const int t = threadIdx.x;
    const int w_ = t >> 6, lane = t & 63;
    const int quad = lane >> 4, l16 = lane & 15;
    const int nbase = nb + 32 * w_;
    f32x4 acc[4][2];
    #pragma unroll
    for (int ot = 0; ot < 4; ot++)
        #pragma unroll
        for (int nt = 0; nt < 2; nt++) { acc[ot][nt][0] = 0.f; acc[ot][nt][1] = 0.f; acc[ot][nt][2] = 0.f; acc[ot][nt][3] = 0.f; }
    const unsigned short* xb = x2T + ((size_t)b * 4096 + nbase) * 256;
    for (int k0 = 0; k0 < 256; k0 += 32) {
        FRAG af[4], bf[2];
        #pragma unroll
        for (int ot = 0; ot < 4; ot++)
            af[ot].u = *(const uint4*)(WB + (size_t)(obase + 16 * ot + l16) * 256 + k0 + quad * 8);
        #pragma unroll
        for (int nt = 0; nt < 2; nt++)
            bf[nt].u = *(const uint4*)(xb + (size_t)(16 * nt + l16) * 256 + k0 + quad * 8);
        #pragma unroll
        for (int ot = 0; ot < 4; ot++)
            #pragma unroll
            for (int nt = 0; nt < 2; nt++)
                acc[ot][nt] = __builtin_amdgcn_mfma_f32_16x16x32_bf16(af[ot].s, bf[nt].s, acc[ot][nt], 0, 0, 0);
    }
    #pragma unroll
    for (int ot = 0; ot < 4; ot++) {
        #pragma unroll
        for (int nt = 0; nt < 2; nt++) {
            int n = nbase + 16 * nt + l16;
            int h = n >> 6, wx = n & 63;
            int i2 = ((h >> 1) << 5) + (wx >> 1);
            int i4 = ((h >> 2) << 4) + (wx >> 2);
            int i8 = ((h >> 3) << 3) + (wx >> 3);
            float vals[4];
            #pragma unroll
            for (int r = 0; r < 4; r++) {
                int o = obase + 16 * ot + 4 * quad + r;
                float bias = (o < 32) ? bq[o] : (o < 64) ? bk[o - 32] : bv[o - 64];
                size_t ro = (size_t)b * 320 + o;
                vals[r] = acc[ot][nt][r] + bias
                        + P2[ro * 1024 + i2] + P4[ro * 256 + i4] + P8[ro * 64 + i8];
            }
            int o0 = obase + 16 * ot + 4 * quad;
            if (o0 < 64) {
                uint2 pk;
                pk.x = (unsigned)f2bf(vals[0]) | ((unsigned)f2bf(vals[1]) << 16);
                pk.y = (unsigned)f2bf(vals[2]) | ((unsigned)f2bf(vals[3]) << 16);
                if (o0 < 32)
                    *(uint2*)(qT + ((size_t)(b * 4096 + n)) * 32 + o0) = pk;
                else
                    *(uint2*)(kT + ((size_t)(b * 4096 + n)) * 32 + (o0 - 32)) = pk;
            } else {
                int chunk = n >> 6;
                int kk = n & 63;
                int khw_ = (kk >> 5) & 1, qd = (kk >> 3) & 3, ko = kk & 7;
                unsigned short* dst = vC + (((size_t)b * 64 + chunk) << 14);
                #pragma unroll
                for (int r = 0; r < 4; r++) {
                    int c = o0 - 64 + r;
                    dst[((((c >> 4) << 1) + khw_) << 9) + ((qd * 16 + (c & 15)) << 3) + ko] = f2bf(vals[r]);
                }
            }
        }
    }
}

// ---------------------------------------------------------------------------
// K7A: softmax stats pass (dense kT reads), XCD-pinned bid decode.
// ---------------------------------------------------------------------------
__global__ __launch_bounds__(1024, 4) void k7a_stats(
    const unsigned short* __restrict__ qT, const unsigned short* __restrict__ kT,
    float* __restrict__ mout, float* __restrict__ ilout)
{
    __shared__ float sm[4][4][16], sl[4][4][16];   // [g][s][l16]
    const int bid = blockIdx.x;
    const int b = (bid >> 1) & 3;
    const int qbase = (((bid >> 3) << 1) | (bid & 1)) << 6;
    const int t = threadIdx.x;
    const int wid = t >> 6, lane = t & 63;
    const int g_ = wid >> 2, s_ = wid & 3;
    const int quad = lane >> 4, l16 = lane & 15;

    FRAG qf;
    qf.u = *(const uint4*)(qT + ((size_t)(b * 4096 + qbase + 16 * g_ + l16)) * 32 + quad * 8);
    const unsigned short* kTb = kT + (size_t)b * 4096 * 32;

    float m_run = -1e30f, l_run = 0.f;
    for (int j = 0; j < 16; j++) {
        const int mo = (s_ << 10) + (j << 6);
        f32x4 e[4];
        #pragma unroll
        for (int mt = 0; mt < 4; mt++) {
            FRAG kf;
            kf.u = *(const uint4*)(kTb + (size_t)(mo + 16 * mt + l16) * 32 + quad * 8);
            f32x4 z; z[0] = 0.f; z[1] = 0.f; z[2] = 0.f; z[3] = 0.f;
            e[mt] = __builtin_amdgcn_mfma_f32_16x16x32_bf16(kf.s, qf.s, z, 0, 0, 0);
        }
        float pm = e[0][0];
        #pragma unroll
        for (int mt = 0; mt < 4; mt++)
            #pragma unroll
            for (int r = 0; r < 4; r++) pm = fmaxf(pm, e[mt][r]);
        float mnew = fmaxf(m_run, pm);
        float al = __expf(m_run - mnew);
        float ps = 0.f;
        #pragma unroll
        for (int mt = 0; mt < 4; mt++)
            #pragma unroll
            for (int r = 0; r < 4; r++) ps += __expf(e[mt][r] - mnew);
        l_run = l_run * al + ps;
        m_run = mnew;
    }
    #pragma unroll
    for (int o = 16; o < 64; o <<= 1) {
        float mo_ = __shfl_xor(m_run, o);
        float lo_ = __shfl_xor(l_run, o);
        float m2 = fmaxf(m_run, mo_);
        l_run = l_run * __expf(m_run - m2) + lo_ * __expf(mo_ - m2);
        m_run = m2;
    }
    if (quad == 0) { sm[g_][s_][l16] = m_run; sl[g_][s_][l16] = l_run; }
    __syncthreads();
    if (t < 64) {
        int g = t >> 4, l = t & 15;
        float m0 = sm[g][0][l], m1 = sm[g][1][l], m2 = sm[g][2][l], m3 = sm[g][3][l];
        float mx = fmaxf(fmaxf(m0, m1), fmaxf(m2, m3));
        float l_ = sl[g][0][l] * __expf(m0 - mx) + sl[g][1][l] * __expf(m1 - mx)
                 + sl[g][2][l] * __expf(m2 - mx) + sl[g][3][l] * __expf(m3 - mx);
        int n = qbase + 16 * g + l;
        mout[b * 4096 + n] = mx;
        ilout[b * 4096 + n] = 1.f / l_;
    }
}

// ---------------------------------------------------------------------------
// K7B v15: PURE Q-SPLIT of the proven v10 block — zero duplication, 2/CU.
//  - v13's c-split cost 2x QK/exp + extra kT reads (61.5 vs v10's 56.6
//    despite 35% occupancy). Q-split duplicates NOTHING: V and kT reads
//    don't depend on q, and QK work scales with q.
//  - Block = 8 waves, 32q x 256c. Each wave owns exactly ONE QK tile:
//    ntq = cw&1 (16q), mtw = 2*khw + (cw>>1) (16 keys) -> 1 MFMA + 4 exp
//    + 1 ds_write per chunk. PV: acc[4][2] = 64c x 32q per wave; per-CU
//    PV MFMA identical to v10.
//  - Grid 512, 2 blocks/CU; pair (bid, bid+256) has the SAME b (decode
//    b=(bid>>1)&3 invariant under +256) -> both read identical V-frags +
//    kT each chunk (L1/L2 hits): per-CU distinct traffic == v10. When one
//    block waits at its barrier, the other computes.
//  - Proven PL swizzle (128B rows, granule ^ (l16&7)); XCD pinning kept;
//    plain __syncthreads (v14's lgkm-only barrier was neutral-negative).
// LDS: PL[2][32][64] 8KB + SB[128][36] 18.4KB = 26.4KB x2 blocks = 53KB/CU.
// ---------------------------------------------------------------------------
__global__ __launch_bounds__(512, 4) void k7b_attn(
    const unsigned short* __restrict__ qT, const unsigned short* __restrict__ kT,
    const unsigned short* __restrict__ vC, const float* __restrict__ mstat,
    const float* __restrict__ ilstat, const float* __restrict__ x2,
    const float* __restrict__ gamma, float* __restrict__ outp)
{
    __shared__ __align__(16) unsigned short PL[2][32][64];  // 8 KB swizzled P
    __shared__ __align__(16) float SB[128][36];             // 18.4 KB combine buffer
    const int bid = blockIdx.x;
    const int b = (bid >> 1) & 3;                       // invariant under bid+256
    const int qgroup = ((bid >> 3) << 1) | (bid & 1);   // 0..127
    const int qbase = qgroup << 5;                      // 32 q-cols per block
    const int t = threadIdx.x;
    const int wid = t >> 6, lane = t & 63;
    const int cw = wid & 3, khw = wid >> 2;
    const int quad = lane >> 4, l16 = lane & 15;
    const int ntq = cw & 1;                 // this wave's QK q-tile
    const int mtw = 2 * khw + (cw >> 1);    // this wave's QK key-tile (0..3)
    const int nq = qbase + 16 * ntq + l16;

    FRAG qf;
    qf.u = *(const uint4*)(qT + ((size_t)(b * 4096 + nq)) * 32 + quad * 8);
    const float mN = mstat[b * 4096 + nq];

    f32x4 acc[4][2];   // [ct: 64c/16 within cw stripe][nt: 32q/16]
    #pragma unroll
    for (int ct = 0; ct < 4; ct++)
        #pragma unroll
        for (int nt = 0; nt < 2; nt++) { acc[ct][nt][0] = 0.f; acc[ct][nt][1] = 0.f; acc[ct][nt][2] = 0.f; acc[ct][nt][3] = 0.f; }
    const unsigned short* kTb = kT + (size_t)b * 4096 * 32;
    // per-wave V-frag base: frag (c16 = 4*cw + ct, khw), lane-contiguous.
    const unsigned short* vfb = vC + ((size_t)b * 64 << 14)
                              + (((8 * cw) + khw) << 9) + lane * 8;

    // PL swizzle: row = 64 shorts = 128 B = 8 granules of 16 B;
    // phys_granule = logical ^ (l16 & 7)  (v10-proven geometry).
    const int po  = 4 * (quad & 1);                                // write sub-off (shorts)
    const int pgw = (2 * mtw + (quad >> 1)) ^ (l16 & 7);           // QK write granule
    const int pgr = ((4 * khw + quad) ^ (l16 & 7)) << 3;           // bp read offset

    FRAG avA[4], avB[4], kcA, kcB;

#define AV_LOAD(AV, CH) do { \
    const unsigned short* vfj = vfb + ((size_t)(CH) << 14); \
    AV[0].u = *(const uint4*)(vfj); \
    AV[1].u = *(const uint4*)(vfj + 1024); \
    AV[2].u = *(const uint4*)(vfj + 2048); \
    AV[3].u = *(const uint4*)(vfj + 3072); \
} while (0)

#define KC_LOAD(K, CH) do { \
    K.u = *(const uint4*)(kTb + (size_t)((((CH) << 6) + 16 * mtw + l16)) * 32 + quad * 8); \
} while (0)

// One QK MFMA for (ntq, mtw) -> 4 exps -> one uint2 into PL.
#define QK_STORE(DST, K) do { \
    f32x4 z; z[0] = 0.f; z[1] = 0.f; z[2] = 0.f; z[3] = 0.f; \
    f32x4 e0 = __builtin_amdgcn_mfma_f32_16x16x32_bf16(K.s, qf.s, z, 0, 0, 0); \
    union { float f; unsigned int u; } p0, p1, p2, p3; \
    uint2 pk; \
    p0.f = __expf(e0[0] - mN); p1.f = __expf(e0[1] - mN); \
    p2.f = __expf(e0[2] - mN); p3.f = __expf(e0[3] - mN); \
    pk.x = __builtin_amdgcn_perm(p1.u, p0.u, 0x07060302u); \
    pk.y = __builtin_amdgcn_perm(p3.u, p2.u, 0x07060302u); \
    *(uint2*)&PL[DST][16 * ntq + l16][pgw * 8 + po] = pk; \
} while (0)

#define PV_STEP(AV, CUR) do { \
    FRAG bp[2]; \
    bp[0].u = *(const uint4*)&PL[CUR][l16][pgr]; \
    bp[1].u = *(const uint4*)&PL[CUR][16 + l16][pgr]; \
    __builtin_amdgcn_s_setprio(1); \
    _Pragma("unroll") \
    for (int ct_ = 0; ct_ < 4; ct_++) { \
        acc[ct_][0] = __builtin_amdgcn_mfma_f32_16x16x32_bf16(AV[ct_].s, bp[0].s, acc[ct_][0], 0, 0, 0); \
        acc[ct_][1] = __builtin_amdgcn_mfma_f32_16x16x32_bf16(AV[ct_].s, bp[1].s, acc[ct_][1], 0, 0, 0); \
    } \
    __builtin_amdgcn_s_setprio(0); \
} while (0)

    // --- prologue: av(0); kc(0); QK(0)->PL[0]; kc(1) ---
    AV_LOAD(avA, 0);
    KC_LOAD(kcA, 0);
    QK_STORE(0, kcA);
    KC_LOAD(kcB, 1);

    for (int jj = 0; jj < 32; jj++) {
        const int j = 2 * jj;
        // ---- phase A: compute PV(j) [even chunk], prefetch j+1 ----
        __syncthreads();
        {
            if (j < 63) AV_LOAD(avB, j + 1);
            QK_STORE(1, kcB);                    // chunk j+1 (j <= 62 always)
            if (j < 62) KC_LOAD(kcA, j + 2);
        }
        PV_STEP(avA, 0);
        // ---- phase B: compute PV(j+1) [odd chunk], prefetch j+2 ----
        __syncthreads();
        if (j < 62) {
            AV_LOAD(avA, j + 2);
            QK_STORE(0, kcA);                    // chunk j+2
            if (j < 61) KC_LOAD(kcB, j + 3);
        }
        PV_STEP(avB, 1);
    }
#undef AV_LOAD
#undef KC_LOAD
#undef QK_STORE
#undef PV_STEP

    // --- epilogue: combine khw halves via SB, 2 c-stripe rounds ---
    const float gm = gamma[0];
    for (int s = 0; s < 2; s++) {
        __syncthreads();
        if (khw == 0 && (cw >> 1) == s) {
            #pragma unroll
            for (int ct = 0; ct < 4; ct++)
                #pragma unroll
                for (int nt = 0; nt < 2; nt++)
                    #pragma unroll
                    for (int r = 0; r < 4; r++)
                        SB[64 * (cw & 1) + 16 * ct + 4 * quad + r][16 * nt + l16] = acc[ct][nt][r];
        }
        __syncthreads();
        if (khw == 1 && (cw >> 1) == s) {
            #pragma unroll
            for (int ct = 0; ct < 4; ct++)
                #pragma unroll
                for (int nt = 0; nt < 2; nt++)
                    #pragma unroll
                    for (int r = 0; r < 4; r++)
                        SB[64 * (cw & 1) + 16 * ct + 4 * quad + r][16 * nt + l16] += acc[ct][nt][r];
        }
        __syncthreads();
        // cooperative store: 128c x 32q with 512 threads, 2 passes of float4
        #pragma unroll
        for (int pass = 0; pass < 2; pass++) {
            int cl = (t >> 3) + 64 * pass;
            int n4 = (t & 7) * 4;
            float4 vv = *(float4*)&SB[cl][n4];
            float4 il4 = *(const float4*)(ilstat + (size_t)b * 4096 + qbase + n4);
            size_t idx = ((size_t)(b * 256 + 128 * s + cl)) * 4096 + qbase + n4;
            float4 xv = *(const float4*)(x2 + idx);
            float4 ov;
            ov.x = gm * vv.x * il4.x + xv.x;
            ov.y = gm * vv.y * il4.y + xv.y;
            ov.z = gm * vv.z * il4.z + xv.z;
            ov.w = gm * vv.w * il4.w + xv.w;
            *(float4*)(outp + idx) = ov;
        }
    }
}

// ---------------------------------------------------------------------------
extern "C" void kernel_launch(void* const* d_in, const int* in_sizes, int n_in,
                              void* d_out, int out_size, void* d_ws, size_t ws_size,
                              hipStream_t stream) {
    (void)in_sizes; (void)n_in; (void)out_size; (void)ws_size;
    const float* x    = (const float*)d_in[0];
    const float* W1   = (const float*)d_in[1];
    const float* b1   = (const float*)d_in[2];
    const float* W2   = (const float*)d_in[3];
    const float* b2   = (const float*)d_in[4];
    const float* Wq   = (const float*)d_in[5];
    const float* bq   = (const float*)d_in[6];
    const float* Wk   = (const float*)d_in[7];
    const float* bk   = (const float*)d_in[8];
    const float* Wv   = (const float*)d_in[9];
    const float* bv   = (const float*)d_in[10];
    const float* gam  = (const float*)d_in[11];
    const float* Wsp  = (const float*)d_in[12];
    const float* bn_g = (const float*)d_in[13];
    const float* bn_b = (const float*)d_in[14];
    const float* bn_m = (const float*)d_in[15];
    const float* bn_v = (const float*)d_in[16];

    float* ws = (float*)d_ws;
    float* bm2   = ws; ws += (size_t)4 * 256 * 1024;
    float* bm4   = ws; ws += (size_t)4 * 256 * 256;
    float* bm8   = ws; ws += (size_t)4 * 256 * 64;
    float* featA = ws; ws += 1024;
    float* fm1   = ws; ws += 1024;
    float* fm2   = ws; ws += 1024;
    float* fm4   = ws; ws += 1024;
    float* fm8   = ws; ws += 1024;
    float* g     = ws; ws += 1024;
    float* comp  = ws; ws += (size_t)4 * 2 * 4096;
    float* spg   = ws; ws += (size_t)4 * 4096;
    float* x2    = ws; ws += (size_t)4 * 256 * 4096;
    float* bm2b  = ws; ws += (size_t)4 * 256 * 1024;
    float* bm4b  = ws; ws += (size_t)4 * 256 * 256;
    float* bm8b  = ws; ws += (size_t)4 * 256 * 64;
    float* P2    = ws; ws += (size_t)4 * 320 * 1024;
    float* P4    = ws; ws += (size_t)4 * 320 * 256;
    float* P8    = ws; ws += (size_t)4 * 320 * 64;
    float* mstat = ws; ws += (size_t)4 * 4096;
    float* ilstat= ws; ws += (size_t)4 * 4096;
    unsigned short* qT  = (unsigned short*)ws; ws += (size_t)4 * 4096 * 32 / 2;
    unsigned short* kT  = (unsigned short*)ws; ws += (size_t)4 * 4096 * 32 / 2;
    unsigned short* vCp = (unsigned short*)ws; ws += (size_t)4 * 64 * 16384 / 2;
    unsigned short* x2T = (unsigned short*)ws; ws += (size_t)4 * 4096 * 256 / 2;
    unsigned short* WB  = (unsigned short*)ws; ws += (size_t)320 * 256 / 2;

    // Stage 1: channel gate (pyramid + fused weight-cast in the extra 80 blocks)
    k_pyramid<<<1104, 256, 0, stream>>>(x, nullptr, nullptr, nullptr,
                                        bm2, bm4, bm8, featA, fm1, fm2, fm4, fm8, 0,
                                        Wq, Wk, Wv, WB);
    // Stage 2: spatial gate (k3 with fused channel-gate MLP; writes g too)
    k3_comp<<<256, 256, 0, stream>>>(x, bm2, bm4, bm8,
                                     featA, fm1, fm2, fm4, fm8,
                                     W1, b1, W2, b2, g, comp);
    k4_spgate<<<256, 64, 0, stream>>>(comp, Wsp, bn_g, bn_b, bn_m, bn_v, spg);
    k_pyramid<<<1024, 256, 0, stream>>>(x, g, spg, x2,
                                        bm2b, bm4b, bm8b,
                                        nullptr, nullptr, nullptr, nullptr, nullptr, 1,
                                        Wq, Wk, Wv, WB);
    // x2 -> bf16 transposed [n][c]
    k_x2t<<<dim3(64, 4, 4), 256, 0, stream>>>(x2, x2T);
    // Stage 3: q/k/v projections, multiscale-decomposed
    k6_gemm<<<dim3(21, 5, 4), 256, 0, stream>>>(Wq, Wk, Wv, bm2b, bm4b, bm8b, P2, P4, P8);
    k6m<<<dim3(32, 5, 4), 256, 0, stream>>>(WB, x2T, bq, bk, bv, P2, P4, P8, qT, kT, vCp);
    // Two-pass attention: stats, then q-split 2-blocks/CU pipelined PV
    k7a_stats<<<256, 1024, 0, stream>>>(qT, kT, mstat, ilstat);
    k7b_attn<<<512, 512, 0, stream>>>(qT, kT, vCp, mstat, ilstat, x2, gam, (float*)d_out);
}

// Round 9
// 271.377 us; speedup vs baseline: 1.0650x; 1.0114x over previous
//
#include <hip/hip_runtime.h>
#include <math.h>

// Shapes (fixed): B=4, C=256, H=W=64, N=4096, 4C=1024, c8=32, r=16.

typedef float f32x4 __attribute__((ext_vector_type(4)));
typedef short s16x8 __attribute__((ext_vector_type(8)));
union FRAG { uint4 u; s16x8 s; };

__device__ __forceinline__ unsigned short f2bf(float f) {
    union { float f; unsigned int u; } v; v.f = f;
    unsigned int r = v.u + 0x7FFFu + ((v.u >> 16) & 1u);
    return (unsigned short)(r >> 16);
}

// ---------------------------------------------------------------------------
// K1/K5: per-(b,c) plane -> block-mean pyramid (+ feats in mode 0, x2 in mode 1)
// Mode-0 launch carries 80 extra blocks (bc >= 1024) that do the WB bf16
// weight-cast (fused former k_wcast — saves a launch).
// ---------------------------------------------------------------------------
__global__ __launch_bounds__(256) void k_pyramid(
    const float* __restrict__ xin, const float* __restrict__ gch,
    const float* __restrict__ spg, float* __restrict__ x2out,
    float* __restrict__ bm2, float* __restrict__ bm4, float* __restrict__ bm8,
    float* __restrict__ featA, float* __restrict__ fm1, float* __restrict__ fm2,
    float* __restrict__ fm4, float* __restrict__ fm8, int mode,
    const float* __restrict__ Wq, const float* __restrict__ Wk,
    const float* __restrict__ Wv, unsigned short* __restrict__ WB)
{
    __shared__ float sx[4096];
    __shared__ float s2[1024];
    __shared__ float s4[256];
    __shared__ float wred[4][8];
    const int bc = blockIdx.x;
    const int t = threadIdx.x;
    if (mode == 0 && bc >= 1024) {
        // fused weight cast: WB[320][256], 80 blocks x 1024 entries
        const int e0 = (bc - 1024) * 1024 + t * 4;
        const int o = e0 >> 8, col = e0 & 255;
        const float* row = (o < 32) ? (Wq + (size_t)o * 1024)
                          : (o < 64) ? (Wk + (size_t)(o - 32) * 1024)
                                     : (Wv + (size_t)(o - 64) * 1024);
        float4 v = *(const float4*)(row + 768 + col);
        uint2 pk;
        pk.x = (unsigned)f2bf(v.x) | ((unsigned)f2bf(v.y) << 16);
        pk.y = (unsigned)f2bf(v.z) | ((unsigned)f2bf(v.w) << 16);
        *(uint2*)(WB + e0) = pk;
        return;
    }
    const int b = bc >> 8;
    const float* xp = xin + (size_t)bc * 4096;
    float gc = 1.f;
    if (mode == 1) gc = gch[bc];
    float sum = 0.f, mx = -1e30f;
    for (int r = 0; r < 4; r++) {
        int i4 = t + 256 * r;
        float4 v = ((const float4*)xp)[i4];
        if (mode == 1) {
            float4 sg = ((const float4*)(spg + (size_t)b * 4096))[i4];
            v.x *= gc * sg.x; v.y *= gc * sg.y; v.z *= gc * sg.z; v.w *= gc * sg.w;
            ((float4*)(x2out + (size_t)bc * 4096))[i4] = v;
        } else {
            sum += v.x + v.y + v.z + v.w;
            mx = fmaxf(mx, fmaxf(fmaxf(v.x, v.y), fmaxf(v.z, v.w)));
        }
        ((float4*)sx)[i4] = v;
    }
    __syncthreads();
    float mx2 = -1e30f;
    for (int r = 0; r < 4; r++) {
        int i = t + 256 * r;
        int r2 = i >> 5, c2 = i & 31;
        int p0 = 128 * r2 + 2 * c2;
        float v = 0.25f * (sx[p0] + sx[p0 + 1] + sx[p0 + 64] + sx[p0 + 65]);
        s2[i] = v;
        bm2[(size_t)bc * 1024 + i] = v;
        mx2 = fmaxf(mx2, v);
    }
    __syncthreads();
    float mx4;
    {
        int r4 = t >> 4, c4 = t & 15;
        int p0 = 64 * r4 + 2 * c4;
        float v = 0.25f * (s2[p0] + s2[p0 + 1] + s2[p0 + 32] + s2[p0 + 33]);
        s4[t] = v;
        bm4[(size_t)bc * 256 + t] = v;
        mx4 = v;
    }
    __syncthreads();
    float mx8 = -1e30f;
    if (t < 64) {
        int r8 = t >> 3, c8 = t & 7;
        int p0 = 32 * r8 + 2 * c8;
        float v = 0.25f * (s4[p0] + s4[p0 + 1] + s4[p0 + 16] + s4[p0 + 17]);
        bm8[(size_t)bc * 64 + t] = v;
        mx8 = v;
    }
    if (mode == 0) {
        float vs = sum, v1 = mx, v2 = mx2, v4 = mx4, v8 = mx8;
        #pragma unroll
        for (int o = 1; o < 64; o <<= 1) {
            vs += __shfl_xor(vs, o);
            v1 = fmaxf(v1, __shfl_xor(v1, o));
            v2 = fmaxf(v2, __shfl_xor(v2, o));
            v4 = fmaxf(v4, __shfl_xor(v4, o));
            v8 = fmaxf(v8, __shfl_xor(v8, o));
        }
        if ((t & 63) == 0) {
            int wd = t >> 6;
            wred[wd][0] = vs; wred[wd][1] = v1; wred[wd][2] = v2;
            wred[wd][3] = v4; wred[wd][4] = v8;
        }
        __syncthreads();
        if (t == 0) featA[bc] = (wred[0][0] + wred[1][0] + wred[2][0] + wred[3][0]) * (1.f / 4096.f);
        else if (t == 1) fm1[bc] = fmaxf(fmaxf(wred[0][1], wred[1][1]), fmaxf(wred[2][1], wred[3][1]));
        else if (t == 2) fm2[bc] = fmaxf(fmaxf(wred[0][2], wred[1][2]), fmaxf(wred[2][2], wred[3][2]));
        else if (t == 3) fm4[bc] = fmaxf(fmaxf(wred[0][3], wred[1][3]), fmaxf(wred[2][3], wred[3][3]));
        else if (t == 4) fm8[bc] = fmaxf(fmaxf(wred[0][4], wred[1][4]), fmaxf(wred[2][4], wred[3][4]));
    }
}

// ---------------------------------------------------------------------------
// K3: spatial-gate input, with the channel-gate MLP FUSED (former k2).
// ---------------------------------------------------------------------------
__global__ __launch_bounds__(256) void k3_comp(
    const float* __restrict__ x, const float* __restrict__ bm2,
    const float* __restrict__ bm4, const float* __restrict__ bm8,
    const float* __restrict__ featA, const float* __restrict__ fm1,
    const float* __restrict__ fm2, const float* __restrict__ fm4,
    const float* __restrict__ fm8,
    const float* __restrict__ W1, const float* __restrict__ b1,
    const float* __restrict__ W2, const float* __restrict__ b2,
    float* __restrict__ g, float* __restrict__ comp)
{
    __shared__ float sf[5][256];
    __shared__ float sh[5][16];
    __shared__ float hs[16];
    __shared__ float sg[256];
    __shared__ float rmx[4][64];
    __shared__ float rsm[4][64];
    const int b = blockIdx.x >> 6;
    const int t = threadIdx.x;
    // --- inline channel-gate MLP (identical math to former k2_gate) ---
    sf[0][t] = featA[(b << 8) + t];
    sf[1][t] = fm1[(b << 8) + t];
    sf[2][t] = fm2[(b << 8) + t];
    sf[3][t] = fm4[(b << 8) + t];
    sf[4][t] = fm8[(b << 8) + t];
    __syncthreads();
    if (t < 80) {
        int f = t / 16, j = t % 16;
        float a = b1[j];
        for (int c = 0; c < 256; c++) a += sf[f][c] * W1[c * 16 + j];
        sh[f][j] = fmaxf(a, 0.f);
    }
    __syncthreads();
    if (t < 16) hs[t] = 4.f * sh[0][t] + sh[1][t] + sh[2][t] + sh[3][t] + sh[4][t];
    __syncthreads();
    {
        float a = 8.f * b2[t];
        for (int j = 0; j < 16; j++) a += hs[j] * W2[j * 256 + t];
        sg[t] = 1.f / (1.f + __expf(-a));
    }
    __syncthreads();
    if ((blockIdx.x & 63) == 0) g[(b << 8) + t] = sg[t];   // for k_pyramid mode 1
    // --- original k3 body ---
    const int pix = ((blockIdx.x & 63) << 6) + (t & 63);
    const int wid = t >> 6;
    const int c0 = wid << 6;
    const int h = pix >> 6, w = pix & 63;
    const int i2 = ((h >> 1) << 5) + (w >> 1);
    const int i4 = ((h >> 2) << 4) + (w >> 2);
    const int i8 = ((h >> 3) << 3) + (w >> 3);
    const float* xb = x + ((size_t)b << 8) * 4096;
    const float* p2 = bm2 + ((size_t)b << 8) * 1024;
    const float* p4 = bm4 + ((size_t)b << 8) * 256;
    const float* p8 = bm8 + ((size_t)b << 8) * 64;
    float mx = -1e30f, sm = 0.f;
    for (int c = c0; c < c0 + 64; c++) {
        float gc = sg[c];
        float xv = xb[(size_t)c * 4096 + pix] * gc;
        float v2 = p2[c * 1024 + i2] * gc;
        float v4 = p4[c * 256 + i4] * gc;
        float v8 = p8[c * 64 + i8] * gc;
        mx = fmaxf(fmaxf(mx, xv), fmaxf(fmaxf(v2, v4), v8));
        sm += xv + v2 + v4 + v8;
    }
    rmx[wid][t & 63] = mx;
    rsm[wid][t & 63] = sm;
    __syncthreads();
    if (wid == 0) {
        int l = t;
        float m = fmaxf(fmaxf(rmx[0][l], rmx[1][l]), fmaxf(rmx[2][l], rmx[3][l]));
        float s = rsm[0][l] + rsm[1][l] + rsm[2][l] + rsm[3][l];
        comp[((size_t)b * 2) * 4096 + pix] = m;
        comp[((size_t)b * 2 + 1) * 4096 + pix] = s * (1.f / 1024.f);
    }
}

// ---------------------------------------------------------------------------
// K4: 7x7 conv (2->1, pad 3, no bias) + BN(eval) + sigmoid. Grid 256 x 64thr.
// ---------------------------------------------------------------------------
__global__ __launch_bounds__(64) void k4_spgate(
    const float* __restrict__ comp, const float* __restrict__ Wsp,
    const float* __restrict__ bn_g, const float* __restrict__ bn_b,
    const float* __restrict__ bn_m, const float* __restrict__ bn_v,
    float* __restrict__ spg)
{
    __shared__ float w[98];
    const int t = threadIdx.x;
    for (int i = t; i < 98; i += 64) w[i] = Wsp[i];
    __syncthreads();
    const int b = blockIdx.x >> 6;
    const int pix = ((blockIdx.x & 63) << 6) + t;
    const int h = pix >> 6, wx = pix & 63;
    const float* c0 = comp + (size_t)b * 2 * 4096;
    float acc = 0.f;
    for (int ci = 0; ci < 2; ci++)
        for (int kh = 0; kh < 7; kh++) {
            int hh = h + kh - 3;
            if (hh < 0 || hh >= 64) continue;
            for (int kw = 0; kw < 7; kw++) {
                int wwp = wx + kw - 3;
                if (wwp < 0 || wwp >= 64) continue;
                acc += c0[ci * 4096 + hh * 64 + wwp] * w[ci * 49 + kh * 7 + kw];
            }
        }
    float sc = rsqrtf(bn_v[0] + 1e-5f) * bn_g[0];
    float sp = (acc - bn_m[0]) * sc + bn_b[0];
    spg[b * 4096 + pix] = 1.f / (1.f + __expf(-sp));
}

// ---------------------------------------------------------------------------
// K_X2T: x2 fp32 [b][256 c][4096 n] -> x2T bf16 [b][4096 n][256 c]
// ---------------------------------------------------------------------------
__global__ __launch_bounds__(256) void k_x2t(
    const float* __restrict__ x2, unsigned short* __restrict__ x2T)
{
    __shared__ unsigned short T[64][72];
    const int b = blockIdx.z;
    const int cb = blockIdx.y * 64;
    const int nb = blockIdx.x * 64;
    const int t = threadIdx.x;
    #pragma unroll
    for (int r = 0; r < 16; r++) {
        int cl = (t >> 6) + 4 * r;
        int nl = t & 63;
        float v = x2[((size_t)(b * 256 + cb + cl)) * 4096 + nb + nl];
        T[nl][cl] = f2bf(v);
    }
    __syncthreads();
    #pragma unroll
    for (int pass = 0; pass < 4; pass++) {
        int nl = (t >> 4) + 16 * pass;
        int c4 = (t & 15) * 4;
        uint2 pk;
        pk.x = (unsigned)T[nl][c4] | ((unsigned)T[nl][c4 + 1] << 16);
        pk.y = (unsigned)T[nl][c4 + 2] | ((unsigned)T[nl][c4 + 3] << 16);
        *(uint2*)(x2T + ((size_t)(b * 4096 + nb + nl)) * 256 + cb + c4) = pk;
    }
}

// ---------------------------------------------------------------------------
// K6: fp32 projection GEMM for low-res P2/P4/P8, all three scales in ONE
// launch: blockIdx.x 0..15 -> P2, 16..19 -> P4, 20 -> P8.
// ---------------------------------------------------------------------------
__global__ __launch_bounds__(256) void k6_gemm(
    const float* __restrict__ Wq, const float* __restrict__ Wk, const float* __restrict__ Wv,
    const float* __restrict__ bm2b, const float* __restrict__ bm4b, const float* __restrict__ bm8b,
    float* __restrict__ P2, float* __restrict__ P4, float* __restrict__ P8)
{
    __shared__ float At[32][68];
    __shared__ float Bt[32][64];
    const int bx = blockIdx.x;
    int col_off, ns, nb;
    const float* src;
    float* outp;
    if (bx < 16)      { col_off = 0;   src = bm2b; ns = 1024; outp = P2; nb = bx; }
    else if (bx < 20) { col_off = 256; src = bm4b; ns = 256;  outp = P4; nb = bx - 16; }
    else              { col_off = 512; src = bm8b; ns = 64;   outp = P8; nb = 0; }
    const int b = blockIdx.z;
    const int o_base = blockIdx.y * 64;
    const int n_base = nb * 64;
    const int t = threadIdx.x;
    const int tn = t >> 4, tm = t & 15;
    const int lk = t & 31, lo8 = t >> 5;
    const int ln = t & 63, lk4 = t >> 6;
    float acc[4][4];
    #pragma unroll
    for (int i = 0; i < 4; i++)
        #pragma unroll
        for (int j = 0; j < 4; j++) acc[i][j] = 0.f;
    for (int k0 = 0; k0 < 256; k0 += 32) {
        __syncthreads();
        #pragma unroll
        for (int r = 0; r < 8; r++) {
            int o = o_base + lo8 + 8 * r;
            const float* wrow = (o < 32) ? (Wq + (size_t)o * 1024)
                              : (o < 64) ? (Wk + (size_t)(o - 32) * 1024)
                                         : (Wv + (size_t)(o - 64) * 1024);
            At[lk][lo8 + 8 * r] = wrow[col_off + k0 + lk];
        }
        #pragma unroll
        for (int r = 0; r < 8; r++)
            Bt[lk4 + 4 * r][ln] = src[((size_t)b * 256 + k0 + lk4 + 4 * r) * ns + n_base + ln];
        __syncthreads();
        #pragma unroll
        for (int kk = 0; kk < 32; kk++) {
            float4 a = *(const float4*)&At[kk][4 * tn];
            float4 bb = *(const float4*)&Bt[kk][4 * tm];
            acc[0][0] += a.x * bb.x; acc[0][1] += a.x * bb.y; acc[0][2] += a.x * bb.z; acc[0][3] += a.x * bb.w;
            acc[1][0] += a.y * bb.x; acc[1][1] += a.y * bb.y; acc[1][2] += a.y * bb.z; acc[1][3] += a.y * bb.w;
            acc[2][0] += a.z * bb.x; acc[2][1] += a.z * bb.y; acc[2][2] += a.z * bb.z; acc[2][3] += a.z * bb.w;
            acc[3][0] += a.w * bb.x; acc[3][1] += a.w * bb.y; acc[3][2] += a.w * bb.z; acc[3][3] += a.w * bb.w;
        }
    }
    #pragma unroll
    for (int i = 0; i < 4; i++)
        #pragma unroll
        for (int j = 0; j < 4; j++)
            outp[((size_t)b * 320 + o_base + 4 * tn + i) * ns + n_base + 4 * tm + j] = acc[i][j];
}

// ---------------------------------------------------------------------------
// K6M: full-res projection via bf16 MFMA, now XCD-PINNED: 1-D grid 640,
// b = (bid>>1)&3 -> each XCD owns one (b, parity): its P2/P4/P8 (~1.7MB)
// + x2T slice stay L2-resident (was: 3-D grid spread all b over all XCDs,
// ~7MB P working set vs 4MB/XCD L2 -> misses on the 96 scalar gather
// loads/lane in the epilogue).
// v writes go to FRAG-CONTIGUOUS layout (see k7b AV_LOAD).
// ---------------------------------------------------------------------------
__global__ __launch_bounds__(256) void k6m(
    const unsigned short* __restrict__ WB, const unsigned short* __restrict__ x2T,
    const float* __restrict__ bq, const float* __restrict__ bk, const float* __restrict__ bv,
    const float* __restrict__ P2, const float* __restrict__ P4, const float* __restrict__ P8,
    unsigned short* __restrict__ qT, unsigned short* __restrict__ kT,
    unsigned short* __restrict__ vC)
{
    const int bid = blockIdx.x;
    const int b = (bid >> 1) & 3;
    const int rest = ((bid >> 3) << 1) | (bid & 1);   // 0..159
    const int nb = (rest & 31) * 128;
    const int obase = (rest >> 5) * 64;
    const int t = threadIdx.x;
    const int w_ = t >> 6, lane = t & 63;
    const int quad = lane >> 4, l16 = lane & 15;
    const int nbase = nb + 32 * w_;
    f32x4 acc[4][2];
    #pragma unroll
    for (int ot = 0; ot < 4; ot++)
        #pragma unroll
        for (int nt = 0; nt < 2; nt++) { acc[ot][nt][0] = 0.f; acc[ot][nt][1] = 0.f; acc[ot][nt][2] = 0.f; acc[ot][nt][3] = 0.f; }
    const unsigned short* xb = x2T + ((size_t)b * 4096 + nbase) * 256;
    for (int k0 = 0; k0 < 256; k0 += 32) {
        FRAG af[4], bf[2];
        #pragma unroll
        for (int ot = 0; ot < 4; ot++)
            af[ot].u = *(const uint4*)(WB + (size_t)(obase + 16 * ot + l16) * 256 + k0 + quad * 8);
        #pragma unroll
        for (int nt = 0; nt < 2; nt++)
            bf[nt].u = *(const uint4*)(xb + (size_t)(16 * nt + l16) * 256 + k0 + quad * 8);
        #pragma unroll
        for (int ot = 0; ot < 4; ot++)
            #pragma unroll
            for (int nt = 0; nt < 2; nt++)
                acc[ot][nt] = __builtin_amdgcn_mfma_f32_16x16x32_bf16(af[ot].s, bf[nt].s, acc[ot][nt], 0, 0, 0);
    }
    #pragma unroll
    for (int ot = 0; ot < 4; ot++) {
        #pragma unroll
        for (int nt = 0; nt < 2; nt++) {
            int n = nbase + 16 * nt + l16;
            int h = n >> 6, wx = n & 63;
            int i2 = ((h >> 1) << 5) + (wx >> 1);
            int i4 = ((h >> 2) << 4) + (wx >> 2);
            int i8 = ((h >> 3) << 3) + (wx >> 3);
            float vals[4];
            #pragma unroll
            for (int r = 0; r < 4; r++) {
                int o = obase + 16 * ot + 4 * quad + r;
                float bias = (o < 32) ? bq[o] : (o < 64) ? bk[o - 32] : bv[o - 64];
                size_t ro = (size_t)b * 320 + o;
                vals[r] = acc[ot][nt][r] + bias
                        + P2[ro * 1024 + i2] + P4[ro * 256 + i4] + P8[ro * 64 + i8];
            }
            int o0 = obase + 16 * ot + 4 * quad;
            if (o0 < 64) {
                uint2 pk;
                pk.x = (unsigned)f2bf(vals[0]) | ((unsigned)f2bf(vals[1]) << 16);
                pk.y = (unsigned)f2bf(vals[2]) | ((unsigned)f2bf(vals[3]) << 16);
                if (o0 < 32)
                    *(uint2*)(qT + ((size_t)(b * 4096 + n)) * 32 + o0) = pk;
                else
                    *(uint2*)(kT + ((size_t)(b * 4096 + n)) * 32 + (o0 - 32)) = pk;
            } else {
                int chunk = n >> 6;
                int kk = n & 63;
                int khw_ = (kk >> 5) & 1, qd = (kk >> 3) & 3, ko = kk & 7;
                unsigned short* dst = vC + (((size_t)b * 64 + chunk) << 14);
                #pragma unroll
                for (int r = 0; r < 4; r++) {
                    int c = o0 - 64 + r;
                    dst[((((c >> 4) << 1) + khw_) << 9) + ((qd * 16 + (c & 15)) << 3) + ko] = f2bf(vals[r]);
                }
            }
        }
    }
}

// ---------------------------------------------------------------------------
// K7A: softmax stats pass (dense kT reads), XCD-pinned bid decode.
// ---------------------------------------------------------------------------
__global__ __launch_bounds__(1024, 4) void k7a_stats(
    const unsigned short* __restrict__ qT, const unsigned short* __restrict__ kT,
    float* __restrict__ mout, float* __restrict__ ilout)
{
    __shared__ float sm[4][4][16], sl[4][4][16];   // [g][s][l16]
    const int bid = blockIdx.x;
    const int b = (bid >> 1) & 3;
    const int qbase = (((bid >> 3) << 1) | (bid & 1)) << 6;
    const int t = threadIdx.x;
    const int wid = t >> 6, lane = t & 63;
    const int g_ = wid >> 2, s_ = wid & 3;
    const int quad = lane >> 4, l16 = lane & 15;

    FRAG qf;
    qf.u = *(const uint4*)(qT + ((size_t)(b * 4096 + qbase + 16 * g_ + l16)) * 32 + quad * 8);
    const unsigned short* kTb = kT + (size_t)b * 4096 * 32;

    float m_run = -1e30f, l_run = 0.f;
    for (int j = 0; j < 16; j++) {
        const int mo = (s_ << 10) + (j << 6);
        f32x4 e[4];
        #pragma unroll
        for (int mt = 0; mt < 4; mt++) {
            FRAG kf;
            kf.u = *(const uint4*)(kTb + (size_t)(mo + 16 * mt + l16) * 32 + quad * 8);
            f32x4 z; z[0] = 0.f; z[1] = 0.f; z[2] = 0.f; z[3] = 0.f;
            e[mt] = __builtin_amdgcn_mfma_f32_16x16x32_bf16(kf.s, qf.s, z, 0, 0, 0);
        }
        float pm = e[0][0];
        #pragma unroll
        for (int mt = 0; mt < 4; mt++)
            #pragma unroll
            for (int r = 0; r < 4; r++) pm = fmaxf(pm, e[mt][r]);
        float mnew = fmaxf(m_run, pm);
        float al = __expf(m_run - mnew);
        float ps = 0.f;
        #pragma unroll
        for (int mt = 0; mt < 4; mt++)
            #pragma unroll
            for (int r = 0; r < 4; r++) ps += __expf(e[mt][r] - mnew);
        l_run = l_run * al + ps;
        m_run = mnew;
    }
    #pragma unroll
    for (int o = 16; o < 64; o <<= 1) {
        float mo_ = __shfl_xor(m_run, o);
        float lo_ = __shfl_xor(l_run, o);
        float m2 = fmaxf(m_run, mo_);
        l_run = l_run * __expf(m_run - m2) + lo_ * __expf(mo_ - m2);
        m_run = m2;
    }
    if (quad == 0) { sm[g_][s_][l16] = m_run; sl[g_][s_][l16] = l_run; }
    __syncthreads();
    if (t < 64) {
        int g = t >> 4, l = t & 15;
        float m0 = sm[g][0][l], m1 = sm[g][1][l], m2 = sm[g][2][l], m3 = sm[g][3][l];
        float mx = fmaxf(fmaxf(m0, m1), fmaxf(m2, m3));
        float l_ = sl[g][0][l] * __expf(m0 - mx) + sl[g][1][l] * __expf(m1 - mx)
                 + sl[g][2][l] * __expf(m2 - mx) + sl[g][3][l] * __expf(m3 - mx);
        int n = qbase + 16 * g + l;
        mout[b * 4096 + n] = mx;
        ilout[b * 4096 + n] = 1.f / l_;
    }
}

// ---------------------------------------------------------------------------
// K7B v16 = v10 VERBATIM (the proven 56.6 µs structure: 64q x 256c, 8 waves,
// 1 block/CU, 2-barrier pipeline, acc[4][4]) + XCD-pinned bid decode (pure
// (b,q)<->block relabeling; proven to cut FETCH 45.7 -> ~18 MB).
// Six structural variants (v11-v15) all lost to v10; reverting.
// ---------------------------------------------------------------------------
__global__ __launch_bounds__(512) void k7b_attn(
    const unsigned short* __restrict__ qT, const unsigned short* __restrict__ kT,
    const unsigned short* __restrict__ vC, const float* __restrict__ mstat,
    const float* __restrict__ ilstat, const float* __restrict__ x2,
    const float* __restrict__ gamma, float* __restrict__ outp)
{
    __shared__ __align__(16) unsigned short PL[2][64][64];  // 16 KB swizzled P
    __shared__ float SB[128][68];                           // 34.8 KB combine buffer
    const int bid = blockIdx.x;
    const int b = (bid >> 1) & 3;
    const int qbase = (((bid >> 3) << 1) | (bid & 1)) << 6;
    const int t = threadIdx.x;
    const int wid = t >> 6, lane = t & 63;
    const int cw = wid & 3, khw = wid >> 2;
    const int quad = lane >> 4, l16 = lane & 15;
    const int ntq = wid & 3;                // QK n-tile of this wave
    const int mt0 = 2 * khw, mt1 = 2 * khw + 1;
    const int nq = qbase + 16 * ntq + l16;  // column of this wave's P rows

    FRAG qf;
    qf.u = *(const uint4*)(qT + ((size_t)(b * 4096 + nq)) * 32 + quad * 8);
    const float mN = mstat[b * 4096 + nq];

    f32x4 acc[4][4];
    #pragma unroll
    for (int ct = 0; ct < 4; ct++)
        #pragma unroll
        for (int nt = 0; nt < 4; nt++) { acc[ct][nt][0] = 0.f; acc[ct][nt][1] = 0.f; acc[ct][nt][2] = 0.f; acc[ct][nt][3] = 0.f; }
    const unsigned short* kTb = kT + (size_t)b * 4096 * 32;
    // per-wave V-frag base: frag (c16 = 4*cw + ct, khw), lane-contiguous.
    const unsigned short* vfb = vC + ((size_t)b * 64 << 14)
                              + (((8 * cw) + khw) << 9) + lane * 8;

    // PL swizzle constants (granule = 8 shorts = 16 B)
    const int po  = 4 * (quad & 1);
    const int pg0 = ((4 * khw + (quad >> 1)) ^ (l16 & 7));        // pkA granule
    const int pg1 = ((4 * khw + 2 + (quad >> 1)) ^ (l16 & 7));    // pkB granule
    const int pgr = ((4 * khw + quad) ^ (l16 & 7)) << 3;          // bp read offset

    FRAG avA[4], avB[4], kc0, kc1;

#define AV_LOAD(AV, CH) do { \
    const unsigned short* vfj = vfb + ((size_t)(CH) << 14); \
    AV[0].u = *(const uint4*)(vfj); \
    AV[1].u = *(const uint4*)(vfj + 1024); \
    AV[2].u = *(const uint4*)(vfj + 2048); \
    AV[3].u = *(const uint4*)(vfj + 3072); \
} while (0)

#define KC_LOAD(CH) do { \
    const int mo_ = (CH) << 6; \
    kc0.u = *(const uint4*)(kTb + (size_t)(mo_ + 16 * mt0 + l16) * 32 + quad * 8); \
    kc1.u = *(const uint4*)(kTb + (size_t)(mo_ + 16 * mt1 + l16) * 32 + quad * 8); \
} while (0)

#define QK_EXP_STORE(DST) do { \
    f32x4 z; z[0] = 0.f; z[1] = 0.f; z[2] = 0.f; z[3] = 0.f; \
    f32x4 e0 = __builtin_amdgcn_mfma_f32_16x16x32_bf16(kc0.s, qf.s, z, 0, 0, 0); \
    f32x4 e1 = __builtin_amdgcn_mfma_f32_16x16x32_bf16(kc1.s, qf.s, z, 0, 0, 0); \
    union { float f; unsigned int u; } p0, p1, p2, p3; \
    uint2 pkA, pkB; \
    p0.f = __expf(e0[0] - mN); p1.f = __expf(e0[1] - mN); \
    p2.f = __expf(e0[2] - mN); p3.f = __expf(e0[3] - mN); \
    pkA.x = __builtin_amdgcn_perm(p1.u, p0.u, 0x07060302u); \
    pkA.y = __builtin_amdgcn_perm(p3.u, p2.u, 0x07060302u); \
    p0.f = __expf(e1[0] - mN); p1.f = __expf(e1[1] - mN); \
    p2.f = __expf(e1[2] - mN); p3.f = __expf(e1[3] - mN); \
    pkB.x = __builtin_amdgcn_perm(p1.u, p0.u, 0x07060302u); \
    pkB.y = __builtin_amdgcn_perm(p3.u, p2.u, 0x07060302u); \
    *(uint2*)&PL[DST][16 * ntq + l16][(pg0 << 3) + po] = pkA; \
    *(uint2*)&PL[DST][16 * ntq + l16][(pg1 << 3) + po] = pkB; \
} while (0)

#define PV_STEP(AV, CUR) do { \
    FRAG bp[4]; \
    _Pragma("unroll") \
    for (int nt = 0; nt < 4; nt++) \
        bp[nt].u = *(const uint4*)&PL[CUR][16 * nt + l16][pgr]; \
    __builtin_amdgcn_s_setprio(1); \
    _Pragma("unroll") \
    for (int ct = 0; ct < 4; ct++) { \
        _Pragma("unroll") \
        for (int nt = 0; nt < 4; nt++) \
            acc[ct][nt] = __builtin_amdgcn_mfma_f32_16x16x32_bf16(AV[ct].s, bp[nt].s, acc[ct][nt], 0, 0, 0); \
    } \
    __builtin_amdgcn_s_setprio(0); \
} while (0)

    // --- prologue: av(0); QK(0)->PL[0]; kc for chunk 1 ---
    AV_LOAD(avA, 0);
    KC_LOAD(0);
    QK_EXP_STORE(0);
    KC_LOAD(1);

    for (int jj = 0; jj < 32; jj++) {
        const int j = 2 * jj;
        // ---- phase A: compute PV(j) [even chunk], prefetch j+1 ----
        __syncthreads();
        {
            AV_LOAD(avB, j + 1);
            QK_EXP_STORE(1);
            if (j < 62) KC_LOAD(j + 2);
        }
        PV_STEP(avA, 0);
        // ---- phase B: compute PV(j+1) [odd chunk], prefetch j+2 ----
        __syncthreads();
        if (j < 62) {
            AV_LOAD(avA, j + 2);
            QK_EXP_STORE(0);
            if (j < 61) KC_LOAD(j + 3);
        }
        PV_STEP(avB, 1);
    }
#undef AV_LOAD
#undef KC_LOAD
#undef QK_EXP_STORE
#undef PV_STEP

    // --- epilogue: combine khw halves via SB, 2 c-stripe rounds ---
    const float gm = gamma[0];
    for (int s = 0; s < 2; s++) {
        __syncthreads();
        if (khw == 0 && (cw >> 1) == s) {
            #pragma unroll
            for (int ct = 0; ct < 4; ct++)
                #pragma unroll
                for (int nt = 0; nt < 4; nt++)
                    #pragma unroll
                    for (int r = 0; r < 4; r++)
                        SB[64 * (cw & 1) + 16 * ct + 4 * quad + r][16 * nt + l16] = acc[ct][nt][r];
        }
        __syncthreads();
        if (khw == 1 && (cw >> 1) == s) {
            #pragma unroll
            for (int ct = 0; ct < 4; ct++)
                #pragma unroll
                for (int nt = 0; nt < 4; nt++)
                    #pragma unroll
                    for (int r = 0; r < 4; r++)
                        SB[64 * (cw & 1) + 16 * ct + 4 * quad + r][16 * nt + l16] += acc[ct][nt][r];
        }
        __syncthreads();
        // cooperative store: 128c x 64n
        #pragma unroll
        for (int pass = 0; pass < 4; pass++) {
            int cl = (t >> 4) + 32 * pass;
            int n4 = (t & 15) * 4;
            float4 vv = *(float4*)&SB[cl][n4];
            float4 il4 = *(const float4*)(ilstat + (size_t)b * 4096 + qbase + n4);
            size_t idx = ((size_t)(b * 256 + 128 * s + cl)) * 4096 + qbase + n4;
            float4 xv = *(const float4*)(x2 + idx);
            float4 ov;
            ov.x = gm * vv.x * il4.x + xv.x;
            ov.y = gm * vv.y * il4.y + xv.y;
            ov.z = gm * vv.z * il4.z + xv.z;
            ov.w = gm * vv.w * il4.w + xv.w;
            *(float4*)(outp + idx) = ov;
        }
    }
}

// ---------------------------------------------------------------------------
extern "C" void kernel_launch(void* const* d_in, const int* in_sizes, int n_in,
                              void* d_out, int out_size, void* d_ws, size_t ws_size,
                              hipStream_t stream) {
    (void)in_sizes; (void)n_in; (void)out_size; (void)ws_size;
    const float* x    = (const float*)d_in[0];
    const float* W1   = (const float*)d_in[1];
    const float* b1   = (const float*)d_in[2];
    const float* W2   = (const float*)d_in[3];
    const float* b2   = (const float*)d_in[4];
    const float* Wq   = (const float*)d_in[5];
    const float* bq   = (const float*)d_in[6];
    const float* Wk   = (const float*)d_in[7];
    const float* bk   = (const float*)d_in[8];
    const float* Wv   = (const float*)d_in[9];
    const float* bv   = (const float*)d_in[10];
    const float* gam  = (const float*)d_in[11];
    const float* Wsp  = (const float*)d_in[12];
    const float* bn_g = (const float*)d_in[13];
    const float* bn_b = (const float*)d_in[14];
    const float* bn_m = (const float*)d_in[15];
    const float* bn_v = (const float*)d_in[16];

    float* ws = (float*)d_ws;
    float* bm2   = ws; ws += (size_t)4 * 256 * 1024;
    float* bm4   = ws; ws += (size_t)4 * 256 * 256;
    float* bm8   = ws; ws += (size_t)4 * 256 * 64;
    float* featA = ws; ws += 1024;
    float* fm1   = ws; ws += 1024;
    float* fm2   = ws; ws += 1024;
    float* fm4   = ws; ws += 1024;
    float* fm8   = ws; ws += 1024;
    float* g     = ws; ws += 1024;
    float* comp  = ws; ws += (size_t)4 * 2 * 4096;
    float* spg   = ws; ws += (size_t)4 * 4096;
    float* x2    = ws; ws += (size_t)4 * 256 * 4096;
    float* bm2b  = ws; ws += (size_t)4 * 256 * 1024;
    float* bm4b  = ws; ws += (size_t)4 * 256 * 256;
    float* bm8b  = ws; ws += (size_t)4 * 256 * 64;
    float* P2    = ws; ws += (size_t)4 * 320 * 1024;
    float* P4    = ws; ws += (size_t)4 * 320 * 256;
    float* P8    = ws; ws += (size_t)4 * 320 * 64;
    float* mstat = ws; ws += (size_t)4 * 4096;
    float* ilstat= ws; ws += (size_t)4 * 4096;
    unsigned short* qT  = (unsigned short*)ws; ws += (size_t)4 * 4096 * 32 / 2;
    unsigned short* kT  = (unsigned short*)ws; ws += (size_t)4 * 4096 * 32 / 2;
    unsigned short* vCp = (unsigned short*)ws; ws += (size_t)4 * 64 * 16384 / 2;
    unsigned short* x2T = (unsigned short*)ws; ws += (size_t)4 * 4096 * 256 / 2;
    unsigned short* WB  = (unsigned short*)ws; ws += (size_t)320 * 256 / 2;

    // Stage 1: channel gate (pyramid + fused weight-cast in the extra 80 blocks)
    k_pyramid<<<1104, 256, 0, stream>>>(x, nullptr, nullptr, nullptr,
                                        bm2, bm4, bm8, featA, fm1, fm2, fm4, fm8, 0,
                                        Wq, Wk, Wv, WB);
    // Stage 2: spatial gate (k3 with fused channel-gate MLP; writes g too)
    k3_comp<<<256, 256, 0, stream>>>(x, bm2, bm4, bm8,
                                     featA, fm1, fm2, fm4, fm8,
                                     W1, b1, W2, b2, g, comp);
    k4_spgate<<<256, 64, 0, stream>>>(comp, Wsp, bn_g, bn_b, bn_m, bn_v, spg);
    k_pyramid<<<1024, 256, 0, stream>>>(x, g, spg, x2,
                                        bm2b, bm4b, bm8b,
                                        nullptr, nullptr, nullptr, nullptr, nullptr, 1,
                                        Wq, Wk, Wv, WB);
    // x2 -> bf16 transposed [n][c]
    k_x2t<<<dim3(64, 4, 4), 256, 0, stream>>>(x2, x2T);
    // Stage 3: q/k/v projections
    k6_gemm<<<dim3(21, 5, 4), 256, 0, stream>>>(Wq, Wk, Wv, bm2b, bm4b, bm8b, P2, P4, P8);
    k6m<<<640, 256, 0, stream>>>(WB, x2T, bq, bk, bv, P2, P4, P8, qT, kT, vCp);
    // Two-pass attention: stats, then the proven v10 PV (+XCD pinning)
    k7a_stats<<<256, 1024, 0, stream>>>(qT, kT, mstat, ilstat);
    k7b_attn<<<256, 512, 0, stream>>>(qT, kT, vCp, mstat, ilstat, x2, gam, (float*)d_out);
}

// Round 10
// 268.383 us; speedup vs baseline: 1.0769x; 1.0112x over previous
//
#include <hip/hip_runtime.h>
#include <math.h>

// Shapes (fixed): B=4, C=256, H=W=64, N=4096, 4C=1024, c8=32, r=16.

typedef float f32x4 __attribute__((ext_vector_type(4)));
typedef short s16x8 __attribute__((ext_vector_type(8)));
union FRAG { uint4 u; s16x8 s; };

__device__ __forceinline__ unsigned short f2bf(float f) {
    union { float f; unsigned int u; } v; v.f = f;
    unsigned int r = v.u + 0x7FFFu + ((v.u >> 16) & 1u);
    return (unsigned short)(r >> 16);
}

// ---------------------------------------------------------------------------
// K1: per-(b,c) plane -> block-mean pyramid + feats (mode 0 only now).
// Carries 80 extra blocks (bc >= 1024) doing the WB bf16 weight-cast.
// ---------------------------------------------------------------------------
__global__ __launch_bounds__(256) void k_pyramid(
    const float* __restrict__ xin,
    float* __restrict__ bm2, float* __restrict__ bm4, float* __restrict__ bm8,
    float* __restrict__ featA, float* __restrict__ fm1, float* __restrict__ fm2,
    float* __restrict__ fm4, float* __restrict__ fm8,
    const float* __restrict__ Wq, const float* __restrict__ Wk,
    const float* __restrict__ Wv, unsigned short* __restrict__ WB)
{
    __shared__ float sx[4096];
    __shared__ float s2[1024];
    __shared__ float s4[256];
    __shared__ float wred[4][8];
    const int bc = blockIdx.x;
    const int t = threadIdx.x;
    if (bc >= 1024) {
        // fused weight cast: WB[320][256], 80 blocks x 1024 entries
        const int e0 = (bc - 1024) * 1024 + t * 4;
        const int o = e0 >> 8, col = e0 & 255;
        const float* row = (o < 32) ? (Wq + (size_t)o * 1024)
                          : (o < 64) ? (Wk + (size_t)(o - 32) * 1024)
                                     : (Wv + (size_t)(o - 64) * 1024);
        float4 v = *(const float4*)(row + 768 + col);
        uint2 pk;
        pk.x = (unsigned)f2bf(v.x) | ((unsigned)f2bf(v.y) << 16);
        pk.y = (unsigned)f2bf(v.z) | ((unsigned)f2bf(v.w) << 16);
        *(uint2*)(WB + e0) = pk;
        return;
    }
    const float* xp = xin + (size_t)bc * 4096;
    float sum = 0.f, mx = -1e30f;
    for (int r = 0; r < 4; r++) {
        int i4 = t + 256 * r;
        float4 v = ((const float4*)xp)[i4];
        sum += v.x + v.y + v.z + v.w;
        mx = fmaxf(mx, fmaxf(fmaxf(v.x, v.y), fmaxf(v.z, v.w)));
        ((float4*)sx)[i4] = v;
    }
    __syncthreads();
    float mx2 = -1e30f;
    for (int r = 0; r < 4; r++) {
        int i = t + 256 * r;
        int r2 = i >> 5, c2 = i & 31;
        int p0 = 128 * r2 + 2 * c2;
        float v = 0.25f * (sx[p0] + sx[p0 + 1] + sx[p0 + 64] + sx[p0 + 65]);
        s2[i] = v;
        bm2[(size_t)bc * 1024 + i] = v;
        mx2 = fmaxf(mx2, v);
    }
    __syncthreads();
    float mx4;
    {
        int r4 = t >> 4, c4 = t & 15;
        int p0 = 64 * r4 + 2 * c4;
        float v = 0.25f * (s2[p0] + s2[p0 + 1] + s2[p0 + 32] + s2[p0 + 33]);
        s4[t] = v;
        bm4[(size_t)bc * 256 + t] = v;
        mx4 = v;
    }
    __syncthreads();
    float mx8 = -1e30f;
    if (t < 64) {
        int r8 = t >> 3, c8 = t & 7;
        int p0 = 32 * r8 + 2 * c8;
        float v = 0.25f * (s4[p0] + s4[p0 + 1] + s4[p0 + 16] + s4[p0 + 17]);
        bm8[(size_t)bc * 64 + t] = v;
        mx8 = v;
    }
    {
        float vs = sum, v1 = mx, v2 = mx2, v4 = mx4, v8 = mx8;
        #pragma unroll
        for (int o = 1; o < 64; o <<= 1) {
            vs += __shfl_xor(vs, o);
            v1 = fmaxf(v1, __shfl_xor(v1, o));
            v2 = fmaxf(v2, __shfl_xor(v2, o));
            v4 = fmaxf(v4, __shfl_xor(v4, o));
            v8 = fmaxf(v8, __shfl_xor(v8, o));
        }
        if ((t & 63) == 0) {
            int wd = t >> 6;
            wred[wd][0] = vs; wred[wd][1] = v1; wred[wd][2] = v2;
            wred[wd][3] = v4; wred[wd][4] = v8;
        }
        __syncthreads();
        if (t == 0) featA[bc] = (wred[0][0] + wred[1][0] + wred[2][0] + wred[3][0]) * (1.f / 4096.f);
        else if (t == 1) fm1[bc] = fmaxf(fmaxf(wred[0][1], wred[1][1]), fmaxf(wred[2][1], wred[3][1]));
        else if (t == 2) fm2[bc] = fmaxf(fmaxf(wred[0][2], wred[1][2]), fmaxf(wred[2][2], wred[3][2]));
        else if (t == 3) fm4[bc] = fmaxf(fmaxf(wred[0][3], wred[1][3]), fmaxf(wred[2][3], wred[3][3]));
        else if (t == 4) fm8[bc] = fmaxf(fmaxf(wred[0][4], wred[1][4]), fmaxf(wred[2][4], wred[3][4]));
    }
}

// ---------------------------------------------------------------------------
// K3: spatial-gate input, with the channel-gate MLP FUSED (former k2).
// ---------------------------------------------------------------------------
__global__ __launch_bounds__(256) void k3_comp(
    const float* __restrict__ x, const float* __restrict__ bm2,
    const float* __restrict__ bm4, const float* __restrict__ bm8,
    const float* __restrict__ featA, const float* __restrict__ fm1,
    const float* __restrict__ fm2, const float* __restrict__ fm4,
    const float* __restrict__ fm8,
    const float* __restrict__ W1, const float* __restrict__ b1,
    const float* __restrict__ W2, const float* __restrict__ b2,
    float* __restrict__ g, float* __restrict__ comp)
{
    __shared__ float sf[5][256];
    __shared__ float sh[5][16];
    __shared__ float hs[16];
    __shared__ float sg[256];
    __shared__ float rmx[4][64];
    __shared__ float rsm[4][64];
    const int b = blockIdx.x >> 6;
    const int t = threadIdx.x;
    // --- inline channel-gate MLP (identical math to former k2_gate) ---
    sf[0][t] = featA[(b << 8) + t];
    sf[1][t] = fm1[(b << 8) + t];
    sf[2][t] = fm2[(b << 8) + t];
    sf[3][t] = fm4[(b << 8) + t];
    sf[4][t] = fm8[(b << 8) + t];
    __syncthreads();
    if (t < 80) {
        int f = t / 16, j = t % 16;
        float a = b1[j];
        for (int c = 0; c < 256; c++) a += sf[f][c] * W1[c * 16 + j];
        sh[f][j] = fmaxf(a, 0.f);
    }
    __syncthreads();
    if (t < 16) hs[t] = 4.f * sh[0][t] + sh[1][t] + sh[2][t] + sh[3][t] + sh[4][t];
    __syncthreads();
    {
        float a = 8.f * b2[t];
        for (int j = 0; j < 16; j++) a += hs[j] * W2[j * 256 + t];
        sg[t] = 1.f / (1.f + __expf(-a));
    }
    __syncthreads();
    if ((blockIdx.x & 63) == 0) g[(b << 8) + t] = sg[t];
    // --- original k3 body ---
    const int pix = ((blockIdx.x & 63) << 6) + (t & 63);
    const int wid = t >> 6;
    const int c0 = wid << 6;
    const int h = pix >> 6, w = pix & 63;
    const int i2 = ((h >> 1) << 5) + (w >> 1);
    const int i4 = ((h >> 2) << 4) + (w >> 2);
    const int i8 = ((h >> 3) << 3) + (w >> 3);
    const float* xb = x + ((size_t)b << 8) * 4096;
    const float* p2 = bm2 + ((size_t)b << 8) * 1024;
    const float* p4 = bm4 + ((size_t)b << 8) * 256;
    const float* p8 = bm8 + ((size_t)b << 8) * 64;
    float mx = -1e30f, sm = 0.f;
    for (int c = c0; c < c0 + 64; c++) {
        float gc = sg[c];
        float xv = xb[(size_t)c * 4096 + pix] * gc;
        float v2 = p2[c * 1024 + i2] * gc;
        float v4 = p4[c * 256 + i4] * gc;
        float v8 = p8[c * 64 + i8] * gc;
        mx = fmaxf(fmaxf(mx, xv), fmaxf(fmaxf(v2, v4), v8));
        sm += xv + v2 + v4 + v8;
    }
    rmx[wid][t & 63] = mx;
    rsm[wid][t & 63] = sm;
    __syncthreads();
    if (wid == 0) {
        int l = t;
        float m = fmaxf(fmaxf(rmx[0][l], rmx[1][l]), fmaxf(rmx[2][l], rmx[3][l]));
        float s = rsm[0][l] + rsm[1][l] + rsm[2][l] + rsm[3][l];
        comp[((size_t)b * 2) * 4096 + pix] = m;
        comp[((size_t)b * 2 + 1) * 4096 + pix] = s * (1.f / 1024.f);
    }
}

// ---------------------------------------------------------------------------
// K4: 7x7 conv (2->1, pad 3, no bias) + BN(eval) + sigmoid. Grid 64 x 256thr.
// ---------------------------------------------------------------------------
__global__ __launch_bounds__(256) void k4_spgate(
    const float* __restrict__ comp, const float* __restrict__ Wsp,
    const float* __restrict__ bn_g, const float* __restrict__ bn_b,
    const float* __restrict__ bn_m, const float* __restrict__ bn_v,
    float* __restrict__ spg)
{
    __shared__ float w[98];
    const int t = threadIdx.x;
    for (int i = t; i < 98; i += 256) w[i] = Wsp[i];
    __syncthreads();
    const int pixg = blockIdx.x * 256 + t;
    const int b = pixg >> 12;
    const int pix = pixg & 4095;
    const int h = pix >> 6, wx = pix & 63;
    const float* c0 = comp + (size_t)b * 2 * 4096;
    float acc = 0.f;
    for (int ci = 0; ci < 2; ci++)
        for (int kh = 0; kh < 7; kh++) {
            int hh = h + kh - 3;
            if (hh < 0 || hh >= 64) continue;
            for (int kw = 0; kw < 7; kw++) {
                int wwp = wx + kw - 3;
                if (wwp < 0 || wwp >= 64) continue;
                acc += c0[ci * 4096 + hh * 64 + wwp] * w[ci * 49 + kh * 7 + kw];
            }
        }
    float sc = rsqrtf(bn_v[0] + 1e-5f) * bn_g[0];
    float sp = (acc - bn_m[0]) * sc + bn_b[0];
    spg[pixg] = 1.f / (1.f + __expf(-sp));
}

// ---------------------------------------------------------------------------
// K_X2TP: fused gate+transpose+pool2 — replaces pyramid-mode-1 AND k_x2t.
// Block (b, 64c, 128n = rows h0,h0+1): reads x, gates by g[c]*spg[n]
// (same order as old pyramid mode-1), writes x2T bf16 [n][c] and bm2b
// (2x2 means, same fp32 addition order as old s2 -> bit-identical).
// The fp32 x2 buffer is GONE: k7b recomputes the residual from x,g,spg.
// ---------------------------------------------------------------------------
__global__ __launch_bounds__(256) void k_x2tp(
    const float* __restrict__ x, const float* __restrict__ g,
    const float* __restrict__ spg,
    unsigned short* __restrict__ x2T, float* __restrict__ bm2b)
{
    __shared__ float sx[128][68];
    __shared__ float gsh[64];
    __shared__ float ssh[128];
    const int b  = blockIdx.z;
    const int cb = blockIdx.y * 64;
    const int nb = blockIdx.x * 128;
    const int t  = threadIdx.x;
    if (t < 64) gsh[t] = g[(b << 8) + cb + t];
    else if (t < 192) ssh[t - 64] = spg[(size_t)b * 4096 + nb + (t - 64)];
    __syncthreads();
    const int nl = t & 127;
    const int ch = t >> 7;             // 0 or 1
    const float sp = ssh[nl];
    #pragma unroll
    for (int r = 0; r < 32; r++) {
        int cl = ch + 2 * r;
        float v = x[((size_t)(b * 256 + cb + cl)) * 4096 + nb + nl];
        sx[nl][cl] = v * (gsh[cl] * sp);
    }
    __syncthreads();
    // transpose write x2T (bf16 [n][c])
    #pragma unroll
    for (int pass = 0; pass < 8; pass++) {
        int nl2 = (t >> 4) + 16 * pass;
        int c4 = (t & 15) * 4;
        uint2 pk;
        pk.x = (unsigned)f2bf(sx[nl2][c4])     | ((unsigned)f2bf(sx[nl2][c4 + 1]) << 16);
        pk.y = (unsigned)f2bf(sx[nl2][c4 + 2]) | ((unsigned)f2bf(sx[nl2][c4 + 3]) << 16);
        *(uint2*)(x2T + ((size_t)(b * 4096 + nb + nl2)) * 256 + cb + c4) = pk;
    }
    // bm2b: 2x2 pool (rows h0,h0+1), 64c x 32w2 outputs
    #pragma unroll
    for (int i = 0; i < 8; i++) {
        int o = t + 256 * i;          // 0..2047
        int c = o >> 5, w2 = o & 31;
        float v = 0.25f * (sx[2 * w2][c] + sx[2 * w2 + 1][c]
                         + sx[64 + 2 * w2][c] + sx[64 + 2 * w2 + 1][c]);
        bm2b[((size_t)(b * 256 + cb + c)) * 1024 + (nb >> 7) * 32 + w2] = v;
    }
}

// ---------------------------------------------------------------------------
// K_POOL48: bm2b -> bm4b, bm8b (same formulas/order as the old s2->s4->s8
// chain -> bit-identical). Grid 1024 = (b,c) planes.
// ---------------------------------------------------------------------------
__global__ __launch_bounds__(256) void k_pool48(
    const float* __restrict__ bm2b, float* __restrict__ bm4b, float* __restrict__ bm8b)
{
    __shared__ float s2[1024];
    __shared__ float s4[256];
    const int bc = blockIdx.x;
    const int t = threadIdx.x;
    ((float4*)s2)[t] = ((const float4*)(bm2b + (size_t)bc * 1024))[t];
    __syncthreads();
    {
        int r4 = t >> 4, c4 = t & 15;
        int p0 = 64 * r4 + 2 * c4;
        float v = 0.25f * (s2[p0] + s2[p0 + 1] + s2[p0 + 32] + s2[p0 + 33]);
        s4[t] = v;
        bm4b[(size_t)bc * 256 + t] = v;
    }
    __syncthreads();
    if (t < 64) {
        int r8 = t >> 3, c8 = t & 7;
        int p0 = 32 * r8 + 2 * c8;
        bm8b[(size_t)bc * 64 + t] = 0.25f * (s4[p0] + s4[p0 + 1] + s4[p0 + 16] + s4[p0 + 17]);
    }
}

// ---------------------------------------------------------------------------
// K6: fp32 projection GEMM for low-res P2/P4/P8, all three scales in ONE
// launch: blockIdx.x 0..15 -> P2, 16..19 -> P4, 20 -> P8.
// ---------------------------------------------------------------------------
__global__ __launch_bounds__(256) void k6_gemm(
    const float* __restrict__ Wq, const float* __restrict__ Wk, const float* __restrict__ Wv,
    const float* __restrict__ bm2b, const float* __restrict__ bm4b, const float* __restrict__ bm8b,
    float* __restrict__ P2, float* __restrict__ P4, float* __restrict__ P8)
{
    __shared__ float At[32][68];
    __shared__ float Bt[32][64];
    const int bx = blockIdx.x;
    int col_off, ns, nb;
    const float* src;
    float* outp;
    if (bx < 16)      { col_off = 0;   src = bm2b; ns = 1024; outp = P2; nb = bx; }
    else if (bx < 20) { col_off = 256; src = bm4b; ns = 256;  outp = P4; nb = bx - 16; }
    else              { col_off = 512; src = bm8b; ns = 64;   outp = P8; nb = 0; }
    const int b = blockIdx.z;
    const int o_base = blockIdx.y * 64;
    const int n_base = nb * 64;
    const int t = threadIdx.x;
    const int tn = t >> 4, tm = t & 15;
    const int lk = t & 31, lo8 = t >> 5;
    const int ln = t & 63, lk4 = t >> 6;
    float acc[4][4];
    #pragma unroll
    for (int i = 0; i < 4; i++)
        #pragma unroll
        for (int j = 0; j < 4; j++) acc[i][j] = 0.f;
    for (int k0 = 0; k0 < 256; k0 += 32) {
        __syncthreads();
        #pragma unroll
        for (int r = 0; r < 8; r++) {
            int o = o_base + lo8 + 8 * r;
            const float* wrow = (o < 32) ? (Wq + (size_t)o * 1024)
                              : (o < 64) ? (Wk + (size_t)(o - 32) * 1024)
                                         : (Wv + (size_t)(o - 64) * 1024);
            At[lk][lo8 + 8 * r] = wrow[col_off + k0 + lk];
        }
        #pragma unroll
        for (int r = 0; r < 8; r++)
            Bt[lk4 + 4 * r][ln] = src[((size_t)b * 256 + k0 + lk4 + 4 * r) * ns + n_base + ln];
        __syncthreads();
        #pragma unroll
        for (int kk = 0; kk < 32; kk++) {
            float4 a = *(const float4*)&At[kk][4 * tn];
            float4 bb = *(const float4*)&Bt[kk][4 * tm];
            acc[0][0] += a.x * bb.x; acc[0][1] += a.x * bb.y; acc[0][2] += a.x * bb.z; acc[0][3] += a.x * bb.w;
            acc[1][0] += a.y * bb.x; acc[1][1] += a.y * bb.y; acc[1][2] += a.y * bb.z; acc[1][3] += a.y * bb.w;
            acc[2][0] += a.z * bb.x; acc[2][1] += a.z * bb.y; acc[2][2] += a.z * bb.z; acc[2][3] += a.z * bb.w;
            acc[3][0] += a.w * bb.x; acc[3][1] += a.w * bb.y; acc[3][2] += a.w * bb.z; acc[3][3] += a.w * bb.w;
        }
    }
    #pragma unroll
    for (int i = 0; i < 4; i++)
        #pragma unroll
        for (int j = 0; j < 4; j++)
            outp[((size_t)b * 320 + o_base + 4 * tn + i) * ns + n_base + 4 * tm + j] = acc[i][j];
}

// ---------------------------------------------------------------------------
// K6M: full-res projection via bf16 MFMA, XCD-PINNED 1-D grid 640.
// v writes go to FRAG-CONTIGUOUS layout (see k7b AV_LOAD).
// ---------------------------------------------------------------------------
__global__ __launch_bounds__(256) void k6m(
    const unsigned short* __restrict__ WB, const unsigned short* __restrict__ x2T,
    const float* __restrict__ bq, const float* __restrict__ bk, const float* __restrict__ bv,
    const float* __restrict__ P2, const float* __restrict__ P4, const float* __restrict__ P8,
    unsigned short* __restrict__ qT, unsigned short* __restrict__ kT,
    unsigned short* __restrict__ vC)
{
    const int bid = blockIdx.x;
    const int b = (bid >> 1) & 3;
    const int rest = ((bid >> 3) << 1) | (bid & 1);   // 0..159
    const int nb = (rest & 31) * 128;
    const int obase = (rest >> 5) * 64;
    const int t = threadIdx.x;
    const int w_ = t >> 6, lane = t & 63;
    const int quad = lane >> 4, l16 = lane & 15;
    const int nbase = nb + 32 * w_;
    f32x4 acc[4][2];
    #pragma unroll
    for (int ot = 0; ot < 4; ot++)
        #pragma unroll
        for (int nt = 0; nt < 2; nt++) { acc[ot][nt][0] = 0.f; acc[ot][nt][1] = 0.f; acc[ot][nt][2] = 0.f; acc[ot][nt][3] = 0.f; }
    const unsigned short* xb = x2T + ((size_t)b * 4096 + nbase) * 256;
    for (int k0 = 0; k0 < 256; k0 += 32) {
        FRAG af[4], bf[2];
        #pragma unroll
        for (int ot = 0; ot < 4; ot++)
            af[ot].u = *(const uint4*)(WB + (size_t)(obase + 16 * ot + l16) * 256 + k0 + quad * 8);
        #pragma unroll
        for (int nt = 0; nt < 2; nt++)
            bf[nt].u = *(const uint4*)(xb + (size_t)(16 * nt + l16) * 256 + k0 + quad * 8);
        #pragma unroll
        for (int ot = 0; ot < 4; ot++)
            #pragma unroll
            for (int nt = 0; nt < 2; nt++)
                acc[ot][nt] = __builtin_amdgcn_mfma_f32_16x16x32_bf16(af[ot].s, bf[nt].s, acc[ot][nt], 0, 0, 0);
    }
    #pragma unroll
    for (int ot = 0; ot < 4; ot++) {
        #pragma unroll
        for (int nt = 0; nt < 2; nt++) {
            int n = nbase + 16 * nt + l16;
            int h = n >> 6, wx = n & 63;
            int i2 = ((h >> 1) << 5) + (wx >> 1);
            int i4 = ((h >> 2) << 4) + (wx >> 2);
            int i8 = ((h >> 3) << 3) + (wx >> 3);
            float vals[4];
            #pragma unroll
            for (int r = 0; r < 4; r++) {
                int o = obase + 16 * ot + 4 * quad + r;
                float bias = (o < 32) ? bq[o] : (o < 64) ? bk[o - 32] : bv[o - 64];
                size_t ro = (size_t)b * 320 + o;
                vals[r] = acc[ot][nt][r] + bias
                        + P2[ro * 1024 + i2] + P4[ro * 256 + i4] + P8[ro * 64 + i8];
            }
            int o0 = obase + 16 * ot + 4 * quad;
            if (o0 < 64) {
                uint2 pk;
                pk.x = (unsigned)f2bf(vals[0]) | ((unsigned)f2bf(vals[1]) << 16);
                pk.y = (unsigned)f2bf(vals[2]) | ((unsigned)f2bf(vals[3]) << 16);
                if (o0 < 32)
                    *(uint2*)(qT + ((size_t)(b * 4096 + n)) * 32 + o0) = pk;
                else
                    *(uint2*)(kT + ((size_t)(b * 4096 + n)) * 32 + (o0 - 32)) = pk;
            } else {
                int chunk = n >> 6;
                int kk = n & 63;
                int khw_ = (kk >> 5) & 1, qd = (kk >> 3) & 3, ko = kk & 7;
                unsigned short* dst = vC + (((size_t)b * 64 + chunk) << 14);
                #pragma unroll
                for (int r = 0; r < 4; r++) {
                    int c = o0 - 64 + r;
                    dst[((((c >> 4) << 1) + khw_) << 9) + ((qd * 16 + (c & 15)) << 3) + ko] = f2bf(vals[r]);
                }
            }
        }
    }
}

// ---------------------------------------------------------------------------
// K7A: softmax stats pass (dense kT reads), XCD-pinned bid decode.
// ---------------------------------------------------------------------------
__global__ __launch_bounds__(1024, 4) void k7a_stats(
    const unsigned short* __restrict__ qT, const unsigned short* __restrict__ kT,
    float* __restrict__ mout, float* __restrict__ ilout)
{
    __shared__ float sm[4][4][16], sl[4][4][16];   // [g][s][l16]
    const int bid = blockIdx.x;
    const int b = (bid >> 1) & 3;
    const int qbase = (((bid >> 3) << 1) | (bid & 1)) << 6;
    const int t = threadIdx.x;
    const int wid = t >> 6, lane = t & 63;
    const int g_ = wid >> 2, s_ = wid & 3;
    const int quad = lane >> 4, l16 = lane & 15;

    FRAG qf;
    qf.u = *(const uint4*)(qT + ((size_t)(b * 4096 + qbase + 16 * g_ + l16)) * 32 + quad * 8);
    const unsigned short* kTb = kT + (size_t)b * 4096 * 32;

    float m_run = -1e30f, l_run = 0.f;
    for (int j = 0; j < 16; j++) {
        const int mo = (s_ << 10) + (j << 6);
        f32x4 e[4];
        #pragma unroll
        for (int mt = 0; mt < 4; mt++) {
            FRAG kf;
            kf.u = *(const uint4*)(kTb + (size_t)(mo + 16 * mt + l16) * 32 + quad * 8);
            f32x4 z; z[0] = 0.f; z[1] = 0.f; z[2] = 0.f; z[3] = 0.f;
            e[mt] = __builtin_amdgcn_mfma_f32_16x16x32_bf16(kf.s, qf.s, z, 0, 0, 0);
        }
        float pm = e[0][0];
        #pragma unroll
        for (int mt = 0; mt < 4; mt++)
            #pragma unroll
            for (int r = 0; r < 4; r++) pm = fmaxf(pm, e[mt][r]);
        float mnew = fmaxf(m_run, pm);
        float al = __expf(m_run - mnew);
        float ps = 0.f;
        #pragma unroll
        for (int mt = 0; mt < 4; mt++)
            #pragma unroll
            for (int r = 0; r < 4; r++) ps += __expf(e[mt][r] - mnew);
        l_run = l_run * al + ps;
        m_run = mnew;
    }
    #pragma unroll
    for (int o = 16; o < 64; o <<= 1) {
        float mo_ = __shfl_xor(m_run, o);
        float lo_ = __shfl_xor(l_run, o);
        float m2 = fmaxf(m_run, mo_);
        l_run = l_run * __expf(m_run - m2) + lo_ * __expf(mo_ - m2);
        m_run = m2;
    }
    if (quad == 0) { sm[g_][s_][l16] = m_run; sl[g_][s_][l16] = l_run; }
    __syncthreads();
    if (t < 64) {
        int g = t >> 4, l = t & 15;
        float m0 = sm[g][0][l], m1 = sm[g][1][l], m2 = sm[g][2][l], m3 = sm[g][3][l];
        float mx = fmaxf(fmaxf(m0, m1), fmaxf(m2, m3));
        float l_ = sl[g][0][l] * __expf(m0 - mx) + sl[g][1][l] * __expf(m1 - mx)
                 + sl[g][2][l] * __expf(m2 - mx) + sl[g][3][l] * __expf(m3 - mx);
        int n = qbase + 16 * g + l;
        mout[b * 4096 + n] = mx;
        ilout[b * 4096 + n] = 1.f / l_;
    }
}

// ---------------------------------------------------------------------------
// K7B v17 = v16 (proven 55.4 µs) with the residual RECOMPUTED from x,g,spg
// (x2 buffer eliminated): res = x * (g[c] * spg[n]), identical fp32 expr
// to what pyramid-mode-1 stored. Same bytes read (x instead of x2).
// ---------------------------------------------------------------------------
__global__ __launch_bounds__(512) void k7b_attn(
    const unsigned short* __restrict__ qT, const unsigned short* __restrict__ kT,
    const unsigned short* __restrict__ vC, const float* __restrict__ mstat,
    const float* __restrict__ ilstat, const float* __restrict__ x,
    const float* __restrict__ g, const float* __restrict__ spg,
    const float* __restrict__ gamma, float* __restrict__ outp)
{
    __shared__ __align__(16) unsigned short PL[2][64][64];  // 16 KB swizzled P
    __shared__ float SB[128][68];                           // 34.8 KB combine buffer
    __shared__ float gsh[256];
    __shared__ float ssh[64];
    const int bid = blockIdx.x;
    const int b = (bid >> 1) & 3;
    const int qbase = (((bid >> 3) << 1) | (bid & 1)) << 6;
    const int t = threadIdx.x;
    const int wid = t >> 6, lane = t & 63;
    const int cw = wid & 3, khw = wid >> 2;
    const int quad = lane >> 4, l16 = lane & 15;
    const int ntq = wid & 3;                // QK n-tile of this wave
    const int mt0 = 2 * khw, mt1 = 2 * khw + 1;
    const int nq = qbase + 16 * ntq + l16;  // column of this wave's P rows

    FRAG qf;
    qf.u = *(const uint4*)(qT + ((size_t)(b * 4096 + nq)) * 32 + quad * 8);
    const float mN = mstat[b * 4096 + nq];

    f32x4 acc[4][4];
    #pragma unroll
    for (int ct = 0; ct < 4; ct++)
        #pragma unroll
        for (int nt = 0; nt < 4; nt++) { acc[ct][nt][0] = 0.f; acc[ct][nt][1] = 0.f; acc[ct][nt][2] = 0.f; acc[ct][nt][3] = 0.f; }
    const unsigned short* kTb = kT + (size_t)b * 4096 * 32;
    // per-wave V-frag base: frag (c16 = 4*cw + ct, khw), lane-contiguous.
    const unsigned short* vfb = vC + ((size_t)b * 64 << 14)
                              + (((8 * cw) + khw) << 9) + lane * 8;

    // PL swizzle constants (granule = 8 shorts = 16 B)
    const int po  = 4 * (quad & 1);
    const int pg0 = ((4 * khw + (quad >> 1)) ^ (l16 & 7));        // pkA granule
    const int pg1 = ((4 * khw + 2 + (quad >> 1)) ^ (l16 & 7));    // pkB granule
    const int pgr = ((4 * khw + quad) ^ (l16 & 7)) << 3;          // bp read offset

    FRAG avA[4], avB[4], kc0, kc1;

#define AV_LOAD(AV, CH) do { \
    const unsigned short* vfj = vfb + ((size_t)(CH) << 14); \
    AV[0].u = *(const uint4*)(vfj); \
    AV[1].u = *(const uint4*)(vfj + 1024); \
    AV[2].u = *(const uint4*)(vfj + 2048); \
    AV[3].u = *(const uint4*)(vfj + 3072); \
} while (0)

#define KC_LOAD(CH) do { \
    const int mo_ = (CH) << 6; \
    kc0.u = *(const uint4*)(kTb + (size_t)(mo_ + 16 * mt0 + l16) * 32 + quad * 8); \
    kc1.u = *(const uint4*)(kTb + (size_t)(mo_ + 16 * mt1 + l16) * 32 + quad * 8); \
} while (0)

#define QK_EXP_STORE(DST) do { \
    f32x4 z; z[0] = 0.f; z[1] = 0.f; z[2] = 0.f; z[3] = 0.f; \
    f32x4 e0 = __builtin_amdgcn_mfma_f32_16x16x32_bf16(kc0.s, qf.s, z, 0, 0, 0); \
    f32x4 e1 = __builtin_amdgcn_mfma_f32_16x16x32_bf16(kc1.s, qf.s, z, 0, 0, 0); \
    union { float f; unsigned int u; } p0, p1, p2, p3; \
    uint2 pkA, pkB; \
    p0.f = __expf(e0[0] - mN); p1.f = __expf(e0[1] - mN); \
    p2.f = __expf(e0[2] - mN); p3.f = __expf(e0[3] - mN); \
    pkA.x = __builtin_amdgcn_perm(p1.u, p0.u, 0x07060302u); \
    pkA.y = __builtin_amdgcn_perm(p3.u, p2.u, 0x07060302u); \
    p0.f = __expf(e1[0] - mN); p1.f = __expf(e1[1] - mN); \
    p2.f = __expf(e1[2] - mN); p3.f = __expf(e1[3] - mN); \
    pkB.x = __builtin_amdgcn_perm(p1.u, p0.u, 0x07060302u); \
    pkB.y = __builtin_amdgcn_perm(p3.u, p2.u, 0x07060302u); \
    *(uint2*)&PL[DST][16 * ntq + l16][(pg0 << 3) + po] = pkA; \
    *(uint2*)&PL[DST][16 * ntq + l16][(pg1 << 3) + po] = pkB; \
} while (0)

#define PV_STEP(AV, CUR) do { \
    FRAG bp[4]; \
    _Pragma("unroll") \
    for (int nt = 0; nt < 4; nt++) \
        bp[nt].u = *(const uint4*)&PL[CUR][16 * nt + l16][pgr]; \
    __builtin_amdgcn_s_setprio(1); \
    _Pragma("unroll") \
    for (int ct = 0; ct < 4; ct++) { \
        _Pragma("unroll") \
        for (int nt = 0; nt < 4; nt++) \
            acc[ct][nt] = __builtin_amdgcn_mfma_f32_16x16x32_bf16(AV[ct].s, bp[nt].s, acc[ct][nt], 0, 0, 0); \
    } \
    __builtin_amdgcn_s_setprio(0); \
} while (0)

    // --- prologue: av(0); QK(0)->PL[0]; kc for chunk 1 ---
    AV_LOAD(avA, 0);
    KC_LOAD(0);
    QK_EXP_STORE(0);
    KC_LOAD(1);

    for (int jj = 0; jj < 32; jj++) {
        const int j = 2 * jj;
        // ---- phase A: compute PV(j) [even chunk], prefetch j+1 ----
        __syncthreads();
        {
            AV_LOAD(avB, j + 1);
            QK_EXP_STORE(1);
            if (j < 62) KC_LOAD(j + 2);
        }
        PV_STEP(avA, 0);
        // ---- phase B: compute PV(j+1) [odd chunk], prefetch j+2 ----
        __syncthreads();
        if (j < 62) {
            AV_LOAD(avA, j + 2);
            QK_EXP_STORE(0);
            if (j < 61) KC_LOAD(j + 3);
        }
        PV_STEP(avB, 1);
    }
#undef AV_LOAD
#undef KC_LOAD
#undef QK_EXP_STORE
#undef PV_STEP

    // residual gate factors for the epilogue
    if (t < 256) gsh[t] = g[(b << 8) + t];
    else if (t < 320) ssh[t - 256] = spg[(size_t)b * 4096 + qbase + (t - 256)];

    // --- epilogue: combine khw halves via SB, 2 c-stripe rounds ---
    const float gm = gamma[0];
    for (int s = 0; s < 2; s++) {
        __syncthreads();
        if (khw == 0 && (cw >> 1) == s) {
            #pragma unroll
            for (int ct = 0; ct < 4; ct++)
                #pragma unroll
                for (int nt = 0; nt < 4; nt++)
                    #pragma unroll
                    for (int r = 0; r < 4; r++)
                        SB[64 * (cw & 1) + 16 * ct + 4 * quad + r][16 * nt + l16] = acc[ct][nt][r];
        }
        __syncthreads();
        if (khw == 1 && (cw >> 1) == s) {
            #pragma unroll
            for (int ct = 0; ct < 4; ct++)
                #pragma unroll
                for (int nt = 0; nt < 4; nt++)
                    #pragma unroll
                    for (int r = 0; r < 4; r++)
                        SB[64 * (cw & 1) + 16 * ct + 4 * quad + r][16 * nt + l16] += acc[ct][nt][r];
        }
        __syncthreads();
        // cooperative store: 128c x 64n
        #pragma unroll
        for (int pass = 0; pass < 4; pass++) {
            int cl = (t >> 4) + 32 * pass;
            int n4 = (t & 15) * 4;
            float4 vv = *(float4*)&SB[cl][n4];
            float4 il4 = *(const float4*)(ilstat + (size_t)b * 4096 + qbase + n4);
            size_t idx = ((size_t)(b * 256 + 128 * s + cl)) * 4096 + qbase + n4;
            float4 xv = *(const float4*)(x + idx);
            float gc = gsh[128 * s + cl];
            float4 ss4 = *(float4*)&ssh[n4];
            float4 ov;
            ov.x = gm * vv.x * il4.x + xv.x * (gc * ss4.x);
            ov.y = gm * vv.y * il4.y + xv.y * (gc * ss4.y);
            ov.z = gm * vv.z * il4.z + xv.z * (gc * ss4.z);
            ov.w = gm * vv.w * il4.w + xv.w * (gc * ss4.w);
            *(float4*)(outp + idx) = ov;
        }
    }
}

// ---------------------------------------------------------------------------
extern "C" void kernel_launch(void* const* d_in, const int* in_sizes, int n_in,
                              void* d_out, int out_size, void* d_ws, size_t ws_size,
                              hipStream_t stream) {
    (void)in_sizes; (void)n_in; (void)out_size; (void)ws_size;
    const float* x    = (const float*)d_in[0];
    const float* W1   = (const float*)d_in[1];
    const float* b1   = (const float*)d_in[2];
    const float* W2   = (const float*)d_in[3];
    const float* b2   = (const float*)d_in[4];
    const float* Wq   = (const float*)d_in[5];
    const float* bq   = (const float*)d_in[6];
    const float* Wk   = (const float*)d_in[7];
    const float* bk   = (const float*)d_in[8];
    const float* Wv   = (const float*)d_in[9];
    const float* bv   = (const float*)d_in[10];
    const float* gam  = (const float*)d_in[11];
    const float* Wsp  = (const float*)d_in[12];
    const float* bn_g = (const float*)d_in[13];
    const float* bn_b = (const float*)d_in[14];
    const float* bn_m = (const float*)d_in[15];
    const float* bn_v = (const float*)d_in[16];

    float* ws = (float*)d_ws;
    float* bm2   = ws; ws += (size_t)4 * 256 * 1024;
    float* bm4   = ws; ws += (size_t)4 * 256 * 256;
    float* bm8   = ws; ws += (size_t)4 * 256 * 64;
    float* featA = ws; ws += 1024;
    float* fm1   = ws; ws += 1024;
    float* fm2   = ws; ws += 1024;
    float* fm4   = ws; ws += 1024;
    float* fm8   = ws; ws += 1024;
    float* g     = ws; ws += 1024;
    float* comp  = ws; ws += (size_t)4 * 2 * 4096;
    float* spg   = ws; ws += (size_t)4 * 4096;
    float* bm2b  = ws; ws += (size_t)4 * 256 * 1024;
    float* bm4b  = ws; ws += (size_t)4 * 256 * 256;
    float* bm8b  = ws; ws += (size_t)4 * 256 * 64;
    float* P2    = ws; ws += (size_t)4 * 320 * 1024;
    float* P4    = ws; ws += (size_t)4 * 320 * 256;
    float* P8    = ws; ws += (size_t)4 * 320 * 64;
    float* mstat = ws; ws += (size_t)4 * 4096;
    float* ilstat= ws; ws += (size_t)4 * 4096;
    unsigned short* qT  = (unsigned short*)ws; ws += (size_t)4 * 4096 * 32 / 2;
    unsigned short* kT  = (unsigned short*)ws; ws += (size_t)4 * 4096 * 32 / 2;
    unsigned short* vCp = (unsigned short*)ws; ws += (size_t)4 * 64 * 16384 / 2;
    unsigned short* x2T = (unsigned short*)ws; ws += (size_t)4 * 4096 * 256 / 2;
    unsigned short* WB  = (unsigned short*)ws; ws += (size_t)320 * 256 / 2;

    // Stage 1: channel gate (pyramid + fused weight-cast in the extra 80 blocks)
    k_pyramid<<<1104, 256, 0, stream>>>(x, bm2, bm4, bm8,
                                        featA, fm1, fm2, fm4, fm8,
                                        Wq, Wk, Wv, WB);
    // Stage 2: spatial gate (k3 with fused channel-gate MLP; writes g too)
    k3_comp<<<256, 256, 0, stream>>>(x, bm2, bm4, bm8,
                                     featA, fm1, fm2, fm4, fm8,
                                     W1, b1, W2, b2, g, comp);
    k4_spgate<<<64, 256, 0, stream>>>(comp, Wsp, bn_g, bn_b, bn_m, bn_v, spg);
    // Fused gate+transpose+pool2 (replaces pyramid mode-1 AND k_x2t),
    // then bm4b/bm8b from bm2b.
    k_x2tp<<<dim3(32, 4, 4), 256, 0, stream>>>(x, g, spg, x2T, bm2b);
    k_pool48<<<1024, 256, 0, stream>>>(bm2b, bm4b, bm8b);
    // Stage 3: q/k/v projections
    k6_gemm<<<dim3(21, 5, 4), 256, 0, stream>>>(Wq, Wk, Wv, bm2b, bm4b, bm8b, P2, P4, P8);
    k6m<<<640, 256, 0, stream>>>(WB, x2T, bq, bk, bv, P2, P4, P8, qT, kT, vCp);
    // Two-pass attention: stats, then the proven PV (+recomputed residual)
    k7a_stats<<<256, 1024, 0, stream>>>(qT, kT, mstat, ilstat);
    k7b_attn<<<256, 512, 0, stream>>>(qT, kT, vCp, mstat, ilstat, x, g, spg, gam, (float*)d_out);
}

// Round 11
// 237.007 us; speedup vs baseline: 1.2194x; 1.1324x over previous
//
#include <hip/hip_runtime.h>
#include <math.h>

// Shapes (fixed): B=4, C=256, H=W=64, N=4096, 4C=1024, c8=32, r=16.

typedef float f32x4 __attribute__((ext_vector_type(4)));
typedef short s16x8 __attribute__((ext_vector_type(8)));
union FRAG { uint4 u; s16x8 s; };

__device__ __forceinline__ unsigned short f2bf(float f) {
    union { float f; unsigned int u; } v; v.f = f;
    unsigned int r = v.u + 0x7FFFu + ((v.u >> 16) & 1u);
    return (unsigned short)(r >> 16);
}

// ---------------------------------------------------------------------------
// K1: per-(b,c) plane -> block-mean pyramid + feats.
// Carries 80 extra blocks (bc >= 1024) doing the WB bf16 weight-cast.
// ---------------------------------------------------------------------------
__global__ __launch_bounds__(256) void k_pyramid(
    const float* __restrict__ xin,
    float* __restrict__ bm2, float* __restrict__ bm4, float* __restrict__ bm8,
    float* __restrict__ featA, float* __restrict__ fm1, float* __restrict__ fm2,
    float* __restrict__ fm4, float* __restrict__ fm8,
    const float* __restrict__ Wq, const float* __restrict__ Wk,
    const float* __restrict__ Wv, unsigned short* __restrict__ WB)
{
    __shared__ float sx[4096];
    __shared__ float s2[1024];
    __shared__ float s4[256];
    __shared__ float wred[4][8];
    const int bc = blockIdx.x;
    const int t = threadIdx.x;
    if (bc >= 1024) {
        const int e0 = (bc - 1024) * 1024 + t * 4;
        const int o = e0 >> 8, col = e0 & 255;
        const float* row = (o < 32) ? (Wq + (size_t)o * 1024)
                          : (o < 64) ? (Wk + (size_t)(o - 32) * 1024)
                                     : (Wv + (size_t)(o - 64) * 1024);
        float4 v = *(const float4*)(row + 768 + col);
        uint2 pk;
        pk.x = (unsigned)f2bf(v.x) | ((unsigned)f2bf(v.y) << 16);
        pk.y = (unsigned)f2bf(v.z) | ((unsigned)f2bf(v.w) << 16);
        *(uint2*)(WB + e0) = pk;
        return;
    }
    const float* xp = xin + (size_t)bc * 4096;
    float sum = 0.f, mx = -1e30f;
    for (int r = 0; r < 4; r++) {
        int i4 = t + 256 * r;
        float4 v = ((const float4*)xp)[i4];
        sum += v.x + v.y + v.z + v.w;
        mx = fmaxf(mx, fmaxf(fmaxf(v.x, v.y), fmaxf(v.z, v.w)));
        ((float4*)sx)[i4] = v;
    }
    __syncthreads();
    float mx2 = -1e30f;
    for (int r = 0; r < 4; r++) {
        int i = t + 256 * r;
        int r2 = i >> 5, c2 = i & 31;
        int p0 = 128 * r2 + 2 * c2;
        float v = 0.25f * (sx[p0] + sx[p0 + 1] + sx[p0 + 64] + sx[p0 + 65]);
        s2[i] = v;
        bm2[(size_t)bc * 1024 + i] = v;
        mx2 = fmaxf(mx2, v);
    }
    __syncthreads();
    float mx4;
    {
        int r4 = t >> 4, c4 = t & 15;
        int p0 = 64 * r4 + 2 * c4;
        float v = 0.25f * (s2[p0] + s2[p0 + 1] + s2[p0 + 32] + s2[p0 + 33]);
        s4[t] = v;
        bm4[(size_t)bc * 256 + t] = v;
        mx4 = v;
    }
    __syncthreads();
    float mx8 = -1e30f;
    if (t < 64) {
        int r8 = t >> 3, c8 = t & 7;
        int p0 = 32 * r8 + 2 * c8;
        float v = 0.25f * (s4[p0] + s4[p0 + 1] + s4[p0 + 16] + s4[p0 + 17]);
        bm8[(size_t)bc * 64 + t] = v;
        mx8 = v;
    }
    {
        float vs = sum, v1 = mx, v2 = mx2, v4 = mx4, v8 = mx8;
        #pragma unroll
        for (int o = 1; o < 64; o <<= 1) {
            vs += __shfl_xor(vs, o);
            v1 = fmaxf(v1, __shfl_xor(v1, o));
            v2 = fmaxf(v2, __shfl_xor(v2, o));
            v4 = fmaxf(v4, __shfl_xor(v4, o));
            v8 = fmaxf(v8, __shfl_xor(v8, o));
        }
        if ((t & 63) == 0) {
            int wd = t >> 6;
            wred[wd][0] = vs; wred[wd][1] = v1; wred[wd][2] = v2;
            wred[wd][3] = v4; wred[wd][4] = v8;
        }
        __syncthreads();
        if (t == 0) featA[bc] = (wred[0][0] + wred[1][0] + wred[2][0] + wred[3][0]) * (1.f / 4096.f);
        else if (t == 1) fm1[bc] = fmaxf(fmaxf(wred[0][1], wred[1][1]), fmaxf(wred[2][1], wred[3][1]));
        else if (t == 2) fm2[bc] = fmaxf(fmaxf(wred[0][2], wred[1][2]), fmaxf(wred[2][2], wred[3][2]));
        else if (t == 3) fm4[bc] = fmaxf(fmaxf(wred[0][3], wred[1][3]), fmaxf(wred[2][3], wred[3][3]));
        else if (t == 4) fm8[bc] = fmaxf(fmaxf(wred[0][4], wred[1][4]), fmaxf(wred[2][4], wred[3][4]));
    }
}

// ---------------------------------------------------------------------------
// K3: spatial-gate input with fused channel-gate MLP. Now 8 waves (512 thr):
// c-split 8 ways (32 c/wave) -> 2 waves/SIMD, half the per-thread load chain.
// ---------------------------------------------------------------------------
__global__ __launch_bounds__(512) void k3_comp(
    const float* __restrict__ x, const float* __restrict__ bm2,
    const float* __restrict__ bm4, const float* __restrict__ bm8,
    const float* __restrict__ featA, const float* __restrict__ fm1,
    const float* __restrict__ fm2, const float* __restrict__ fm4,
    const float* __restrict__ fm8,
    const float* __restrict__ W1, const float* __restrict__ b1,
    const float* __restrict__ W2, const float* __restrict__ b2,
    float* __restrict__ g, float* __restrict__ comp)
{
    __shared__ float sf[5][256];
    __shared__ float sh[5][16];
    __shared__ float hs[16];
    __shared__ float sg[256];
    __shared__ float rmx[8][64];
    __shared__ float rsm[8][64];
    const int b = blockIdx.x >> 6;
    const int t = threadIdx.x;
    if (t < 256) {
        sf[0][t] = featA[(b << 8) + t];
        sf[1][t] = fm1[(b << 8) + t];
        sf[2][t] = fm2[(b << 8) + t];
        sf[3][t] = fm4[(b << 8) + t];
        sf[4][t] = fm8[(b << 8) + t];
    }
    __syncthreads();
    if (t < 80) {
        int f = t / 16, j = t % 16;
        float a = b1[j];
        for (int c = 0; c < 256; c++) a += sf[f][c] * W1[c * 16 + j];
        sh[f][j] = fmaxf(a, 0.f);
    }
    __syncthreads();
    if (t < 16) hs[t] = 4.f * sh[0][t] + sh[1][t] + sh[2][t] + sh[3][t] + sh[4][t];
    __syncthreads();
    if (t < 256) {
        float a = 8.f * b2[t];
        for (int j = 0; j < 16; j++) a += hs[j] * W2[j * 256 + t];
        sg[t] = 1.f / (1.f + __expf(-a));
    }
    __syncthreads();
    if ((blockIdx.x & 63) == 0 && t < 256) g[(b << 8) + t] = sg[t];
    const int pix = ((blockIdx.x & 63) << 6) + (t & 63);
    const int wid = t >> 6;
    const int c0 = wid << 5;
    const int h = pix >> 6, w = pix & 63;
    const int i2 = ((h >> 1) << 5) + (w >> 1);
    const int i4 = ((h >> 2) << 4) + (w >> 2);
    const int i8 = ((h >> 3) << 3) + (w >> 3);
    const float* xb = x + ((size_t)b << 8) * 4096;
    const float* p2 = bm2 + ((size_t)b << 8) * 1024;
    const float* p4 = bm4 + ((size_t)b << 8) * 256;
    const float* p8 = bm8 + ((size_t)b << 8) * 64;
    float mx = -1e30f, sm = 0.f;
    for (int c = c0; c < c0 + 32; c++) {
        float gc = sg[c];
        float xv = xb[(size_t)c * 4096 + pix] * gc;
        float v2 = p2[c * 1024 + i2] * gc;
        float v4 = p4[c * 256 + i4] * gc;
        float v8 = p8[c * 64 + i8] * gc;
        mx = fmaxf(fmaxf(mx, xv), fmaxf(fmaxf(v2, v4), v8));
        sm += xv + v2 + v4 + v8;
    }
    rmx[wid][t & 63] = mx;
    rsm[wid][t & 63] = sm;
    __syncthreads();
    if (wid == 0) {
        int l = t;
        float m = rmx[0][l], s = rsm[0][l];
        #pragma unroll
        for (int wsrc = 1; wsrc < 8; wsrc++) {
            m = fmaxf(m, rmx[wsrc][l]);
            s += rsm[wsrc][l];
        }
        comp[((size_t)b * 2) * 4096 + pix] = m;
        comp[((size_t)b * 2 + 1) * 4096 + pix] = s * (1.f / 1024.f);
    }
}

// ---------------------------------------------------------------------------
// K4: 7x7 conv (2->1, pad 3, no bias) + BN(eval) + sigmoid. Grid 64 x 256thr.
// ---------------------------------------------------------------------------
__global__ __launch_bounds__(256) void k4_spgate(
    const float* __restrict__ comp, const float* __restrict__ Wsp,
    const float* __restrict__ bn_g, const float* __restrict__ bn_b,
    const float* __restrict__ bn_m, const float* __restrict__ bn_v,
    float* __restrict__ spg)
{
    __shared__ float w[98];
    const int t = threadIdx.x;
    for (int i = t; i < 98; i += 256) w[i] = Wsp[i];
    __syncthreads();
    const int pixg = blockIdx.x * 256 + t;
    const int b = pixg >> 12;
    const int pix = pixg & 4095;
    const int h = pix >> 6, wx = pix & 63;
    const float* c0 = comp + (size_t)b * 2 * 4096;
    float acc = 0.f;
    for (int ci = 0; ci < 2; ci++)
        for (int kh = 0; kh < 7; kh++) {
            int hh = h + kh - 3;
            if (hh < 0 || hh >= 64) continue;
            for (int kw = 0; kw < 7; kw++) {
                int wwp = wx + kw - 3;
                if (wwp < 0 || wwp >= 64) continue;
                acc += c0[ci * 4096 + hh * 64 + wwp] * w[ci * 49 + kh * 7 + kw];
            }
        }
    float sc = rsqrtf(bn_v[0] + 1e-5f) * bn_g[0];
    float sp = (acc - bn_m[0]) * sc + bn_b[0];
    spg[pixg] = 1.f / (1.f + __expf(-sp));
}

// ---------------------------------------------------------------------------
// K_X2TP: fused gate+transpose+pool2 (x2 buffer eliminated).
// ---------------------------------------------------------------------------
__global__ __launch_bounds__(256) void k_x2tp(
    const float* __restrict__ x, const float* __restrict__ g,
    const float* __restrict__ spg,
    unsigned short* __restrict__ x2T, float* __restrict__ bm2b)
{
    __shared__ float sx[128][68];
    __shared__ float gsh[64];
    __shared__ float ssh[128];
    const int b  = blockIdx.z;
    const int cb = blockIdx.y * 64;
    const int nb = blockIdx.x * 128;
    const int t  = threadIdx.x;
    if (t < 64) gsh[t] = g[(b << 8) + cb + t];
    else if (t < 192) ssh[t - 64] = spg[(size_t)b * 4096 + nb + (t - 64)];
    __syncthreads();
    const int nl = t & 127;
    const int ch = t >> 7;
    const float sp = ssh[nl];
    #pragma unroll
    for (int r = 0; r < 32; r++) {
        int cl = ch + 2 * r;
        float v = x[((size_t)(b * 256 + cb + cl)) * 4096 + nb + nl];
        sx[nl][cl] = v * (gsh[cl] * sp);
    }
    __syncthreads();
    #pragma unroll
    for (int pass = 0; pass < 8; pass++) {
        int nl2 = (t >> 4) + 16 * pass;
        int c4 = (t & 15) * 4;
        uint2 pk;
        pk.x = (unsigned)f2bf(sx[nl2][c4])     | ((unsigned)f2bf(sx[nl2][c4 + 1]) << 16);
        pk.y = (unsigned)f2bf(sx[nl2][c4 + 2]) | ((unsigned)f2bf(sx[nl2][c4 + 3]) << 16);
        *(uint2*)(x2T + ((size_t)(b * 4096 + nb + nl2)) * 256 + cb + c4) = pk;
    }
    #pragma unroll
    for (int i = 0; i < 8; i++) {
        int o = t + 256 * i;
        int c = o >> 5, w2 = o & 31;
        float v = 0.25f * (sx[2 * w2][c] + sx[2 * w2 + 1][c]
                         + sx[64 + 2 * w2][c] + sx[64 + 2 * w2 + 1][c]);
        bm2b[((size_t)(b * 256 + cb + c)) * 1024 + (nb >> 7) * 32 + w2] = v;
    }
}

// ---------------------------------------------------------------------------
// K_POOL48: bm2b -> bm4b, bm8b.
// ---------------------------------------------------------------------------
__global__ __launch_bounds__(256) void k_pool48(
    const float* __restrict__ bm2b, float* __restrict__ bm4b, float* __restrict__ bm8b)
{
    __shared__ float s2[1024];
    __shared__ float s4[256];
    const int bc = blockIdx.x;
    const int t = threadIdx.x;
    ((float4*)s2)[t] = ((const float4*)(bm2b + (size_t)bc * 1024))[t];
    __syncthreads();
    {
        int r4 = t >> 4, c4 = t & 15;
        int p0 = 64 * r4 + 2 * c4;
        float v = 0.25f * (s2[p0] + s2[p0 + 1] + s2[p0 + 32] + s2[p0 + 33]);
        s4[t] = v;
        bm4b[(size_t)bc * 256 + t] = v;
    }
    __syncthreads();
    if (t < 64) {
        int r8 = t >> 3, c8 = t & 7;
        int p0 = 32 * r8 + 2 * c8;
        bm8b[(size_t)bc * 64 + t] = 0.25f * (s4[p0] + s4[p0 + 1] + s4[p0 + 16] + s4[p0 + 17]);
    }
}

// ---------------------------------------------------------------------------
// K6: fp32 projection GEMM for low-res P2/P4/P8.
// ---------------------------------------------------------------------------
__global__ __launch_bounds__(256) void k6_gemm(
    const float* __restrict__ Wq, const float* __restrict__ Wk, const float* __restrict__ Wv,
    const float* __restrict__ bm2b, const float* __restrict__ bm4b, const float* __restrict__ bm8b,
    float* __restrict__ P2, float* __restrict__ P4, float* __restrict__ P8)
{
    __shared__ float At[32][68];
    __shared__ float Bt[32][64];
    const int bx = blockIdx.x;
    int col_off, ns, nb;
    const float* src;
    float* outp;
    if (bx < 16)      { col_off = 0;   src = bm2b; ns = 1024; outp = P2; nb = bx; }
    else if (bx < 20) { col_off = 256; src = bm4b; ns = 256;  outp = P4; nb = bx - 16; }
    else              { col_off = 512; src = bm8b; ns = 64;   outp = P8; nb = 0; }
    const int b = blockIdx.z;
    const int o_base = blockIdx.y * 64;
    const int n_base = nb * 64;
    const int t = threadIdx.x;
    const int tn = t >> 4, tm = t & 15;
    const int lk = t & 31, lo8 = t >> 5;
    const int ln = t & 63, lk4 = t >> 6;
    float acc[4][4];
    #pragma unroll
    for (int i = 0; i < 4; i++)
        #pragma unroll
        for (int j = 0; j < 4; j++) acc[i][j] = 0.f;
    for (int k0 = 0; k0 < 256; k0 += 32) {
        __syncthreads();
        #pragma unroll
        for (int r = 0; r < 8; r++) {
            int o = o_base + lo8 + 8 * r;
            const float* wrow = (o < 32) ? (Wq + (size_t)o * 1024)
                              : (o < 64) ? (Wk + (size_t)(o - 32) * 1024)
                                         : (Wv + (size_t)(o - 64) * 1024);
            At[lk][lo8 + 8 * r] = wrow[col_off + k0 + lk];
        }
        #pragma unroll
        for (int r = 0; r < 8; r++)
            Bt[lk4 + 4 * r][ln] = src[((size_t)b * 256 + k0 + lk4 + 4 * r) * ns + n_base + ln];
        __syncthreads();
        #pragma unroll
        for (int kk = 0; kk < 32; kk++) {
            float4 a = *(const float4*)&At[kk][4 * tn];
            float4 bb = *(const float4*)&Bt[kk][4 * tm];
            acc[0][0] += a.x * bb.x; acc[0][1] += a.x * bb.y; acc[0][2] += a.x * bb.z; acc[0][3] += a.x * bb.w;
            acc[1][0] += a.y * bb.x; acc[1][1] += a.y * bb.y; acc[1][2] += a.y * bb.z; acc[1][3] += a.y * bb.w;
            acc[2][0] += a.z * bb.x; acc[2][1] += a.z * bb.y; acc[2][2] += a.z * bb.z; acc[2][3] += a.z * bb.w;
            acc[3][0] += a.w * bb.x; acc[3][1] += a.w * bb.y; acc[3][2] += a.w * bb.z; acc[3][3] += a.w * bb.w;
        }
    }
    #pragma unroll
    for (int i = 0; i < 4; i++)
        #pragma unroll
        for (int j = 0; j < 4; j++)
            outp[((size_t)b * 320 + o_base + 4 * tn + i) * ns + n_base + 4 * tm + j] = acc[i][j];
}

// ---------------------------------------------------------------------------
// K6M: full-res projection via bf16 MFMA, XCD-PINNED 1-D grid 640.
// obase==0 blocks additionally emit per-token |q|, |k| norms (for the
// softmax-shift bound that replaces the deleted k7a stats pass).
// ---------------------------------------------------------------------------
__global__ __launch_bounds__(256) void k6m(
    const unsigned short* __restrict__ WB, const unsigned short* __restrict__ x2T,
    const float* __restrict__ bq, const float* __restrict__ bk, const float* __restrict__ bv,
    const float* __restrict__ P2, const float* __restrict__ P4, const float* __restrict__ P8,
    unsigned short* __restrict__ qT, unsigned short* __restrict__ kT,
    unsigned short* __restrict__ vC, float* __restrict__ qn, float* __restrict__ kn)
{
    const int bid = blockIdx.x;
    const int b = (bid >> 1) & 3;
    const int rest = ((bid >> 3) << 1) | (bid & 1);   // 0..159
    const int nb = (rest & 31) * 128;
    const int obase = (rest >> 5) * 64;
    const int t = threadIdx.x;
    const int w_ = t >> 6, lane = t & 63;
    const int quad = lane >> 4, l16 = lane & 15;
    const int nbase = nb + 32 * w_;
    f32x4 acc[4][2];
    #pragma unroll
    for (int ot = 0; ot < 4; ot++)
        #pragma unroll
        for (int nt = 0; nt < 2; nt++) { acc[ot][nt][0] = 0.f; acc[ot][nt][1] = 0.f; acc[ot][nt][2] = 0.f; acc[ot][nt][3] = 0.f; }
    const unsigned short* xb = x2T + ((size_t)b * 4096 + nbase) * 256;
    for (int k0 = 0; k0 < 256; k0 += 32) {
        FRAG af[4], bf[2];
        #pragma unroll
        for (int ot = 0; ot < 4; ot++)
            af[ot].u = *(const uint4*)(WB + (size_t)(obase + 16 * ot + l16) * 256 + k0 + quad * 8);
        #pragma unroll
        for (int nt = 0; nt < 2; nt++)
            bf[nt].u = *(const uint4*)(xb + (size_t)(16 * nt + l16) * 256 + k0 + quad * 8);
        #pragma unroll
        for (int ot = 0; ot < 4; ot++)
            #pragma unroll
            for (int nt = 0; nt < 2; nt++)
                acc[ot][nt] = __builtin_amdgcn_mfma_f32_16x16x32_bf16(af[ot].s, bf[nt].s, acc[ot][nt], 0, 0, 0);
    }
    float qsq[2] = {0.f, 0.f}, ksq[2] = {0.f, 0.f};
    #pragma unroll
    for (int ot = 0; ot < 4; ot++) {
        #pragma unroll
        for (int nt = 0; nt < 2; nt++) {
            int n = nbase + 16 * nt + l16;
            int h = n >> 6, wx = n & 63;
            int i2 = ((h >> 1) << 5) + (wx >> 1);
            int i4 = ((h >> 2) << 4) + (wx >> 2);
            int i8 = ((h >> 3) << 3) + (wx >> 3);
            float vals[4];
            #pragma unroll
            for (int r = 0; r < 4; r++) {
                int o = obase + 16 * ot + 4 * quad + r;
                float bias = (o < 32) ? bq[o] : (o < 64) ? bk[o - 32] : bv[o - 64];
                size_t ro = (size_t)b * 320 + o;
                vals[r] = acc[ot][nt][r] + bias
                        + P2[ro * 1024 + i2] + P4[ro * 256 + i4] + P8[ro * 64 + i8];
            }
            float ss = vals[0] * vals[0] + vals[1] * vals[1]
                     + vals[2] * vals[2] + vals[3] * vals[3];
            if (ot < 2) qsq[nt] += ss; else ksq[nt] += ss;
            int o0 = obase + 16 * ot + 4 * quad;
            if (o0 < 64) {
                uint2 pk;
                pk.x = (unsigned)f2bf(vals[0]) | ((unsigned)f2bf(vals[1]) << 16);
                pk.y = (unsigned)f2bf(vals[2]) | ((unsigned)f2bf(vals[3]) << 16);
                if (o0 < 32)
                    *(uint2*)(qT + ((size_t)(b * 4096 + n)) * 32 + o0) = pk;
                else
                    *(uint2*)(kT + ((size_t)(b * 4096 + n)) * 32 + (o0 - 32)) = pk;
            } else {
                int chunk = n >> 6;
                int kk = n & 63;
                int khw_ = (kk >> 5) & 1, qd = (kk >> 3) & 3, ko = kk & 7;
                unsigned short* dst = vC + (((size_t)b * 64 + chunk) << 14);
                #pragma unroll
                for (int r = 0; r < 4; r++) {
                    int c = o0 - 64 + r;
                    dst[((((c >> 4) << 1) + khw_) << 9) + ((qd * 16 + (c & 15)) << 3) + ko] = f2bf(vals[r]);
                }
            }
        }
    }
    if (obase == 0) {
        #pragma unroll
        for (int nt = 0; nt < 2; nt++) {
            float q2 = qsq[nt], k2 = ksq[nt];
            q2 += __shfl_xor(q2, 16); q2 += __shfl_xor(q2, 32);
            k2 += __shfl_xor(k2, 16); k2 += __shfl_xor(k2, 32);
            if (quad == 0) {
                int n = nbase + 16 * nt + l16;
                qn[b * 4096 + n] = sqrtf(q2);
                kn[b * 4096 + n] = sqrtf(k2);
            }
        }
    }
}

// ---------------------------------------------------------------------------
// K_MBOUND: mstat[b][n] = 1.02 * |q_n| * max_n |k_n|  — a guaranteed upper
// bound on row-max of QK^T (Cauchy-Schwarz + bf16-rounding margin). Softmax
// is shift-exact for any bound >= max, so this replaces the k7a stats pass.
// ---------------------------------------------------------------------------
__global__ __launch_bounds__(1024) void k_mbound(
    const float* __restrict__ qn, const float* __restrict__ kn,
    float* __restrict__ mstat)
{
    __shared__ float red[16];
    __shared__ float Ks;
    const int b = blockIdx.x, t = threadIdx.x;
    float mx = 0.f;
    #pragma unroll
    for (int i = 0; i < 4; i++) mx = fmaxf(mx, kn[b * 4096 + t + 1024 * i]);
    #pragma unroll
    for (int o = 1; o < 64; o <<= 1) mx = fmaxf(mx, __shfl_xor(mx, o));
    if ((t & 63) == 0) red[t >> 6] = mx;
    __syncthreads();
    if (t == 0) {
        float m = red[0];
        #pragma unroll
        for (int i = 1; i < 16; i++) m = fmaxf(m, red[i]);
        Ks = 1.02f * m;
    }
    __syncthreads();
    const float K = Ks;
    #pragma unroll
    for (int i = 0; i < 4; i++) {
        int n = t + 1024 * i;
        mstat[b * 4096 + n] = qn[b * 4096 + n] * K;
    }
}

// ---------------------------------------------------------------------------
// K7B v18 = proven v16/v17 structure + SELF-COMPUTED softmax denominator:
// each producer wave accumulates l = sum of its fp32 exp(e - m̂) values
// (wave-private, zero extra sync); epilogue quad-reduces + combines khw
// halves in LDS -> il. mstat is now the Cauchy-Schwarz bound (shift-exact).
// The entire k7a stats kernel is deleted.
// ---------------------------------------------------------------------------
__global__ __launch_bounds__(512) void k7b_attn(
    const unsigned short* __restrict__ qT, const unsigned short* __restrict__ kT,
    const unsigned short* __restrict__ vC, const float* __restrict__ mstat,
    const float* __restrict__ x, const float* __restrict__ g,
    const float* __restrict__ spg, const float* __restrict__ gamma,
    float* __restrict__ outp)
{
    __shared__ __align__(16) unsigned short PL[2][64][64];  // 16 KB swizzled P
    __shared__ float SB[128][68];                           // 34.8 KB combine buffer
    __shared__ float gsh[256];
    __shared__ float ssh[64];
    __shared__ float lsh[2][64];
    __shared__ float ilsh[64];
    const int bid = blockIdx.x;
    const int b = (bid >> 1) & 3;
    const int qbase = (((bid >> 3) << 1) | (bid & 1)) << 6;
    const int t = threadIdx.x;
    const int wid = t >> 6, lane = t & 63;
    const int cw = wid & 3, khw = wid >> 2;
    const int quad = lane >> 4, l16 = lane & 15;
    const int ntq = wid & 3;                // QK n-tile of this wave
    const int mt0 = 2 * khw, mt1 = 2 * khw + 1;
    const int nq = qbase + 16 * ntq + l16;  // column of this wave's P rows

    FRAG qf;
    qf.u = *(const uint4*)(qT + ((size_t)(b * 4096 + nq)) * 32 + quad * 8);
    const float mN = mstat[b * 4096 + nq];
    float l_run = 0.f;

    f32x4 acc[4][4];
    #pragma unroll
    for (int ct = 0; ct < 4; ct++)
        #pragma unroll
        for (int nt = 0; nt < 4; nt++) { acc[ct][nt][0] = 0.f; acc[ct][nt][1] = 0.f; acc[ct][nt][2] = 0.f; acc[ct][nt][3] = 0.f; }
    const unsigned short* kTb = kT + (size_t)b * 4096 * 32;
    const unsigned short* vfb = vC + ((size_t)b * 64 << 14)
                              + (((8 * cw) + khw) << 9) + lane * 8;

    const int po  = 4 * (quad & 1);
    const int pg0 = ((4 * khw + (quad >> 1)) ^ (l16 & 7));
    const int pg1 = ((4 * khw + 2 + (quad >> 1)) ^ (l16 & 7));
    const int pgr = ((4 * khw + quad) ^ (l16 & 7)) << 3;

    FRAG avA[4], avB[4], kc0, kc1;

#define AV_LOAD(AV, CH) do { \
    const unsigned short* vfj = vfb + ((size_t)(CH) << 14); \
    AV[0].u = *(const uint4*)(vfj); \
    AV[1].u = *(const uint4*)(vfj + 1024); \
    AV[2].u = *(const uint4*)(vfj + 2048); \
    AV[3].u = *(const uint4*)(vfj + 3072); \
} while (0)

#define KC_LOAD(CH) do { \
    const int mo_ = (CH) << 6; \
    kc0.u = *(const uint4*)(kTb + (size_t)(mo_ + 16 * mt0 + l16) * 32 + quad * 8); \
    kc1.u = *(const uint4*)(kTb + (size_t)(mo_ + 16 * mt1 + l16) * 32 + quad * 8); \
} while (0)

#define QK_EXP_STORE(DST) do { \
    f32x4 z; z[0] = 0.f; z[1] = 0.f; z[2] = 0.f; z[3] = 0.f; \
    f32x4 e0 = __builtin_amdgcn_mfma_f32_16x16x32_bf16(kc0.s, qf.s, z, 0, 0, 0); \
    f32x4 e1 = __builtin_amdgcn_mfma_f32_16x16x32_bf16(kc1.s, qf.s, z, 0, 0, 0); \
    union { float f; unsigned int u; } p0, p1, p2, p3; \
    uint2 pkA, pkB; \
    p0.f = __expf(e0[0] - mN); p1.f = __expf(e0[1] - mN); \
    p2.f = __expf(e0[2] - mN); p3.f = __expf(e0[3] - mN); \
    l_run += (p0.f + p1.f) + (p2.f + p3.f); \
    pkA.x = __builtin_amdgcn_perm(p1.u, p0.u, 0x07060302u); \
    pkA.y = __builtin_amdgcn_perm(p3.u, p2.u, 0x07060302u); \
    p0.f = __expf(e1[0] - mN); p1.f = __expf(e1[1] - mN); \
    p2.f = __expf(e1[2] - mN); p3.f = __expf(e1[3] - mN); \
    l_run += (p0.f + p1.f) + (p2.f + p3.f); \
    pkB.x = __builtin_amdgcn_perm(p1.u, p0.u, 0x07060302u); \
    pkB.y = __builtin_amdgcn_perm(p3.u, p2.u, 0x07060302u); \
    *(uint2*)&PL[DST][16 * ntq + l16][(pg0 << 3) + po] = pkA; \
    *(uint2*)&PL[DST][16 * ntq + l16][(pg1 << 3) + po] = pkB; \
} while (0)

#define PV_STEP(AV, CUR) do { \
    FRAG bp[4]; \
    _Pragma("unroll") \
    for (int nt = 0; nt < 4; nt++) \
        bp[nt].u = *(const uint4*)&PL[CUR][16 * nt + l16][pgr]; \
    __builtin_amdgcn_s_setprio(1); \
    _Pragma("unroll") \
    for (int ct = 0; ct < 4; ct++) { \
        _Pragma("unroll") \
        for (int nt = 0; nt < 4; nt++) \
            acc[ct][nt] = __builtin_amdgcn_mfma_f32_16x16x32_bf16(AV[ct].s, bp[nt].s, acc[ct][nt], 0, 0, 0); \
    } \
    __builtin_amdgcn_s_setprio(0); \
} while (0)

    // --- prologue: av(0); QK(0)->PL[0]; kc for chunk 1 ---
    AV_LOAD(avA, 0);
    KC_LOAD(0);
    QK_EXP_STORE(0);
    KC_LOAD(1);

    for (int jj = 0; jj < 32; jj++) {
        const int j = 2 * jj;
        __syncthreads();
        {
            AV_LOAD(avB, j + 1);
            QK_EXP_STORE(1);
            if (j < 62) KC_LOAD(j + 2);
        }
        PV_STEP(avA, 0);
        __syncthreads();
        if (j < 62) {
            AV_LOAD(avA, j + 2);
            QK_EXP_STORE(0);
            if (j < 61) KC_LOAD(j + 3);
        }
        PV_STEP(avB, 1);
    }
#undef AV_LOAD
#undef KC_LOAD
#undef QK_EXP_STORE
#undef PV_STEP

    // l: reduce across quads (lanes l16, +16, +32, +48 hold the 4 row-quads
    // of this wave's khw half) -> per-(ntq,l16) half-sum.
    l_run += __shfl_xor(l_run, 16);
    l_run += __shfl_xor(l_run, 32);
    if (quad == 0) lsh[khw][16 * ntq + l16] = l_run;

    // residual gate factors for the epilogue
    if (t < 256) gsh[t] = g[(b << 8) + t];
    else if (t < 320) ssh[t - 256] = spg[(size_t)b * 4096 + qbase + (t - 256)];

    // --- epilogue: combine khw halves via SB, 2 c-stripe rounds ---
    const float gm = gamma[0];
    for (int s = 0; s < 2; s++) {
        __syncthreads();
        if (s == 0 && t < 64) ilsh[t] = 1.f / (lsh[0][t] + lsh[1][t]);
        if (khw == 0 && (cw >> 1) == s) {
            #pragma unroll
            for (int ct = 0; ct < 4; ct++)
                #pragma unroll
                for (int nt = 0; nt < 4; nt++)
                    #pragma unroll
                    for (int r = 0; r < 4; r++)
                        SB[64 * (cw & 1) + 16 * ct + 4 * quad + r][16 * nt + l16] = acc[ct][nt][r];
        }
        __syncthreads();
        if (khw == 1 && (cw >> 1) == s) {
            #pragma unroll
            for (int ct = 0; ct < 4; ct++)
                #pragma unroll
                for (int nt = 0; nt < 4; nt++)
                    #pragma unroll
                    for (int r = 0; r < 4; r++)
                        SB[64 * (cw & 1) + 16 * ct + 4 * quad + r][16 * nt + l16] += acc[ct][nt][r];
        }
        __syncthreads();
        // cooperative store: 128c x 64n
        #pragma unroll
        for (int pass = 0; pass < 4; pass++) {
            int cl = (t >> 4) + 32 * pass;
            int n4 = (t & 15) * 4;
            float4 vv = *(float4*)&SB[cl][n4];
            float4 il4 = *(float4*)&ilsh[n4];
            size_t idx = ((size_t)(b * 256 + 128 * s + cl)) * 4096 + qbase + n4;
            float4 xv = *(const float4*)(x + idx);
            float gc = gsh[128 * s + cl];
            float4 ss4 = *(float4*)&ssh[n4];
            float4 ov;
            ov.x = gm * vv.x * il4.x + xv.x * (gc * ss4.x);
            ov.y = gm * vv.y * il4.y + xv.y * (gc * ss4.y);
            ov.z = gm * vv.z * il4.z + xv.z * (gc * ss4.z);
            ov.w = gm * vv.w * il4.w + xv.w * (gc * ss4.w);
            *(float4*)(outp + idx) = ov;
        }
    }
}

// ---------------------------------------------------------------------------
extern "C" void kernel_launch(void* const* d_in, const int* in_sizes, int n_in,
                              void* d_out, int out_size, void* d_ws, size_t ws_size,
                              hipStream_t stream) {
    (void)in_sizes; (void)n_in; (void)out_size; (void)ws_size;
    const float* x    = (const float*)d_in[0];
    const float* W1   = (const float*)d_in[1];
    const float* b1   = (const float*)d_in[2];
    const float* W2   = (const float*)d_in[3];
    const float* b2   = (const float*)d_in[4];
    const float* Wq   = (const float*)d_in[5];
    const float* bq   = (const float*)d_in[6];
    const float* Wk   = (const float*)d_in[7];
    const float* bk   = (const float*)d_in[8];
    const float* Wv   = (const float*)d_in[9];
    const float* bv   = (const float*)d_in[10];
    const float* gam  = (const float*)d_in[11];
    const float* Wsp  = (const float*)d_in[12];
    const float* bn_g = (const float*)d_in[13];
    const float* bn_b = (const float*)d_in[14];
    const float* bn_m = (const float*)d_in[15];
    const float* bn_v = (const float*)d_in[16];

    float* ws = (float*)d_ws;
    float* bm2   = ws; ws += (size_t)4 * 256 * 1024;
    float* bm4   = ws; ws += (size_t)4 * 256 * 256;
    float* bm8   = ws; ws += (size_t)4 * 256 * 64;
    float* featA = ws; ws += 1024;
    float* fm1   = ws; ws += 1024;
    float* fm2   = ws; ws += 1024;
    float* fm4   = ws; ws += 1024;
    float* fm8   = ws; ws += 1024;
    float* g     = ws; ws += 1024;
    float* comp  = ws; ws += (size_t)4 * 2 * 4096;
    float* spg   = ws; ws += (size_t)4 * 4096;
    float* bm2b  = ws; ws += (size_t)4 * 256 * 1024;
    float* bm4b  = ws; ws += (size_t)4 * 256 * 256;
    float* bm8b  = ws; ws += (size_t)4 * 256 * 64;
    float* P2    = ws; ws += (size_t)4 * 320 * 1024;
    float* P4    = ws; ws += (size_t)4 * 320 * 256;
    float* P8    = ws; ws += (size_t)4 * 320 * 64;
    float* mstat = ws; ws += (size_t)4 * 4096;
    float* qn    = ws; ws += (size_t)4 * 4096;
    float* kn    = ws; ws += (size_t)4 * 4096;
    unsigned short* qT  = (unsigned short*)ws; ws += (size_t)4 * 4096 * 32 / 2;
    unsigned short* kT  = (unsigned short*)ws; ws += (size_t)4 * 4096 * 32 / 2;
    unsigned short* vCp = (unsigned short*)ws; ws += (size_t)4 * 64 * 16384 / 2;
    unsigned short* x2T = (unsigned short*)ws; ws += (size_t)4 * 4096 * 256 / 2;
    unsigned short* WB  = (unsigned short*)ws; ws += (size_t)320 * 256 / 2;

    // Stage 1: channel gate (pyramid + fused weight-cast)
    k_pyramid<<<1104, 256, 0, stream>>>(x, bm2, bm4, bm8,
                                        featA, fm1, fm2, fm4, fm8,
                                        Wq, Wk, Wv, WB);
    // Stage 2: spatial gate (k3 with fused channel-gate MLP; 8 waves)
    k3_comp<<<256, 512, 0, stream>>>(x, bm2, bm4, bm8,
                                     featA, fm1, fm2, fm4, fm8,
                                     W1, b1, W2, b2, g, comp);
    k4_spgate<<<64, 256, 0, stream>>>(comp, Wsp, bn_g, bn_b, bn_m, bn_v, spg);
    // Fused gate+transpose+pool2, then bm4b/bm8b
    k_x2tp<<<dim3(32, 4, 4), 256, 0, stream>>>(x, g, spg, x2T, bm2b);
    k_pool48<<<1024, 256, 0, stream>>>(bm2b, bm4b, bm8b);
    // Stage 3: q/k/v projections (+ per-token q/k norms)
    k6_gemm<<<dim3(21, 5, 4), 256, 0, stream>>>(Wq, Wk, Wv, bm2b, bm4b, bm8b, P2, P4, P8);
    k6m<<<640, 256, 0, stream>>>(WB, x2T, bq, bk, bv, P2, P4, P8, qT, kT, vCp, qn, kn);
    // Softmax shift bound (replaces the whole k7a stats pass)
    k_mbound<<<4, 1024, 0, stream>>>(qn, kn, mstat);
    // Attention: single pass, denominator computed in-kernel
    k7b_attn<<<256, 512, 0, stream>>>(qT, kT, vCp, mstat, x, g, spg, gam, (float*)d_out);
}